// Round 6
// baseline (6984.233 us; speedup 1.0000x reference)
//
#include <hip/hip_runtime.h>
#include <math.h>

#define NB   8
#define CI   64
#define COC  64
#define HQ   256
#define HK   64
#define KS   5
#define LL   256
#define NPAD 1664

// ---------------- weight transpose: [CO][CI][3][3] -> [half][CI][tap][32] ----------------
__global__ void wtrans2_kernel(const float* __restrict__ Wt, float* __restrict__ Wo) {
  const int co = threadIdx.x;   // 0..63
  const int tap = blockIdx.x;   // 0..8
  const int ci = blockIdx.y;    // 0..63
  Wo[(((co >> 5) * 64 + ci) * 9 + tap) * 32 + (co & 31)] = Wt[(co * 64 + ci) * 9 + tap];
}

// ---------------- pad copy: src[H][W] -> dst[(H+2)][S] at +1,+1 ----------------
__global__ void pad_copy(const float* __restrict__ src, float* __restrict__ dst,
                         int H, int W, int S, int total) {
  const int idx = blockIdx.x * 256 + threadIdx.x;
  if (idx >= total) return;
  const int p = idx / (H * W);
  const int rem = idx - p * H * W;
  const int y = rem / W, x = rem - y * W;
  dst[((size_t)p * (H + 2) + y + 1) * S + x + 1] = src[idx];
}

// ---------------- border zero ----------------
__global__ void border_zero(float* __restrict__ dst, int H, int W, int S) {
  const int p = blockIdx.x;
  float* b = dst + (size_t)p * (H + 2) * S;
  for (int c = threadIdx.x; c < S; c += 256) {
    b[c] = 0.f;
    b[(size_t)(H + 1) * S + c] = 0.f;
  }
  for (int r = 1 + threadIdx.x; r <= H; r += 256) {
    b[(size_t)r * S] = 0.f;
    b[(size_t)r * S + W + 1] = 0.f;
  }
}

// ---------------- conv 3x3 pad1 + bias + leaky relu ----------------
// block tile: 64x X 8y X 32co. grid (W/64, H/8, NB*2). 256 threads.
// waves_per_eu(4,4): pin 4 waves/EU so regalloc gets 128 VGPRs (no acc spill).
__global__ __launch_bounds__(256) __attribute__((amdgpu_waves_per_eu(4, 4)))
void conv3p(
    const float* __restrict__ inp /*padded [(H+2)][S]*/,
    const float* __restrict__ Wts /*[half][CI][9][32]*/,
    const float* __restrict__ bias, float* __restrict__ out,
    int H, int Wd, int S) {
  const int x0 = blockIdx.x * 64;
  const int y0 = blockIdx.y * 8;
  const int z  = blockIdx.z;
  const int n  = z >> 1;
  const int half = z & 1;
  const int cob = half * 32;
  const int tid = threadIdx.x;
  const int xq = tid & 15;
  const int yt = (tid >> 4) & 3;
  const int cg = tid >> 6;
  const int Hp = H + 2;

  __shared__ float in_s[10 * 76];
  __shared__ float w_s[9 * 32];

  float acc[8][2][4];
  #pragma unroll
  for (int a = 0; a < 8; ++a)
    #pragma unroll
    for (int b = 0; b < 2; ++b)
      #pragma unroll
      for (int c = 0; c < 4; ++c) acc[a][b][c] = 0.f;

  const bool hasA = tid < 180;
  const bool hasW = (tid >= 180) && (tid < 252);
  const int arow = tid / 18, ac4 = tid - arow * 18;
  const float* gplane0 = inp + (size_t)(n * CI) * Hp * S;
  const size_t aoff = ((size_t)(y0 + arow)) * S + x0 + ac4 * 4;
  const int wi = tid - 180;
  const float* wbase = Wts + (size_t)half * 64 * 288;

  float4 sA = make_float4(0.f, 0.f, 0.f, 0.f);
  float4 sW = make_float4(0.f, 0.f, 0.f, 0.f);
  if (hasA) sA = *(const float4*)(gplane0 + aoff);
  if (hasW) sW = *(const float4*)(wbase + wi * 4);

  for (int ci = 0; ci < CI; ++ci) {
    __syncthreads();
    if (hasA) *(float4*)&in_s[arow * 76 + ac4 * 4] = sA;
    if (hasW) *(float4*)&w_s[wi * 4] = sW;
    if (ci + 1 < CI) {
      if (hasA) sA = *(const float4*)(gplane0 + (size_t)(ci + 1) * Hp * S + aoff);
      if (hasW) sW = *(const float4*)(wbase + (size_t)(ci + 1) * 288 + wi * 4);
    }
    __syncthreads();

    // my 4 rows x 8 cols via 2x ds_read_b128 per row (cols 0..5 used)
    float xin[4][8];
    const int rb = yt * 2, cb = xq * 4;
    #pragma unroll
    for (int r = 0; r < 4; ++r) {
      const float4 xa = *(const float4*)&in_s[(rb + r) * 76 + cb];
      const float4 xb = *(const float4*)&in_s[(rb + r) * 76 + cb + 4];
      xin[r][0] = xa.x; xin[r][1] = xa.y; xin[r][2] = xa.z; xin[r][3] = xa.w;
      xin[r][4] = xb.x; xin[r][5] = xb.y; xin[r][6] = xb.z; xin[r][7] = xb.w;
    }

    #pragma unroll
    for (int tap = 0; tap < 9; ++tap) {
      const int ky = tap / 3, kx = tap % 3;
      const float4 w0 = *(const float4*)&w_s[tap * 32 + cg * 8];
      const float4 w1 = *(const float4*)&w_s[tap * 32 + cg * 8 + 4];
      const float wv[8] = {w0.x, w0.y, w0.z, w0.w, w1.x, w1.y, w1.z, w1.w};
      #pragma unroll
      for (int c8 = 0; c8 < 8; ++c8)
        #pragma unroll
        for (int dy = 0; dy < 2; ++dy)
          #pragma unroll
          for (int dx = 0; dx < 4; ++dx)
            acc[c8][dy][dx] = fmaf(wv[c8], xin[dy + ky][dx + kx], acc[c8][dy][dx]);
    }
  }

  #pragma unroll
  for (int c8 = 0; c8 < 8; ++c8) {
    const int co = cob + cg * 8 + c8;
    const float bv = bias[co];
    #pragma unroll
    for (int dy = 0; dy < 2; ++dy) {
      float4 o;
      float t;
      t = acc[c8][dy][0] + bv; o.x = t > 0.f ? t : 0.01f * t;
      t = acc[c8][dy][1] + bv; o.y = t > 0.f ? t : 0.01f * t;
      t = acc[c8][dy][2] + bv; o.z = t > 0.f ? t : 0.01f * t;
      t = acc[c8][dy][3] + bv; o.w = t > 0.f ? t : 0.01f * t;
      *(float4*)(out + ((size_t)(n * COC + co) * H + y0 + yt * 2 + dy) * Wd + x0 + xq * 4) = o;
    }
  }
}

// ---------------- k-patch squared norms ----------------
__global__ void knorm_kernel(const float* __restrict__ kfea, float* __restrict__ norms) {
  const int l = blockIdx.x, n = blockIdx.y, c = threadIdx.x;
  const int ly = l >> 4, lx = l & 15;
  const float* base = kfea + ((size_t)(n * CI + c) * HK) * HK;
  float ss = 0.f;
  #pragma unroll
  for (int i = 0; i < KS; ++i) {
    const int r = 4 * ly + i;
    if (r >= HK) continue;
    #pragma unroll
    for (int j = 0; j < KS; ++j) {
      const int cc = 4 * lx + j;
      if (cc >= HK) continue;
      const float v = base[r * HK + cc];
      ss = fmaf(v, v, ss);
    }
  }
  for (int off = 32; off; off >>= 1) ss += __shfl_down(ss, off);
  if (c == 0) norms[n * LL + l] = ss;
}

__global__ void kscale_kernel(const float* __restrict__ norms, float* __restrict__ kscale) {
  const int n = blockIdx.x, t = threadIdx.x;
  float v = norms[n * LL + t];
  for (int off = 32; off; off >>= 1) v = fmaxf(v, __shfl_down(v, off));
  __shared__ float red[4];
  if ((t & 63) == 0) red[t >> 6] = v;
  __syncthreads();
  if (t == 0) {
    const float m = fmaxf(fmaxf(red[0], red[1]), fmaxf(red[2], red[3]));
    kscale[n] = 10.0f / sqrtf(m);
  }
}

// ---------------- fused QK correlation + softmax ----------------
__global__ __launch_bounds__(256) void qk_softmax(
    const float* __restrict__ qfea, const float* __restrict__ kfea,
    const float* __restrict__ kscale, float* __restrict__ wn) {
  const int h = blockIdx.x, n = blockIdx.y;
  const int tid = threadIdx.x;
  const int lt = tid >> 4;
  const int wt = tid & 15;
  __shared__ float k_s[25 * 16 * 16];
  __shared__ float q_s[25 * 64];
  __shared__ float red[64 * 17];
  float acc[16][4];
  #pragma unroll
  for (int a = 0; a < 16; ++a)
    #pragma unroll
    for (int b = 0; b < 4; ++b) acc[a][b] = 0.f;

  const float* kb = kfea + (size_t)n * CI * HK * HK;
  const float* qb = qfea + (size_t)n * CI * HQ * HQ;

  for (int ci = 0; ci < CI; ++ci) {
    __syncthreads();
    for (int s = tid; s < 25 * 256; s += 256) {
      const int lx = s & 15, ly = (s >> 4) & 15, ij = s >> 8;
      const int i = ij / 5, j = ij % 5;
      const int r = 4 * ly + i, c = 4 * lx + j;
      k_s[s] = (r < HK && c < HK) ? kb[((size_t)ci * HK + r) * HK + c] : 0.f;
    }
    for (int s = tid; s < 25 * 64; s += 256) {
      const int w = s & 63, ij = s >> 6;
      const int i = ij / 5, j = ij % 5;
      const int gr = 4 * h + i, gc = 4 * w + j;
      q_s[s] = (gr < HQ && gc < HQ) ? qb[((size_t)ci * HQ + gr) * HQ + gc] : 0.f;
    }
    __syncthreads();
    #pragma unroll 5
    for (int ij = 0; ij < 25; ++ij) {
      const float4 q4 = *(const float4*)&q_s[ij * 64 + wt * 4];
      const float4* kp4 = (const float4*)&k_s[(ij * 16 + lt) * 16];
      const float4 k0 = kp4[0], k1 = kp4[1], k2 = kp4[2], k3 = kp4[3];
      const float kk[16] = {k0.x, k0.y, k0.z, k0.w, k1.x, k1.y, k1.z, k1.w,
                            k2.x, k2.y, k2.z, k2.w, k3.x, k3.y, k3.z, k3.w};
      const float qq[4] = {q4.x, q4.y, q4.z, q4.w};
      #pragma unroll
      for (int li = 0; li < 16; ++li)
        #pragma unroll
        for (int ww = 0; ww < 4; ++ww)
          acc[li][ww] = fmaf(kk[li], qq[ww], acc[li][ww]);
    }
  }

  const float f = kscale[n];
  #pragma unroll
  for (int li = 0; li < 16; ++li)
    #pragma unroll
    for (int ww = 0; ww < 4; ++ww) acc[li][ww] *= f;

  #pragma unroll
  for (int ww = 0; ww < 4; ++ww) {
    float m = acc[0][ww];
    #pragma unroll
    for (int li = 1; li < 16; ++li) m = fmaxf(m, acc[li][ww]);
    red[(wt * 4 + ww) * 17 + lt] = m;
  }
  __syncthreads();
  if (tid < 64) {
    float m = red[tid * 17];
    #pragma unroll
    for (int k = 1; k < 16; ++k) m = fmaxf(m, red[tid * 17 + k]);
    red[tid * 17 + 16] = m;
  }
  __syncthreads();
  float sloc[4];
  #pragma unroll
  for (int ww = 0; ww < 4; ++ww) {
    const float m = red[(wt * 4 + ww) * 17 + 16];
    float s = 0.f;
    #pragma unroll
    for (int li = 0; li < 16; ++li) {
      const float e = __expf(acc[li][ww] - m);
      acc[li][ww] = e;
      s += e;
    }
    sloc[ww] = s;
  }
  __syncthreads();
  #pragma unroll
  for (int ww = 0; ww < 4; ++ww) red[(wt * 4 + ww) * 17 + lt] = sloc[ww];
  __syncthreads();
  if (tid < 64) {
    float s = red[tid * 17];
    #pragma unroll
    for (int k = 1; k < 16; ++k) s += red[tid * 17 + k];
    red[tid * 17 + 16] = s;
  }
  __syncthreads();
  #pragma unroll
  for (int ww = 0; ww < 4; ++ww) {
    const int w = wt * 4 + ww;
    const float inv = 1.0f / red[w * 17 + 16];
    float* dst = wn + (((size_t)(n * 64 + h) * 64 + w) * 256) + lt * 16;
    #pragma unroll
    for (int q = 0; q < 4; ++q) {
      float4 o = make_float4(acc[q * 4 + 0][ww] * inv, acc[q * 4 + 1][ww] * inv,
                             acc[q * 4 + 2][ww] * inv, acc[q * 4 + 3][ww] * inv);
      *(float4*)(dst + q * 4) = o;
    }
  }
}

// ---------------- v-patch matrix gather ----------------
__global__ void vp_gather(const float* __restrict__ vfea, float* __restrict__ vp) {
  const int bij = blockIdx.x * 256 + threadIdx.x;
  const int l = blockIdx.y, n = blockIdx.z;
  if (bij >= NPAD) return;
  const int ij = bij >> 6, b = bij & 63;
  float val = 0.f;
  if (ij < 25) {
    const int i = ij / 5, j = ij % 5;
    const int ly = l >> 4, lx = l & 15;
    const int r = 4 * ly + i, c = 4 * lx + j;
    if (r < HK && c < HK) val = vfea[((size_t)(n * COC + b) * HK + r) * HK + c];
  }
  vp[((size_t)(n * LL + l)) * NPAD + bij] = val;
}

// ---------------- PV GEMM (z = batch) ----------------
__global__ __launch_bounds__(256) void pv_gemm(
    const float* __restrict__ A0, const float* __restrict__ B0, float* __restrict__ C0) {
  const int nz = blockIdx.z;
  const float* A = A0 + (size_t)nz * 4096 * 256;
  const float* Bm = B0 + (size_t)nz * LL * NPAD;
  float* C = C0 + (size_t)nz * 4096 * NPAD;
  const int m0 = blockIdx.x * 128;
  const int n0 = blockIdx.y * 128;
  const int tid = threadIdx.x;
  const int tm = tid & 15, tn = tid >> 4;
  __shared__ float As[16][132];
  __shared__ float Bs[16][128];
  float acc[8][8];
  #pragma unroll
  for (int a = 0; a < 8; ++a)
    #pragma unroll
    for (int b = 0; b < 8; ++b) acc[a][b] = 0.f;

  for (int k0 = 0; k0 < 256; k0 += 16) {
    __syncthreads();
    #pragma unroll
    for (int r = 0; r < 2; ++r) {
      const int idx = tid + r * 256;
      const int row = idx >> 2, c4 = idx & 3;
      const float4 v = *(const float4*)&A[(size_t)(m0 + row) * 256 + k0 + c4 * 4];
      As[c4 * 4 + 0][row] = v.x;
      As[c4 * 4 + 1][row] = v.y;
      As[c4 * 4 + 2][row] = v.z;
      As[c4 * 4 + 3][row] = v.w;
    }
    #pragma unroll
    for (int r = 0; r < 2; ++r) {
      const int idx = tid + r * 256;
      const int row = idx >> 5, c4 = idx & 31;
      *(float4*)&Bs[row][c4 * 4] = *(const float4*)&Bm[(size_t)(k0 + row) * NPAD + n0 + c4 * 4];
    }
    __syncthreads();
    #pragma unroll
    for (int k = 0; k < 16; ++k) {
      const float4 a0 = *(const float4*)&As[k][tm * 8];
      const float4 a1 = *(const float4*)&As[k][tm * 8 + 4];
      const float4 b0 = *(const float4*)&Bs[k][tn * 8];
      const float4 b1 = *(const float4*)&Bs[k][tn * 8 + 4];
      const float av[8] = {a0.x, a0.y, a0.z, a0.w, a1.x, a1.y, a1.z, a1.w};
      const float bv[8] = {b0.x, b0.y, b0.z, b0.w, b1.x, b1.y, b1.z, b1.w};
      #pragma unroll
      for (int mi = 0; mi < 8; ++mi)
        #pragma unroll
        for (int ni = 0; ni < 8; ++ni)
          acc[mi][ni] = fmaf(av[mi], bv[ni], acc[mi][ni]);
    }
  }
  #pragma unroll
  for (int mi = 0; mi < 8; ++mi) {
    float* dst = &C[(size_t)(m0 + tm * 8 + mi) * NPAD + n0 + tn * 8];
    *(float4*)dst = make_float4(acc[mi][0], acc[mi][1], acc[mi][2], acc[mi][3]);
    *(float4*)(dst + 4) = make_float4(acc[mi][4], acc[mi][5], acc[mi][6], acc[mi][7]);
  }
}

// ---------------- conv-transpose contribution gather (+ /6), writes padded res ----------------
__global__ __launch_bounds__(256) void u_scatter(
    const float* __restrict__ U0, float* __restrict__ resp, int n0) {
  const int n = n0 + blockIdx.z;
  const float* U = U0 + (size_t)blockIdx.z * 4096 * NPAD;
  const int y = blockIdx.y;
  const int xt = blockIdx.x;
  const int tid = threadIdx.x;
  __shared__ float t_lds[64][65];
  const int ym = (y + 1) >> 2, yr = (y + 1) & 3;
  const bool v0 = (ym < 64);
  const bool v1 = (yr == 0 && ym >= 1);
  const int b = tid & 63, xg = tid >> 6;
  for (int xi = 0; xi < 16; ++xi) {
    const int x = xt * 64 + xg * 16 + xi;
    const int xm = (x + 1) >> 2, xr = (x + 1) & 3;
    const bool u0 = (xm < 64);
    const bool u1 = (xr == 0 && xm >= 1);
    float s = 0.f;
    if (v0) {
      const size_t rb = (size_t)(ym * 64) * NPAD;
      if (u0) s += U[rb + (size_t)xm * NPAD + (yr * 5 + xr) * 64 + b];
      if (u1) s += U[rb + (size_t)(xm - 1) * NPAD + (yr * 5 + 4) * 64 + b];
    }
    if (v1) {
      const size_t rb = (size_t)((ym - 1) * 64) * NPAD;
      if (u0) s += U[rb + (size_t)xm * NPAD + (4 * 5 + xr) * 64 + b];
      if (u1) s += U[rb + (size_t)(xm - 1) * NPAD + (4 * 5 + 4) * 64 + b];
    }
    t_lds[xg * 16 + xi][b] = s * (1.0f / 6.0f);
  }
  __syncthreads();
  const int xl = tid & 63, bg = tid >> 6;
  for (int bb = 0; bb < 16; ++bb) {
    const int bc = bg * 16 + bb;
    resp[((size_t)(n * COC + bc) * 258 + y + 1) * 264 + xt * 64 + xl + 1] = t_lds[xl][bc];
  }
}

extern "C" void kernel_launch(void* const* d_in, const int* in_sizes, int n_in,
                              void* d_out, int out_size, void* d_ws, size_t ws_size,
                              hipStream_t stream) {
  const float* ms   = (const float*)d_in[0];
  const float* pan  = (const float*)d_in[1];
  const float* pan2 = (const float*)d_in[2];
  const float* Wq   = (const float*)d_in[3];
  const float* bq   = (const float*)d_in[4];
  const float* Wk   = (const float*)d_in[5];
  const float* bk   = (const float*)d_in[6];
  const float* Wv   = (const float*)d_in[7];
  const float* bv   = (const float*)d_in[8];
  const float* Wr   = (const float*)d_in[9];
  const float* br   = (const float*)d_in[10];
  float* out = (float*)d_out;

  float* ws = (float*)d_ws;
  const size_t SZ_Q   = (size_t)NB * COC * HQ * HQ;          // 33.55M
  const size_t SZ_K   = (size_t)NB * CI * HK * HK;           // 2.10M
  const size_t SZ_WN  = (size_t)NB * 64 * 64 * LL;           // 8.39M
  const size_t SZ_VP  = (size_t)NB * LL * NPAD;              // 3.41M
  const size_t SZ_PS  = (size_t)NB * CI * 66 * 72;           // 2.43M (small padded)
  const size_t SZ_U1  = (size_t)4096 * NPAD;                 // 6.82M per batch
  const size_t SZ_UA  = (size_t)NB * SZ_U1;                  // 54.53M

  float* q_fea   = ws;                    // also res_pad (aliased)
  float* k_fea   = q_fea + SZ_Q;
  float* v_fea   = k_fea + SZ_K;
  float* wn      = v_fea + SZ_K;
  float* vp      = wn + SZ_WN;
  float* norms   = vp + SZ_VP;
  float* kscale  = norms + NB * LL;
  float* wtq     = kscale + 64;
  float* wtk     = wtq + 36864;
  float* wtv     = wtk + 36864;
  float* wtr     = wtv + 36864;
  float* ms_pad  = wtr + 36864;
  float* pan2pad = ms_pad + SZ_PS;
  float* shared_blk = pan2pad + SZ_PS;    // pan_pad, later U
  float* pan_pad = shared_blk;
  float* U       = shared_blk;
  float* res_pad = q_fea;

  const size_t base_elems = (size_t)(shared_blk - ws);
  const bool batched = ws_size >= (base_elems + SZ_UA) * sizeof(float);

  // weight transposes
  wtrans2_kernel<<<dim3(9, 64), 64, 0, stream>>>(Wq, wtq);
  wtrans2_kernel<<<dim3(9, 64), 64, 0, stream>>>(Wk, wtk);
  wtrans2_kernel<<<dim3(9, 64), 64, 0, stream>>>(Wv, wtv);
  wtrans2_kernel<<<dim3(9, 64), 64, 0, stream>>>(Wr, wtr);

  // pad inputs
  {
    const int totB = NB * CI * HQ * HQ;
    pad_copy<<<dim3((totB + 255) / 256), 256, 0, stream>>>(pan, pan_pad, HQ, HQ, 264, totB);
    const int totS = NB * CI * HK * HK;
    pad_copy<<<dim3((totS + 255) / 256), 256, 0, stream>>>(ms, ms_pad, HK, HK, 72, totS);
    pad_copy<<<dim3((totS + 255) / 256), 256, 0, stream>>>(pan2, pan2pad, HK, HK, 72, totS);
    border_zero<<<dim3(NB * CI), 256, 0, stream>>>(pan_pad, HQ, HQ, 264);
    border_zero<<<dim3(NB * CI), 256, 0, stream>>>(ms_pad, HK, HK, 72);
    border_zero<<<dim3(NB * CI), 256, 0, stream>>>(pan2pad, HK, HK, 72);
  }

  // feature convs
  conv3p<<<dim3(HK / 64, HK / 8, NB * 2), 256, 0, stream>>>(pan2pad, wtk, bk, k_fea, HK, HK, 72);
  conv3p<<<dim3(HK / 64, HK / 8, NB * 2), 256, 0, stream>>>(ms_pad,  wtv, bv, v_fea, HK, HK, 72);
  conv3p<<<dim3(HQ / 64, HQ / 8, NB * 2), 256, 0, stream>>>(pan_pad, wtq, bq, q_fea, HQ, HQ, 264);

  // k-patch max norm -> scale
  knorm_kernel<<<dim3(LL, NB), 64, 0, stream>>>(k_fea, norms);
  kscale_kernel<<<NB, 256, 0, stream>>>(norms, kscale);

  // attention weights (reads q_fea, k_fea -- both dead afterwards)
  qk_softmax<<<dim3(64, NB), 256, 0, stream>>>(q_fea, k_fea, kscale, wn);

  // res_pad borders (aliases q_fea/k_fea; must be after qk_softmax)
  border_zero<<<dim3(NB * CI), 256, 0, stream>>>(res_pad, HQ, HQ, 264);

  // v patch matrix
  vp_gather<<<dim3((NPAD + 255) / 256, LL, NB), 256, 0, stream>>>(v_fea, vp);

  // PV GEMM + conv-transpose gather (U aliases pan_pad; pan_pad dead after q conv)
  if (batched) {
    pv_gemm<<<dim3(32, 13, NB), 256, 0, stream>>>(wn, vp, U);
    u_scatter<<<dim3(4, HQ, NB), 256, 0, stream>>>(U, res_pad, 0);
  } else {
    for (int n = 0; n < NB; ++n) {
      pv_gemm<<<dim3(32, 13, 1), 256, 0, stream>>>(wn + (size_t)n * 4096 * 256,
                                                   vp + (size_t)n * LL * NPAD, U);
      u_scatter<<<dim3(4, HQ, 1), 256, 0, stream>>>(U, res_pad, n);
    }
  }

  // final conv (reads padded res)
  conv3p<<<dim3(HQ / 64, HQ / 8, NB * 2), 256, 0, stream>>>(res_pad, wtr, br, out, HQ, HQ, 264);
}

// Round 7
// 2524.637 us; speedup vs baseline: 2.7664x; 2.7664x over previous
//
#include <hip/hip_runtime.h>
#include <math.h>

#define NB   8
#define CI   64
#define COC  64
#define HQ   256
#define HK   64
#define KS   5
#define LL   256
#define NPAD 1664

// ---------------- weight transpose: [CO][CI][3][3] -> [cogrp8][CI][tap][8] ----------------
__global__ void wtrans8_kernel(const float* __restrict__ Wt, float* __restrict__ Wo) {
  const int co = threadIdx.x;   // 0..63
  const int tap = blockIdx.x;   // 0..8
  const int ci = blockIdx.y;    // 0..63
  Wo[(((co >> 3) * 64 + ci) * 9 + tap) * 8 + (co & 7)] = Wt[(co * 64 + ci) * 9 + tap];
}

// ---------------- pad copy: src[H][W] -> dst[(H+2)][S] at +1,+1 ----------------
__global__ void pad_copy(const float* __restrict__ src, float* __restrict__ dst,
                         int H, int W, int S, int total) {
  const int idx = blockIdx.x * 256 + threadIdx.x;
  if (idx >= total) return;
  const int p = idx / (H * W);
  const int rem = idx - p * H * W;
  const int y = rem / W, x = rem - y * W;
  dst[((size_t)p * (H + 2) + y + 1) * S + x + 1] = src[idx];
}

// ---------------- border zero ----------------
__global__ void border_zero(float* __restrict__ dst, int H, int W, int S) {
  const int p = blockIdx.x;
  float* b = dst + (size_t)p * (H + 2) * S;
  for (int c = threadIdx.x; c < S; c += 256) {
    b[c] = 0.f;
    b[(size_t)(H + 1) * S + c] = 0.f;
  }
  for (int r = 1 + threadIdx.x; r <= H; r += 256) {
    b[(size_t)r * S] = 0.f;
    b[(size_t)r * S + W + 1] = 0.f;
  }
}

// ---------------- conv 3x3 pad1 + bias + leaky relu, low-register tiled ----------------
// block tile: 64x X 8y X 8co; 256 threads: xq=tid&15 (4px), yt=(tid>>4)&7 (1 row), cg=tid>>7 (4co).
// grid (W/64, H/8, NB*8cogrp). ~55 live floats/thread -> fits the 64-VGPR budget, no spill.
__global__ __launch_bounds__(256) void conv3s(
    const float* __restrict__ inp /*padded [(H+2)][S]*/,
    const float* __restrict__ Wts /*[cogrp8][CI][9][8]*/,
    const float* __restrict__ bias, float* __restrict__ out,
    int H, int Wd, int S) {
  const int x0 = blockIdx.x * 64;
  const int y0 = blockIdx.y * 8;
  const int z  = blockIdx.z;
  const int n  = z >> 3;
  const int cog = z & 7;
  const int tid = threadIdx.x;
  const int xq = tid & 15;
  const int yt = (tid >> 4) & 7;
  const int cg = tid >> 7;
  const int Hp = H + 2;

  __shared__ float in_s[10 * 72];
  __shared__ float w_s[CI * 9 * 8];   // all weights for this co-group: 18 KB

  // stage ALL weights once (coalesced float4)
  {
    const float* wbase = Wts + (size_t)cog * (CI * 9 * 8);
    for (int idx = tid; idx < CI * 9 * 2; idx += 256)
      *(float4*)&w_s[idx * 4] = *(const float4*)(wbase + idx * 4);
  }

  float acc[4][4];
  #pragma unroll
  for (int a = 0; a < 4; ++a)
    #pragma unroll
    for (int b = 0; b < 4; ++b) acc[a][b] = 0.f;

  const bool hasA = tid < 180;
  const int arow = tid / 18, ac4 = tid - arow * 18;
  const float* gplane0 = inp + (size_t)(n * CI) * Hp * S;
  const size_t aoff = ((size_t)(y0 + arow)) * S + x0 + ac4 * 4;

  float4 sA = make_float4(0.f, 0.f, 0.f, 0.f);
  if (hasA) sA = *(const float4*)(gplane0 + aoff);

  for (int ci = 0; ci < CI; ++ci) {
    __syncthreads();
    if (hasA) *(float4*)&in_s[arow * 72 + ac4 * 4] = sA;
    if (ci + 1 < CI && hasA)
      sA = *(const float4*)(gplane0 + (size_t)(ci + 1) * Hp * S + aoff);
    __syncthreads();

    // rows yt..yt+2, cols xq*4 .. xq*4+7
    float xin[3][8];
    const int cb = xq * 4;
    #pragma unroll
    for (int r = 0; r < 3; ++r) {
      const float4 xa = *(const float4*)&in_s[(yt + r) * 72 + cb];
      const float4 xb = *(const float4*)&in_s[(yt + r) * 72 + cb + 4];
      xin[r][0] = xa.x; xin[r][1] = xa.y; xin[r][2] = xa.z; xin[r][3] = xa.w;
      xin[r][4] = xb.x; xin[r][5] = xb.y; xin[r][6] = xb.z; xin[r][7] = xb.w;
    }

    const float* wci = &w_s[(ci * 9) * 8 + cg * 4];
    #pragma unroll
    for (int ky = 0; ky < 3; ++ky) {
      #pragma unroll
      for (int kx = 0; kx < 3; ++kx) {
        const float4 w4 = *(const float4*)&wci[(ky * 3 + kx) * 8];
        const float wv[4] = {w4.x, w4.y, w4.z, w4.w};
        #pragma unroll
        for (int c = 0; c < 4; ++c)
          #pragma unroll
          for (int dx = 0; dx < 4; ++dx)
            acc[c][dx] = fmaf(wv[c], xin[ky][dx + kx], acc[c][dx]);
      }
    }
  }

  #pragma unroll
  for (int c = 0; c < 4; ++c) {
    const int co = cog * 8 + cg * 4 + c;
    const float bv = bias[co];
    float4 o;
    float t;
    t = acc[c][0] + bv; o.x = t > 0.f ? t : 0.01f * t;
    t = acc[c][1] + bv; o.y = t > 0.f ? t : 0.01f * t;
    t = acc[c][2] + bv; o.z = t > 0.f ? t : 0.01f * t;
    t = acc[c][3] + bv; o.w = t > 0.f ? t : 0.01f * t;
    *(float4*)(out + ((size_t)(n * COC + co) * H + y0 + yt) * Wd + x0 + xq * 4) = o;
  }
}

// ---------------- k-patch squared norms ----------------
__global__ void knorm_kernel(const float* __restrict__ kfea, float* __restrict__ norms) {
  const int l = blockIdx.x, n = blockIdx.y, c = threadIdx.x;
  const int ly = l >> 4, lx = l & 15;
  const float* base = kfea + ((size_t)(n * CI + c) * HK) * HK;
  float ss = 0.f;
  #pragma unroll
  for (int i = 0; i < KS; ++i) {
    const int r = 4 * ly + i;
    if (r >= HK) continue;
    #pragma unroll
    for (int j = 0; j < KS; ++j) {
      const int cc = 4 * lx + j;
      if (cc >= HK) continue;
      const float v = base[r * HK + cc];
      ss = fmaf(v, v, ss);
    }
  }
  for (int off = 32; off; off >>= 1) ss += __shfl_down(ss, off);
  if (c == 0) norms[n * LL + l] = ss;
}

__global__ void kscale_kernel(const float* __restrict__ norms, float* __restrict__ kscale) {
  const int n = blockIdx.x, t = threadIdx.x;
  float v = norms[n * LL + t];
  for (int off = 32; off; off >>= 1) v = fmaxf(v, __shfl_down(v, off));
  __shared__ float red[4];
  if ((t & 63) == 0) red[t >> 6] = v;
  __syncthreads();
  if (t == 0) {
    const float m = fmaxf(fmaxf(red[0], red[1]), fmaxf(red[2], red[3]));
    kscale[n] = 10.0f / sqrtf(m);
  }
}

// ---------------- fused QK correlation + softmax ----------------
__global__ __launch_bounds__(256) void qk_softmax(
    const float* __restrict__ qfea, const float* __restrict__ kfea,
    const float* __restrict__ kscale, float* __restrict__ wn) {
  const int h = blockIdx.x, n = blockIdx.y;
  const int tid = threadIdx.x;
  const int lt = tid >> 4;
  const int wt = tid & 15;
  __shared__ float k_s[25 * 16 * 16];
  __shared__ float q_s[25 * 64];
  __shared__ float red[64 * 17];
  float acc[16][4];
  #pragma unroll
  for (int a = 0; a < 16; ++a)
    #pragma unroll
    for (int b = 0; b < 4; ++b) acc[a][b] = 0.f;

  const float* kb = kfea + (size_t)n * CI * HK * HK;
  const float* qb = qfea + (size_t)n * CI * HQ * HQ;

  for (int ci = 0; ci < CI; ++ci) {
    __syncthreads();
    for (int s = tid; s < 25 * 256; s += 256) {
      const int lx = s & 15, ly = (s >> 4) & 15, ij = s >> 8;
      const int i = ij / 5, j = ij % 5;
      const int r = 4 * ly + i, c = 4 * lx + j;
      k_s[s] = (r < HK && c < HK) ? kb[((size_t)ci * HK + r) * HK + c] : 0.f;
    }
    for (int s = tid; s < 25 * 64; s += 256) {
      const int w = s & 63, ij = s >> 6;
      const int i = ij / 5, j = ij % 5;
      const int gr = 4 * h + i, gc = 4 * w + j;
      q_s[s] = (gr < HQ && gc < HQ) ? qb[((size_t)ci * HQ + gr) * HQ + gc] : 0.f;
    }
    __syncthreads();
    #pragma unroll 5
    for (int ij = 0; ij < 25; ++ij) {
      const float4 q4 = *(const float4*)&q_s[ij * 64 + wt * 4];
      const float4* kp4 = (const float4*)&k_s[(ij * 16 + lt) * 16];
      const float4 k0 = kp4[0], k1 = kp4[1], k2 = kp4[2], k3 = kp4[3];
      const float kk[16] = {k0.x, k0.y, k0.z, k0.w, k1.x, k1.y, k1.z, k1.w,
                            k2.x, k2.y, k2.z, k2.w, k3.x, k3.y, k3.z, k3.w};
      const float qq[4] = {q4.x, q4.y, q4.z, q4.w};
      #pragma unroll
      for (int li = 0; li < 16; ++li)
        #pragma unroll
        for (int ww = 0; ww < 4; ++ww)
          acc[li][ww] = fmaf(kk[li], qq[ww], acc[li][ww]);
    }
  }

  const float f = kscale[n];
  #pragma unroll
  for (int li = 0; li < 16; ++li)
    #pragma unroll
    for (int ww = 0; ww < 4; ++ww) acc[li][ww] *= f;

  #pragma unroll
  for (int ww = 0; ww < 4; ++ww) {
    float m = acc[0][ww];
    #pragma unroll
    for (int li = 1; li < 16; ++li) m = fmaxf(m, acc[li][ww]);
    red[(wt * 4 + ww) * 17 + lt] = m;
  }
  __syncthreads();
  if (tid < 64) {
    float m = red[tid * 17];
    #pragma unroll
    for (int k = 1; k < 16; ++k) m = fmaxf(m, red[tid * 17 + k]);
    red[tid * 17 + 16] = m;
  }
  __syncthreads();
  float sloc[4];
  #pragma unroll
  for (int ww = 0; ww < 4; ++ww) {
    const float m = red[(wt * 4 + ww) * 17 + 16];
    float s = 0.f;
    #pragma unroll
    for (int li = 0; li < 16; ++li) {
      const float e = __expf(acc[li][ww] - m);
      acc[li][ww] = e;
      s += e;
    }
    sloc[ww] = s;
  }
  __syncthreads();
  #pragma unroll
  for (int ww = 0; ww < 4; ++ww) red[(wt * 4 + ww) * 17 + lt] = sloc[ww];
  __syncthreads();
  if (tid < 64) {
    float s = red[tid * 17];
    #pragma unroll
    for (int k = 1; k < 16; ++k) s += red[tid * 17 + k];
    red[tid * 17 + 16] = s;
  }
  __syncthreads();
  #pragma unroll
  for (int ww = 0; ww < 4; ++ww) {
    const int w = wt * 4 + ww;
    const float inv = 1.0f / red[w * 17 + 16];
    float* dst = wn + (((size_t)(n * 64 + h) * 64 + w) * 256) + lt * 16;
    #pragma unroll
    for (int q = 0; q < 4; ++q) {
      float4 o = make_float4(acc[q * 4 + 0][ww] * inv, acc[q * 4 + 1][ww] * inv,
                             acc[q * 4 + 2][ww] * inv, acc[q * 4 + 3][ww] * inv);
      *(float4*)(dst + q * 4) = o;
    }
  }
}

// ---------------- v-patch matrix gather ----------------
__global__ void vp_gather(const float* __restrict__ vfea, float* __restrict__ vp) {
  const int bij = blockIdx.x * 256 + threadIdx.x;
  const int l = blockIdx.y, n = blockIdx.z;
  if (bij >= NPAD) return;
  const int ij = bij >> 6, b = bij & 63;
  float val = 0.f;
  if (ij < 25) {
    const int i = ij / 5, j = ij % 5;
    const int ly = l >> 4, lx = l & 15;
    const int r = 4 * ly + i, c = 4 * lx + j;
    if (r < HK && c < HK) val = vfea[((size_t)(n * COC + b) * HK + r) * HK + c];
  }
  vp[((size_t)(n * LL + l)) * NPAD + bij] = val;
}

// ---------------- PV GEMM (z = batch) ----------------
__global__ __launch_bounds__(256) void pv_gemm(
    const float* __restrict__ A0, const float* __restrict__ B0, float* __restrict__ C0) {
  const int nz = blockIdx.z;
  const float* A = A0 + (size_t)nz * 4096 * 256;
  const float* Bm = B0 + (size_t)nz * LL * NPAD;
  float* C = C0 + (size_t)nz * 4096 * NPAD;
  const int m0 = blockIdx.x * 128;
  const int n0 = blockIdx.y * 128;
  const int tid = threadIdx.x;
  const int tm = tid & 15, tn = tid >> 4;
  __shared__ float As[16][132];
  __shared__ float Bs[16][128];
  float acc[8][8];
  #pragma unroll
  for (int a = 0; a < 8; ++a)
    #pragma unroll
    for (int b = 0; b < 8; ++b) acc[a][b] = 0.f;

  for (int k0 = 0; k0 < 256; k0 += 16) {
    __syncthreads();
    #pragma unroll
    for (int r = 0; r < 2; ++r) {
      const int idx = tid + r * 256;
      const int row = idx >> 2, c4 = idx & 3;
      const float4 v = *(const float4*)&A[(size_t)(m0 + row) * 256 + k0 + c4 * 4];
      As[c4 * 4 + 0][row] = v.x;
      As[c4 * 4 + 1][row] = v.y;
      As[c4 * 4 + 2][row] = v.z;
      As[c4 * 4 + 3][row] = v.w;
    }
    #pragma unroll
    for (int r = 0; r < 2; ++r) {
      const int idx = tid + r * 256;
      const int row = idx >> 5, c4 = idx & 31;
      *(float4*)&Bs[row][c4 * 4] = *(const float4*)&Bm[(size_t)(k0 + row) * NPAD + n0 + c4 * 4];
    }
    __syncthreads();
    #pragma unroll
    for (int k = 0; k < 16; ++k) {
      const float4 a0 = *(const float4*)&As[k][tm * 8];
      const float4 a1 = *(const float4*)&As[k][tm * 8 + 4];
      const float4 b0 = *(const float4*)&Bs[k][tn * 8];
      const float4 b1 = *(const float4*)&Bs[k][tn * 8 + 4];
      const float av[8] = {a0.x, a0.y, a0.z, a0.w, a1.x, a1.y, a1.z, a1.w};
      const float bv[8] = {b0.x, b0.y, b0.z, b0.w, b1.x, b1.y, b1.z, b1.w};
      #pragma unroll
      for (int mi = 0; mi < 8; ++mi)
        #pragma unroll
        for (int ni = 0; ni < 8; ++ni)
          acc[mi][ni] = fmaf(av[mi], bv[ni], acc[mi][ni]);
    }
  }
  #pragma unroll
  for (int mi = 0; mi < 8; ++mi) {
    float* dst = &C[(size_t)(m0 + tm * 8 + mi) * NPAD + n0 + tn * 8];
    *(float4*)dst = make_float4(acc[mi][0], acc[mi][1], acc[mi][2], acc[mi][3]);
    *(float4*)(dst + 4) = make_float4(acc[mi][4], acc[mi][5], acc[mi][6], acc[mi][7]);
  }
}

// ---------------- conv-transpose contribution gather (+ /6), writes padded res ----------------
__global__ __launch_bounds__(256) void u_scatter(
    const float* __restrict__ U0, float* __restrict__ resp, int n0) {
  const int n = n0 + blockIdx.z;
  const float* U = U0 + (size_t)blockIdx.z * 4096 * NPAD;
  const int y = blockIdx.y;
  const int xt = blockIdx.x;
  const int tid = threadIdx.x;
  __shared__ float t_lds[64][65];
  const int ym = (y + 1) >> 2, yr = (y + 1) & 3;
  const bool v0 = (ym < 64);
  const bool v1 = (yr == 0 && ym >= 1);
  const int b = tid & 63, xg = tid >> 6;
  for (int xi = 0; xi < 16; ++xi) {
    const int x = xt * 64 + xg * 16 + xi;
    const int xm = (x + 1) >> 2, xr = (x + 1) & 3;
    const bool u0 = (xm < 64);
    const bool u1 = (xr == 0 && xm >= 1);
    float s = 0.f;
    if (v0) {
      const size_t rb = (size_t)(ym * 64) * NPAD;
      if (u0) s += U[rb + (size_t)xm * NPAD + (yr * 5 + xr) * 64 + b];
      if (u1) s += U[rb + (size_t)(xm - 1) * NPAD + (yr * 5 + 4) * 64 + b];
    }
    if (v1) {
      const size_t rb = (size_t)((ym - 1) * 64) * NPAD;
      if (u0) s += U[rb + (size_t)xm * NPAD + (4 * 5 + xr) * 64 + b];
      if (u1) s += U[rb + (size_t)(xm - 1) * NPAD + (4 * 5 + 4) * 64 + b];
    }
    t_lds[xg * 16 + xi][b] = s * (1.0f / 6.0f);
  }
  __syncthreads();
  const int xl = tid & 63, bg = tid >> 6;
  for (int bb = 0; bb < 16; ++bb) {
    const int bc = bg * 16 + bb;
    resp[((size_t)(n * COC + bc) * 258 + y + 1) * 264 + xt * 64 + xl + 1] = t_lds[xl][bc];
  }
}

extern "C" void kernel_launch(void* const* d_in, const int* in_sizes, int n_in,
                              void* d_out, int out_size, void* d_ws, size_t ws_size,
                              hipStream_t stream) {
  const float* ms   = (const float*)d_in[0];
  const float* pan  = (const float*)d_in[1];
  const float* pan2 = (const float*)d_in[2];
  const float* Wq   = (const float*)d_in[3];
  const float* bq   = (const float*)d_in[4];
  const float* Wk   = (const float*)d_in[5];
  const float* bk   = (const float*)d_in[6];
  const float* Wv   = (const float*)d_in[7];
  const float* bv   = (const float*)d_in[8];
  const float* Wr   = (const float*)d_in[9];
  const float* br   = (const float*)d_in[10];
  float* out = (float*)d_out;

  float* ws = (float*)d_ws;
  const size_t SZ_Q   = (size_t)NB * COC * HQ * HQ;          // 33.55M
  const size_t SZ_K   = (size_t)NB * CI * HK * HK;           // 2.10M
  const size_t SZ_WN  = (size_t)NB * 64 * 64 * LL;           // 8.39M
  const size_t SZ_VP  = (size_t)NB * LL * NPAD;              // 3.41M
  const size_t SZ_PS  = (size_t)NB * CI * 66 * 72;           // 2.43M (small padded)
  const size_t SZ_U1  = (size_t)4096 * NPAD;                 // 6.82M per batch
  const size_t SZ_UA  = (size_t)NB * SZ_U1;                  // 54.53M

  float* q_fea   = ws;                    // also res_pad (aliased)
  float* k_fea   = q_fea + SZ_Q;
  float* v_fea   = k_fea + SZ_K;
  float* wn      = v_fea + SZ_K;
  float* vp      = wn + SZ_WN;
  float* norms   = vp + SZ_VP;
  float* kscale  = norms + NB * LL;
  float* wtq     = kscale + 64;
  float* wtk     = wtq + 36864;
  float* wtv     = wtk + 36864;
  float* wtr     = wtv + 36864;
  float* ms_pad  = wtr + 36864;
  float* pan2pad = ms_pad + SZ_PS;
  float* shared_blk = pan2pad + SZ_PS;    // pan_pad, later U
  float* pan_pad = shared_blk;
  float* U       = shared_blk;
  float* res_pad = q_fea;

  const size_t base_elems = (size_t)(shared_blk - ws);
  const bool batched = ws_size >= (base_elems + SZ_UA) * sizeof(float);

  // weight transposes
  wtrans8_kernel<<<dim3(9, 64), 64, 0, stream>>>(Wq, wtq);
  wtrans8_kernel<<<dim3(9, 64), 64, 0, stream>>>(Wk, wtk);
  wtrans8_kernel<<<dim3(9, 64), 64, 0, stream>>>(Wv, wtv);
  wtrans8_kernel<<<dim3(9, 64), 64, 0, stream>>>(Wr, wtr);

  // pad inputs
  {
    const int totB = NB * CI * HQ * HQ;
    pad_copy<<<dim3((totB + 255) / 256), 256, 0, stream>>>(pan, pan_pad, HQ, HQ, 264, totB);
    const int totS = NB * CI * HK * HK;
    pad_copy<<<dim3((totS + 255) / 256), 256, 0, stream>>>(ms, ms_pad, HK, HK, 72, totS);
    pad_copy<<<dim3((totS + 255) / 256), 256, 0, stream>>>(pan2, pan2pad, HK, HK, 72, totS);
    border_zero<<<dim3(NB * CI), 256, 0, stream>>>(pan_pad, HQ, HQ, 264);
    border_zero<<<dim3(NB * CI), 256, 0, stream>>>(ms_pad, HK, HK, 72);
    border_zero<<<dim3(NB * CI), 256, 0, stream>>>(pan2pad, HK, HK, 72);
  }

  // feature convs
  conv3s<<<dim3(HK / 64, HK / 8, NB * 8), 256, 0, stream>>>(pan2pad, wtk, bk, k_fea, HK, HK, 72);
  conv3s<<<dim3(HK / 64, HK / 8, NB * 8), 256, 0, stream>>>(ms_pad,  wtv, bv, v_fea, HK, HK, 72);
  conv3s<<<dim3(HQ / 64, HQ / 8, NB * 8), 256, 0, stream>>>(pan_pad, wtq, bq, q_fea, HQ, HQ, 264);

  // k-patch max norm -> scale
  knorm_kernel<<<dim3(LL, NB), 64, 0, stream>>>(k_fea, norms);
  kscale_kernel<<<NB, 256, 0, stream>>>(norms, kscale);

  // attention weights (reads q_fea, k_fea -- both dead afterwards)
  qk_softmax<<<dim3(64, NB), 256, 0, stream>>>(q_fea, k_fea, kscale, wn);

  // res_pad borders (aliases q_fea/k_fea; must be after qk_softmax)
  border_zero<<<dim3(NB * CI), 256, 0, stream>>>(res_pad, HQ, HQ, 264);

  // v patch matrix
  vp_gather<<<dim3((NPAD + 255) / 256, LL, NB), 256, 0, stream>>>(v_fea, vp);

  // PV GEMM + conv-transpose gather (U aliases pan_pad; pan_pad dead after q conv)
  if (batched) {
    pv_gemm<<<dim3(32, 13, NB), 256, 0, stream>>>(wn, vp, U);
    u_scatter<<<dim3(4, HQ, NB), 256, 0, stream>>>(U, res_pad, 0);
  } else {
    for (int n = 0; n < NB; ++n) {
      pv_gemm<<<dim3(32, 13, 1), 256, 0, stream>>>(wn + (size_t)n * 4096 * 256,
                                                   vp + (size_t)n * LL * NPAD, U);
      u_scatter<<<dim3(4, HQ, 1), 256, 0, stream>>>(U, res_pad, n);
    }
  }

  // final conv (reads padded res)
  conv3s<<<dim3(HQ / 64, HQ / 8, NB * 8), 256, 0, stream>>>(res_pad, wtr, br, out, HQ, HQ, 264);
}

// Round 8
// 2252.090 us; speedup vs baseline: 3.1012x; 1.1210x over previous
//
#include <hip/hip_runtime.h>
#include <math.h>

#define NB   8
#define CI   64
#define COC  64
#define HQ   256
#define HK   64
#define KS   5
#define LL   256
#define NPAD 1664
#define QPS  (257 * 264)   // q padded plane stride (floats)

// ---------------- weight transpose: [CO][CI][3][3] -> [cogrp8][CI][tap][8] ----------------
__global__ void wtrans8_kernel(const float* __restrict__ Wt, float* __restrict__ Wo) {
  const int co = threadIdx.x;
  const int tap = blockIdx.x;
  const int ci = blockIdx.y;
  Wo[(((co >> 3) * 64 + ci) * 9 + tap) * 8 + (co & 7)] = Wt[(co * 64 + ci) * 9 + tap];
}

// ---------------- pad copy ----------------
__global__ void pad_copy(const float* __restrict__ src, float* __restrict__ dst,
                         int H, int W, int S, int total) {
  const int idx = blockIdx.x * 256 + threadIdx.x;
  if (idx >= total) return;
  const int p = idx / (H * W);
  const int rem = idx - p * H * W;
  const int y = rem / W, x = rem - y * W;
  dst[((size_t)p * (H + 2) + y + 1) * S + x + 1] = src[idx];
}

__global__ void border_zero(float* __restrict__ dst, int H, int W, int S) {
  const int p = blockIdx.x;
  float* b = dst + (size_t)p * (H + 2) * S;
  for (int c = threadIdx.x; c < S; c += 256) {
    b[c] = 0.f;
    b[(size_t)(H + 1) * S + c] = 0.f;
  }
  for (int r = 1 + threadIdx.x; r <= H; r += 256) {
    b[(size_t)r * S] = 0.f;
    b[(size_t)r * S + W + 1] = 0.f;
  }
}

// zero the same-pad strips of q_pad: row 256 and col 256 of each [257][264] plane
__global__ void qpad_zero(float* __restrict__ q) {
  float* p = q + (size_t)blockIdx.x * QPS;
  for (int c = threadIdx.x; c < 264; c += 256) p[256 * 264 + c] = 0.f;
  for (int r = threadIdx.x; r < 256; r += 256) p[r * 264 + 256] = 0.f;
}

// ---------------- conv 3x3 pad1 + bias + leaky relu (low-register) ----------------
// block 64x X 8y X 8co; grid (W/64, H/8, NB*8). outPS/outRS generalize output layout.
__global__ __launch_bounds__(256) void conv3s(
    const float* __restrict__ inp /*padded [(H+2)][S]*/,
    const float* __restrict__ Wts /*[cogrp8][CI][9][8]*/,
    const float* __restrict__ bias, float* __restrict__ out,
    int H, int Wd, int S, int outPS, int outRS) {
  const int x0 = blockIdx.x * 64;
  const int y0 = blockIdx.y * 8;
  const int z  = blockIdx.z;
  const int n  = z >> 3;
  const int cog = z & 7;
  const int tid = threadIdx.x;
  const int xq = tid & 15;
  const int yt = (tid >> 4) & 7;
  const int cg = tid >> 7;
  const int Hp = H + 2;

  __shared__ float in_s[10 * 72];
  __shared__ float w_s[CI * 9 * 8];

  {
    const float* wbase = Wts + (size_t)cog * (CI * 9 * 8);
    for (int idx = tid; idx < CI * 9 * 2; idx += 256)
      *(float4*)&w_s[idx * 4] = *(const float4*)(wbase + idx * 4);
  }

  float acc[4][4];
  #pragma unroll
  for (int a = 0; a < 4; ++a)
    #pragma unroll
    for (int b = 0; b < 4; ++b) acc[a][b] = 0.f;

  const bool hasA = tid < 180;
  const int arow = tid / 18, ac4 = tid - arow * 18;
  const float* gplane0 = inp + (size_t)(n * CI) * Hp * S;
  const size_t aoff = ((size_t)(y0 + arow)) * S + x0 + ac4 * 4;

  float4 sA = make_float4(0.f, 0.f, 0.f, 0.f);
  if (hasA) sA = *(const float4*)(gplane0 + aoff);

  for (int ci = 0; ci < CI; ++ci) {
    __syncthreads();
    if (hasA) *(float4*)&in_s[arow * 72 + ac4 * 4] = sA;
    if (ci + 1 < CI && hasA)
      sA = *(const float4*)(gplane0 + (size_t)(ci + 1) * Hp * S + aoff);
    __syncthreads();

    float xin[3][8];
    const int cb = xq * 4;
    #pragma unroll
    for (int r = 0; r < 3; ++r) {
      const float4 xa = *(const float4*)&in_s[(yt + r) * 72 + cb];
      const float4 xb = *(const float4*)&in_s[(yt + r) * 72 + cb + 4];
      xin[r][0] = xa.x; xin[r][1] = xa.y; xin[r][2] = xa.z; xin[r][3] = xa.w;
      xin[r][4] = xb.x; xin[r][5] = xb.y; xin[r][6] = xb.z; xin[r][7] = xb.w;
    }

    const float* wci = &w_s[(ci * 9) * 8 + cg * 4];
    #pragma unroll
    for (int ky = 0; ky < 3; ++ky) {
      #pragma unroll
      for (int kx = 0; kx < 3; ++kx) {
        const float4 w4 = *(const float4*)&wci[(ky * 3 + kx) * 8];
        const float wv[4] = {w4.x, w4.y, w4.z, w4.w};
        #pragma unroll
        for (int c = 0; c < 4; ++c)
          #pragma unroll
          for (int dx = 0; dx < 4; ++dx)
            acc[c][dx] = fmaf(wv[c], xin[ky][dx + kx], acc[c][dx]);
      }
    }
  }

  #pragma unroll
  for (int c = 0; c < 4; ++c) {
    const int co = cog * 8 + cg * 4 + c;
    const float bv = bias[co];
    float4 o;
    float t;
    t = acc[c][0] + bv; o.x = t > 0.f ? t : 0.01f * t;
    t = acc[c][1] + bv; o.y = t > 0.f ? t : 0.01f * t;
    t = acc[c][2] + bv; o.z = t > 0.f ? t : 0.01f * t;
    t = acc[c][3] + bv; o.w = t > 0.f ? t : 0.01f * t;
    *(float4*)(out + (size_t)(n * COC + co) * outPS + (size_t)(y0 + yt) * outRS + x0 + xq * 4) = o;
  }
}

// ---------------- k-patch squared norms ----------------
__global__ void knorm_kernel(const float* __restrict__ kfea, float* __restrict__ norms) {
  const int l = blockIdx.x, n = blockIdx.y, c = threadIdx.x;
  const int ly = l >> 4, lx = l & 15;
  const float* base = kfea + ((size_t)(n * CI + c) * HK) * HK;
  float ss = 0.f;
  #pragma unroll
  for (int i = 0; i < KS; ++i) {
    const int r = 4 * ly + i;
    if (r >= HK) continue;
    #pragma unroll
    for (int j = 0; j < KS; ++j) {
      const int cc = 4 * lx + j;
      if (cc >= HK) continue;
      const float v = base[r * HK + cc];
      ss = fmaf(v, v, ss);
    }
  }
  for (int off = 32; off; off >>= 1) ss += __shfl_down(ss, off);
  if (c == 0) norms[n * LL + l] = ss;
}

__global__ void kscale_kernel(const float* __restrict__ norms, float* __restrict__ kscale) {
  const int n = blockIdx.x, t = threadIdx.x;
  float v = norms[n * LL + t];
  for (int off = 32; off; off >>= 1) v = fmaxf(v, __shfl_down(v, off));
  __shared__ float red[4];
  if ((t & 63) == 0) red[t >> 6] = v;
  __syncthreads();
  if (t == 0) {
    const float m = fmaxf(fmaxf(red[0], red[1]), fmaxf(red[2], red[3]));
    kscale[n] = 10.0f / sqrtf(m);
  }
}

// ---------------- K im2col gather (kscale folded, XOR-swizzled slots) ----------------
// kp[(n*64+ci)*6400 + ij*256 + swz(l)], grid (25, 64, 8), block 256
__global__ void kp_gather(const float* __restrict__ kfea, const float* __restrict__ kscale,
                          float* __restrict__ kp) {
  const int l = threadIdx.x;
  const int ij = blockIdx.x, ci = blockIdx.y, n = blockIdx.z;
  const int i = ij / 5, j = ij % 5;
  const int lt = l >> 4, li = l & 15;
  const int r = 4 * lt + i, c = 4 * (li) + j;   // NOTE: row from l>>4, col from l&15
  float v = 0.f;
  if (r < HK && c < HK) v = kfea[((size_t)(n * CI + ci) * HK + r) * HK + c];
  v *= kscale[n];
  const int r2 = li >> 2, e = li & 3;
  const int slot = (lt * 4 + r2) ^ (lt >> 1);
  kp[((size_t)(n * CI + ci) * 25 + ij) * 256 + slot * 4 + e] = v;
}

// ---------------- QK partial scores: 128 thr, acc[16 l][8 w], ci-half split ----------------
// grid (64 h, 2 cih, 8 n); sc[cih][n][h][w][l] raw partial scores
__global__ __launch_bounds__(128, 2) void qk_scores(
    const float* __restrict__ qpad, const float* __restrict__ kp,
    float* __restrict__ scores, size_t half_stride) {
  const int h = blockIdx.x, cih = blockIdx.y, n = blockIdx.z;
  const int tid = threadIdx.x;
  const int lt = tid & 15;   // l group: l = lt*16 + li
  const int wt = tid >> 4;   // 0..7:  w = wt*8 + wi
  __shared__ float k_s[25 * 256];
  __shared__ float q_s[25 * 64];

  // precomputed swizzled k read offsets (floats)
  int koff[4];
  #pragma unroll
  for (int r2 = 0; r2 < 4; ++r2) koff[r2] = (((lt * 4 + r2) ^ (lt >> 1)) << 2);

  float acc[16][8];
  #pragma unroll
  for (int a = 0; a < 16; ++a)
    #pragma unroll
    for (int b = 0; b < 8; ++b) acc[a][b] = 0.f;

  const float* qn = qpad + (size_t)(n * CI + cih * 32) * QPS + (size_t)(4 * h) * 264;
  const float* kpb = kp + ((size_t)(n * CI + cih * 32)) * 6400;

  for (int cc = 0; cc < 32; ++cc) {
    __syncthreads();
    // stage K: 1600 float4, pre-swizzled linear copy
    const float4* ksrc = (const float4*)(kpb + (size_t)cc * 6400);
    #pragma unroll
    for (int it = 0; it < 13; ++it) {
      const int idx = tid + it * 128;
      if (idx < 1600) *(float4*)&k_s[idx * 4] = ksrc[idx];
    }
    // stage Q: im2col from padded plane (no bounds checks)
    const float* qp = qn + (size_t)cc * QPS;
    #pragma unroll
    for (int it = 0; it < 13; ++it) {
      const int s = tid + it * 128;
      if (s < 1600) {
        const int ij = s >> 6, w = s & 63;
        const int i = (ij * 205) >> 10;
        const int j = ij - 5 * i;
        q_s[s] = qp[i * 264 + 4 * w + j];
      }
    }
    __syncthreads();

    #pragma unroll 5
    for (int ij = 0; ij < 25; ++ij) {
      const float* kb = &k_s[ij * 256];
      float kk[16];
      #pragma unroll
      for (int r2 = 0; r2 < 4; ++r2) {
        const float4 kv = *(const float4*)(kb + koff[r2]);
        kk[r2 * 4 + 0] = kv.x; kk[r2 * 4 + 1] = kv.y;
        kk[r2 * 4 + 2] = kv.z; kk[r2 * 4 + 3] = kv.w;
      }
      const float4 q0 = *(const float4*)&q_s[ij * 64 + wt * 8];
      const float4 q1 = *(const float4*)&q_s[ij * 64 + wt * 8 + 4];
      const float qq[8] = {q0.x, q0.y, q0.z, q0.w, q1.x, q1.y, q1.z, q1.w};
      #pragma unroll
      for (int li = 0; li < 16; ++li)
        #pragma unroll
        for (int wi = 0; wi < 8; ++wi)
          acc[li][wi] = fmaf(kk[li], qq[wi], acc[li][wi]);
    }
  }

  float* dst = scores + (size_t)cih * half_stride + ((size_t)(n * 64 + h) * 64) * 256;
  #pragma unroll
  for (int wi = 0; wi < 8; ++wi) {
    float* d2 = dst + (size_t)(wt * 8 + wi) * 256 + lt * 16;
    #pragma unroll
    for (int r2 = 0; r2 < 4; ++r2) {
      *(float4*)(d2 + r2 * 4) = make_float4(acc[r2 * 4 + 0][wi], acc[r2 * 4 + 1][wi],
                                            acc[r2 * 4 + 2][wi], acc[r2 * 4 + 3][wi]);
    }
  }
}

// ---------------- softmax over l (sums the two ci-half partials) ----------------
// grid (8192), block 256: 4 rows (of 32768) per block, one wave per row
__global__ void softmax_rows(const float* __restrict__ sa, const float* __restrict__ sb,
                             float* __restrict__ wn) {
  const int row = blockIdx.x * 4 + (threadIdx.x >> 6);
  const int lane = threadIdx.x & 63;
  const size_t idx = (size_t)row * 64 + lane;
  const float4 a = ((const float4*)sa)[idx];
  const float4 b = ((const float4*)sb)[idx];
  float4 v = make_float4(a.x + b.x, a.y + b.y, a.z + b.z, a.w + b.w);
  float m = fmaxf(fmaxf(v.x, v.y), fmaxf(v.z, v.w));
  for (int off = 32; off; off >>= 1) m = fmaxf(m, __shfl_xor(m, off));
  float4 e;
  e.x = __expf(v.x - m); e.y = __expf(v.y - m);
  e.z = __expf(v.z - m); e.w = __expf(v.w - m);
  float s = e.x + e.y + e.z + e.w;
  for (int off = 32; off; off >>= 1) s += __shfl_xor(s, off);
  const float inv = 1.0f / s;
  ((float4*)wn)[idx] = make_float4(e.x * inv, e.y * inv, e.z * inv, e.w * inv);
}

// ---------------- v-patch matrix gather ----------------
__global__ void vp_gather(const float* __restrict__ vfea, float* __restrict__ vp) {
  const int bij = blockIdx.x * 256 + threadIdx.x;
  const int l = blockIdx.y, n = blockIdx.z;
  if (bij >= NPAD) return;
  const int ij = bij >> 6, b = bij & 63;
  float val = 0.f;
  if (ij < 25) {
    const int i = ij / 5, j = ij % 5;
    const int ly = l >> 4, lx = l & 15;
    const int r = 4 * ly + i, c = 4 * lx + j;
    if (r < HK && c < HK) val = vfea[((size_t)(n * COC + b) * HK + r) * HK + c];
  }
  vp[((size_t)(n * LL + l)) * NPAD + bij] = val;
}

// ---------------- PV GEMM (z = batch) ----------------
__global__ __launch_bounds__(256) void pv_gemm(
    const float* __restrict__ A0, const float* __restrict__ B0, float* __restrict__ C0) {
  const int nz = blockIdx.z;
  const float* A = A0 + (size_t)nz * 4096 * 256;
  const float* Bm = B0 + (size_t)nz * LL * NPAD;
  float* C = C0 + (size_t)nz * 4096 * NPAD;
  const int m0 = blockIdx.x * 128;
  const int n0 = blockIdx.y * 128;
  const int tid = threadIdx.x;
  const int tm = tid & 15, tn = tid >> 4;
  __shared__ float As[16][132];
  __shared__ float Bs[16][128];
  float acc[8][8];
  #pragma unroll
  for (int a = 0; a < 8; ++a)
    #pragma unroll
    for (int b = 0; b < 8; ++b) acc[a][b] = 0.f;

  for (int k0 = 0; k0 < 256; k0 += 16) {
    __syncthreads();
    #pragma unroll
    for (int r = 0; r < 2; ++r) {
      const int idx = tid + r * 256;
      const int row = idx >> 2, c4 = idx & 3;
      const float4 v = *(const float4*)&A[(size_t)(m0 + row) * 256 + k0 + c4 * 4];
      As[c4 * 4 + 0][row] = v.x;
      As[c4 * 4 + 1][row] = v.y;
      As[c4 * 4 + 2][row] = v.z;
      As[c4 * 4 + 3][row] = v.w;
    }
    #pragma unroll
    for (int r = 0; r < 2; ++r) {
      const int idx = tid + r * 256;
      const int row = idx >> 5, c4 = idx & 31;
      *(float4*)&Bs[row][c4 * 4] = *(const float4*)&Bm[(size_t)(k0 + row) * NPAD + n0 + c4 * 4];
    }
    __syncthreads();
    #pragma unroll
    for (int k = 0; k < 16; ++k) {
      const float4 a0 = *(const float4*)&As[k][tm * 8];
      const float4 a1 = *(const float4*)&As[k][tm * 8 + 4];
      const float4 b0 = *(const float4*)&Bs[k][tn * 8];
      const float4 b1 = *(const float4*)&Bs[k][tn * 8 + 4];
      const float av[8] = {a0.x, a0.y, a0.z, a0.w, a1.x, a1.y, a1.z, a1.w};
      const float bv[8] = {b0.x, b0.y, b0.z, b0.w, b1.x, b1.y, b1.z, b1.w};
      #pragma unroll
      for (int mi = 0; mi < 8; ++mi)
        #pragma unroll
        for (int ni = 0; ni < 8; ++ni)
          acc[mi][ni] = fmaf(av[mi], bv[ni], acc[mi][ni]);
    }
  }
  #pragma unroll
  for (int mi = 0; mi < 8; ++mi) {
    float* dst = &C[(size_t)(m0 + tm * 8 + mi) * NPAD + n0 + tn * 8];
    *(float4*)dst = make_float4(acc[mi][0], acc[mi][1], acc[mi][2], acc[mi][3]);
    *(float4*)(dst + 4) = make_float4(acc[mi][4], acc[mi][5], acc[mi][6], acc[mi][7]);
  }
}

// ---------------- conv-transpose contribution gather (+ /6), writes padded res ----------------
__global__ __launch_bounds__(256) void u_scatter(
    const float* __restrict__ U0, float* __restrict__ resp, int n0) {
  const int n = n0 + blockIdx.z;
  const float* U = U0 + (size_t)blockIdx.z * 4096 * NPAD;
  const int y = blockIdx.y;
  const int xt = blockIdx.x;
  const int tid = threadIdx.x;
  __shared__ float t_lds[64][65];
  const int ym = (y + 1) >> 2, yr = (y + 1) & 3;
  const bool v0 = (ym < 64);
  const bool v1 = (yr == 0 && ym >= 1);
  const int b = tid & 63, xg = tid >> 6;
  for (int xi = 0; xi < 16; ++xi) {
    const int x = xt * 64 + xg * 16 + xi;
    const int xm = (x + 1) >> 2, xr = (x + 1) & 3;
    const bool u0 = (xm < 64);
    const bool u1 = (xr == 0 && xm >= 1);
    float s = 0.f;
    if (v0) {
      const size_t rb = (size_t)(ym * 64) * NPAD;
      if (u0) s += U[rb + (size_t)xm * NPAD + (yr * 5 + xr) * 64 + b];
      if (u1) s += U[rb + (size_t)(xm - 1) * NPAD + (yr * 5 + 4) * 64 + b];
    }
    if (v1) {
      const size_t rb = (size_t)((ym - 1) * 64) * NPAD;
      if (u0) s += U[rb + (size_t)xm * NPAD + (4 * 5 + xr) * 64 + b];
      if (u1) s += U[rb + (size_t)(xm - 1) * NPAD + (4 * 5 + 4) * 64 + b];
    }
    t_lds[xg * 16 + xi][b] = s * (1.0f / 6.0f);
  }
  __syncthreads();
  const int xl = tid & 63, bg = tid >> 6;
  for (int bb = 0; bb < 16; ++bb) {
    const int bc = bg * 16 + bb;
    resp[((size_t)(n * COC + bc) * 258 + y + 1) * 264 + xt * 64 + xl + 1] = t_lds[xl][bc];
  }
}

extern "C" void kernel_launch(void* const* d_in, const int* in_sizes, int n_in,
                              void* d_out, int out_size, void* d_ws, size_t ws_size,
                              hipStream_t stream) {
  const float* ms   = (const float*)d_in[0];
  const float* pan  = (const float*)d_in[1];
  const float* pan2 = (const float*)d_in[2];
  const float* Wq   = (const float*)d_in[3];
  const float* bq   = (const float*)d_in[4];
  const float* Wk   = (const float*)d_in[5];
  const float* bk   = (const float*)d_in[6];
  const float* Wv   = (const float*)d_in[7];
  const float* bv   = (const float*)d_in[8];
  const float* Wr   = (const float*)d_in[9];
  const float* br   = (const float*)d_in[10];
  float* out = (float*)d_out;

  float* ws = (float*)d_ws;
  const size_t SZ_QP  = (size_t)NB * CI * QPS;               // 34.74M (q padded)
  const size_t SZ_K   = (size_t)NB * CI * HK * HK;           // 2.10M
  const size_t SZ_WN  = (size_t)NB * 64 * 64 * LL;           // 8.39M
  const size_t SZ_VP  = (size_t)NB * LL * NPAD;              // 3.41M
  const size_t SZ_KP  = (size_t)NB * CI * 25 * 256;          // 3.28M
  const size_t SZ_PS  = (size_t)NB * CI * 66 * 72;           // 2.43M
  const size_t SZ_U1  = (size_t)4096 * NPAD;                 // 6.82M per batch
  const size_t SZ_UA  = (size_t)NB * SZ_U1;                  // 54.53M

  float* q_pad   = ws;                    // [n][ci][257][264]; later res_pad
  float* k_fea   = q_pad + SZ_QP;
  float* v_fea   = k_fea + SZ_K;
  float* wn      = v_fea + SZ_K;
  float* vp      = wn + SZ_WN;
  float* kp      = vp + SZ_VP;
  float* norms   = kp + SZ_KP;
  float* kscale  = norms + NB * LL;
  float* wtq     = kscale + 64;
  float* wtk     = wtq + 36864;
  float* wtv     = wtk + 36864;
  float* wtr     = wtv + 36864;
  float* ms_pad  = wtr + 36864;
  float* pan2pad = ms_pad + SZ_PS;
  float* shared_blk = pan2pad + SZ_PS;    // pan_pad -> scores -> U
  float* pan_pad = shared_blk;
  float* scores  = shared_blk;
  float* U       = shared_blk;
  float* res_pad = q_pad;

  const size_t base_elems = (size_t)(shared_blk - ws);
  const bool batched = ws_size >= (base_elems + SZ_UA) * sizeof(float);

  // weight transposes
  wtrans8_kernel<<<dim3(9, 64), 64, 0, stream>>>(Wq, wtq);
  wtrans8_kernel<<<dim3(9, 64), 64, 0, stream>>>(Wk, wtk);
  wtrans8_kernel<<<dim3(9, 64), 64, 0, stream>>>(Wv, wtv);
  wtrans8_kernel<<<dim3(9, 64), 64, 0, stream>>>(Wr, wtr);

  // pad inputs
  {
    const int totB = NB * CI * HQ * HQ;
    pad_copy<<<dim3((totB + 255) / 256), 256, 0, stream>>>(pan, pan_pad, HQ, HQ, 264, totB);
    const int totS = NB * CI * HK * HK;
    pad_copy<<<dim3((totS + 255) / 256), 256, 0, stream>>>(ms, ms_pad, HK, HK, 72, totS);
    pad_copy<<<dim3((totS + 255) / 256), 256, 0, stream>>>(pan2, pan2pad, HK, HK, 72, totS);
    border_zero<<<dim3(NB * CI), 256, 0, stream>>>(pan_pad, HQ, HQ, 264);
    border_zero<<<dim3(NB * CI), 256, 0, stream>>>(ms_pad, HK, HK, 72);
    border_zero<<<dim3(NB * CI), 256, 0, stream>>>(pan2pad, HK, HK, 72);
    qpad_zero<<<dim3(NB * CI), 256, 0, stream>>>(q_pad);
  }

  // feature convs (q conv writes into padded layout)
  conv3s<<<dim3(HK / 64, HK / 8, NB * 8), 256, 0, stream>>>(pan2pad, wtk, bk, k_fea, HK, HK, 72, HK * HK, HK);
  conv3s<<<dim3(HK / 64, HK / 8, NB * 8), 256, 0, stream>>>(ms_pad,  wtv, bv, v_fea, HK, HK, 72, HK * HK, HK);
  conv3s<<<dim3(HQ / 64, HQ / 8, NB * 8), 256, 0, stream>>>(pan_pad, wtq, bq, q_pad, HQ, HQ, 264, QPS, 264);

  // k-patch max norm -> scale
  knorm_kernel<<<dim3(LL, NB), 64, 0, stream>>>(k_fea, norms);
  kscale_kernel<<<NB, 256, 0, stream>>>(norms, kscale);

  // K im2col (kscale folded, swizzled)
  kp_gather<<<dim3(25, CI, NB), 256, 0, stream>>>(k_fea, kscale, kp);

  // QK partial scores (2 ci-halves) + softmax
  qk_scores<<<dim3(64, 2, NB), 128, 0, stream>>>(q_pad, kp, scores, SZ_WN);
  softmax_rows<<<dim3(8192), 256, 0, stream>>>(scores, scores + SZ_WN, wn);

  // res_pad borders (aliases q_pad/k_fea; must be after qk/kp use of them)
  border_zero<<<dim3(NB * CI), 256, 0, stream>>>(res_pad, HQ, HQ, 264);

  // v patch matrix
  vp_gather<<<dim3((NPAD + 255) / 256, LL, NB), 256, 0, stream>>>(v_fea, vp);

  // PV GEMM + conv-transpose gather (U aliases scores region; scores dead after softmax)
  if (batched) {
    pv_gemm<<<dim3(32, 13, NB), 256, 0, stream>>>(wn, vp, U);
    u_scatter<<<dim3(4, HQ, NB), 256, 0, stream>>>(U, res_pad, 0);
  } else {
    for (int n = 0; n < NB; ++n) {
      pv_gemm<<<dim3(32, 13, 1), 256, 0, stream>>>(wn + (size_t)n * 4096 * 256,
                                                   vp + (size_t)n * LL * NPAD, U);
      u_scatter<<<dim3(4, HQ, 1), 256, 0, stream>>>(U, res_pad, n);
    }
  }

  // final conv (reads padded res)
  conv3s<<<dim3(HQ / 64, HQ / 8, NB * 8), 256, 0, stream>>>(res_pad, wtr, br, out, HQ, HQ, 264, HQ * HQ, HQ);
}

// Round 9
// 1198.431 us; speedup vs baseline: 5.8278x; 1.8792x over previous
//
#include <hip/hip_runtime.h>
#include <math.h>

#define NB   8
#define CI   64
#define COC  64
#define HQ   256
#define HK   64
#define KS   5
#define LL   256
#define NPAD 1664
#define QPS  (257 * 264)   // q padded plane stride (floats)

typedef __attribute__((ext_vector_type(8))) short bf16x8s;
typedef __attribute__((ext_vector_type(4))) float f32x4;

static __device__ __forceinline__ unsigned short f2bf(float f) {
  union { float f; unsigned u; } v; v.f = f;
  unsigned r = v.u + 0x7FFF + ((v.u >> 16) & 1);
  return (unsigned short)(r >> 16);
}

// ---------------- weight transpose for conv3s: [CO][CI][3][3] -> [cogrp8][CI][tap][8] ----------------
__global__ void wtrans8_kernel(const float* __restrict__ Wt, float* __restrict__ Wo) {
  const int co = threadIdx.x;
  const int tap = blockIdx.x;
  const int ci = blockIdx.y;
  Wo[(((co >> 3) * 64 + ci) * 9 + tap) * 8 + (co & 7)] = Wt[(co * 64 + ci) * 9 + tap];
}

// ---------------- weight image for conv3m: [18 chunk][64 co][40] bf16 ----------------
// chunk = tap*2 + cihalf; slot s<32 holds W[co][ci = cihalf*32+s][tap]
__global__ void wtrans_mfma(const float* __restrict__ Wt, unsigned short* __restrict__ wimg) {
  const int ch = blockIdx.x;
  const int tap = ch >> 1, cih = ch & 1;
  for (int idx = threadIdx.x; idx < 64 * 40; idx += 256) {
    const int co = idx / 40, s = idx - co * 40;
    unsigned short v = 0;
    if (s < 32) v = f2bf(Wt[((size_t)co * 64 + cih * 32 + s) * 9 + tap]);
    wimg[(size_t)ch * 64 * 40 + idx] = v;
  }
}

// ---------------- pad copy (fp32 ci-major, for small convs) ----------------
__global__ void pad_copy(const float* __restrict__ src, float* __restrict__ dst,
                         int H, int W, int S, int total) {
  const int idx = blockIdx.x * 256 + threadIdx.x;
  if (idx >= total) return;
  const int p = idx / (H * W);
  const int rem = idx - p * H * W;
  const int y = rem / W, x = rem - y * W;
  dst[((size_t)p * (H + 2) + y + 1) * S + x + 1] = src[idx];
}

__global__ void border_zero(float* __restrict__ dst, int H, int W, int S) {
  const int p = blockIdx.x;
  float* b = dst + (size_t)p * (H + 2) * S;
  for (int c = threadIdx.x; c < S; c += 256) {
    b[c] = 0.f;
    b[(size_t)(H + 1) * S + c] = 0.f;
  }
  for (int r = 1 + threadIdx.x; r <= H; r += 256) {
    b[(size_t)r * S] = 0.f;
    b[(size_t)r * S + W + 1] = 0.f;
  }
}

// zero same-pad strips of q_pad (fp32): row 256 and col 256 of each [257][264] plane
__global__ void qpad_zero(float* __restrict__ q) {
  float* p = q + (size_t)blockIdx.x * QPS;
  for (int c = threadIdx.x; c < 264; c += 256) p[256 * 264 + c] = 0.f;
  for (int r = threadIdx.x; r < 256; r += 256) p[r * 264 + 256] = 0.f;
}

// ---------------- pan fp32 [ci][256][256] -> bf16 [row 258][col 264][ci 64] ----------------
// grid (4 ct, 258 g, 8 n), block 256; row g = orig y-1, col c = orig x-1
__global__ void pad_rci(const float* __restrict__ src, unsigned short* __restrict__ dst) {
  const int ct = blockIdx.x, g = blockIdx.y, n = blockIdx.z;
  const int c0 = ct * 66;
  __shared__ float t[64 * 68];
  const int jl = threadIdx.x & 63, cg = threadIdx.x >> 6;
  const int row = g - 1;
  const bool rok = (row >= 0 && row < 256);
  for (int ci = cg; ci < 64; ci += 4) {
    #pragma unroll
    for (int jb = 0; jb < 2; ++jb) {
      const int j = jl + jb * 64;
      if (j < 66) {
        const int x = c0 - 1 + j;
        float v = 0.f;
        if (rok && x >= 0 && x < 256)
          v = src[(((size_t)n * 64 + ci) * 256 + row) * 256 + x];
        t[ci * 68 + j] = v;
      }
    }
  }
  __syncthreads();
  const int cil = threadIdx.x & 63, cc = threadIdx.x >> 6;
  unsigned short* db = dst + (((size_t)n * 258 + g) * 264) * 64;
  for (int c = cc; c < 66; c += 4)
    db[(size_t)(c0 + c) * 64 + cil] = f2bf(t[cil * 68 + c]);
}

// zero borders of resbf (rows 0,257 full; cols 0,257 for rows 1..256)
__global__ void rbz(unsigned short* __restrict__ resbf) {
  const int n = blockIdx.x;
  unsigned short* b = resbf + (size_t)n * 258 * 264 * 64;
  for (int idx = threadIdx.x; idx < 264 * 64; idx += 256) {
    b[idx] = 0;
    b[(size_t)257 * 264 * 64 + idx] = 0;
  }
  for (int idx = threadIdx.x; idx < 256 * 64; idx += 256) {
    const int r = idx >> 6, ci = idx & 63;
    b[((size_t)(r + 1) * 264) * 64 + ci] = 0;
    b[((size_t)(r + 1) * 264 + 257) * 64 + ci] = 0;
  }
}

// ---------------- MFMA conv 3x3 + bias + leaky relu (bf16 in, fp32 out) ----------------
// grid (4 xt, 256 y, 8 n), 256 thr = 4 waves; wave = 16co x 64pix; K = 18 chunks of 32
__global__ __launch_bounds__(256) void conv3m(
    const unsigned short* __restrict__ inbf,  // [n][258][264][64ci] bf16
    const unsigned short* __restrict__ wimg,  // [18][64co][40] bf16
    const float* __restrict__ bias,
    float* __restrict__ out, int PS, int RS) {
  const int x0 = blockIdx.x * 64;
  const int y  = blockIdx.y;
  const int n  = blockIdx.z;
  const int tid = threadIdx.x;
  const int lane = tid & 63;
  const int wv = tid >> 6;
  const int col = lane & 15;
  const int kg  = lane >> 4;

  __shared__ unsigned short in_s[3 * 66 * 72];

  // stage input tile: rows y..y+2, cols x0..x0+65, 64 ci each (128 B per (r,c))
  {
    const unsigned short* src = inbf + ((size_t)n * 258 + y) * 264 * 64;
    if (tid < 198) {
      const int r = tid / 66, c = tid - r * 66;
      const unsigned short* s = src + ((size_t)r * 264 + x0 + c) * 64;
      unsigned short* d = &in_s[(r * 66 + c) * 72];
      #pragma unroll
      for (int q = 0; q < 8; ++q)
        *(float4*)(d + q * 8) = *(const float4*)(s + q * 8);
    }
  }
  __syncthreads();

  f32x4 acc[4];
  #pragma unroll
  for (int p = 0; p < 4; ++p) acc[p] = (f32x4){0.f, 0.f, 0.f, 0.f};

  const unsigned short* wbase = wimg + ((size_t)(wv * 16 + col)) * 40 + kg * 8;

  #pragma unroll 2
  for (int ch = 0; ch < 18; ++ch) {
    const int tap = ch >> 1, cih = ch & 1;
    const int dy = tap / 3, dx = tap - dy * 3;
    const bf16x8s a = *(const bf16x8s*)(wbase + (size_t)ch * 64 * 40);
    const int cix = cih * 32 + kg * 8;
    #pragma unroll
    for (int p = 0; p < 4; ++p) {
      const int c = p * 16 + col + dx;
      const bf16x8s b = *(const bf16x8s*)&in_s[(dy * 66 + c) * 72 + cix];
      acc[p] = __builtin_amdgcn_mfma_f32_16x16x32_bf16(a, b, acc[p], 0, 0, 0);
    }
  }

  // epilogue: co = wv*16 + kg*4 + reg, pix col = lane&15
  const int cobase = wv * 16 + kg * 4;
  const float4 bb = *(const float4*)&bias[cobase];
  const float bv[4] = {bb.x, bb.y, bb.z, bb.w};
  #pragma unroll
  for (int p = 0; p < 4; ++p) {
    const int x = x0 + p * 16 + col;
    #pragma unroll
    for (int r = 0; r < 4; ++r) {
      float t = acc[p][r] + bv[r];
      t = t > 0.f ? t : 0.01f * t;
      out[(size_t)(n * 64 + cobase + r) * PS + (size_t)y * RS + x] = t;
    }
  }
}

// ---------------- small conv 3x3 (fp32, for k/v 64x64) ----------------
__global__ __launch_bounds__(256) void conv3s(
    const float* __restrict__ inp, const float* __restrict__ Wts,
    const float* __restrict__ bias, float* __restrict__ out,
    int H, int Wd, int S, int outPS, int outRS) {
  const int x0 = blockIdx.x * 64;
  const int y0 = blockIdx.y * 8;
  const int z  = blockIdx.z;
  const int n  = z >> 3;
  const int cog = z & 7;
  const int tid = threadIdx.x;
  const int xq = tid & 15;
  const int yt = (tid >> 4) & 7;
  const int cg = tid >> 7;
  const int Hp = H + 2;

  __shared__ float in_s[10 * 72];
  __shared__ float w_s[CI * 9 * 8];

  {
    const float* wbase = Wts + (size_t)cog * (CI * 9 * 8);
    for (int idx = tid; idx < CI * 9 * 2; idx += 256)
      *(float4*)&w_s[idx * 4] = *(const float4*)(wbase + idx * 4);
  }

  float acc[4][4];
  #pragma unroll
  for (int a = 0; a < 4; ++a)
    #pragma unroll
    for (int b = 0; b < 4; ++b) acc[a][b] = 0.f;

  const bool hasA = tid < 180;
  const int arow = tid / 18, ac4 = tid - arow * 18;
  const float* gplane0 = inp + (size_t)(n * CI) * Hp * S;
  const size_t aoff = ((size_t)(y0 + arow)) * S + x0 + ac4 * 4;

  float4 sA = make_float4(0.f, 0.f, 0.f, 0.f);
  if (hasA) sA = *(const float4*)(gplane0 + aoff);

  for (int ci = 0; ci < CI; ++ci) {
    __syncthreads();
    if (hasA) *(float4*)&in_s[arow * 72 + ac4 * 4] = sA;
    if (ci + 1 < CI && hasA)
      sA = *(const float4*)(gplane0 + (size_t)(ci + 1) * Hp * S + aoff);
    __syncthreads();

    float xin[3][8];
    const int cb = xq * 4;
    #pragma unroll
    for (int r = 0; r < 3; ++r) {
      const float4 xa = *(const float4*)&in_s[(yt + r) * 72 + cb];
      const float4 xb = *(const float4*)&in_s[(yt + r) * 72 + cb + 4];
      xin[r][0] = xa.x; xin[r][1] = xa.y; xin[r][2] = xa.z; xin[r][3] = xa.w;
      xin[r][4] = xb.x; xin[r][5] = xb.y; xin[r][6] = xb.z; xin[r][7] = xb.w;
    }

    const float* wci = &w_s[(ci * 9) * 8 + cg * 4];
    #pragma unroll
    for (int ky = 0; ky < 3; ++ky) {
      #pragma unroll
      for (int kx = 0; kx < 3; ++kx) {
        const float4 w4 = *(const float4*)&wci[(ky * 3 + kx) * 8];
        const float wv[4] = {w4.x, w4.y, w4.z, w4.w};
        #pragma unroll
        for (int c = 0; c < 4; ++c)
          #pragma unroll
          for (int dx = 0; dx < 4; ++dx)
            acc[c][dx] = fmaf(wv[c], xin[ky][dx + kx], acc[c][dx]);
      }
    }
  }

  #pragma unroll
  for (int c = 0; c < 4; ++c) {
    const int co = cog * 8 + cg * 4 + c;
    const float bv = bias[co];
    float4 o;
    float t;
    t = acc[c][0] + bv; o.x = t > 0.f ? t : 0.01f * t;
    t = acc[c][1] + bv; o.y = t > 0.f ? t : 0.01f * t;
    t = acc[c][2] + bv; o.z = t > 0.f ? t : 0.01f * t;
    t = acc[c][3] + bv; o.w = t > 0.f ? t : 0.01f * t;
    *(float4*)(out + (size_t)(n * COC + co) * outPS + (size_t)(y0 + yt) * outRS + x0 + xq * 4) = o;
  }
}

// ---------------- k-patch squared norms ----------------
__global__ void knorm_kernel(const float* __restrict__ kfea, float* __restrict__ norms) {
  const int l = blockIdx.x, n = blockIdx.y, c = threadIdx.x;
  const int ly = l >> 4, lx = l & 15;
  const float* base = kfea + ((size_t)(n * CI + c) * HK) * HK;
  float ss = 0.f;
  #pragma unroll
  for (int i = 0; i < KS; ++i) {
    const int r = 4 * ly + i;
    if (r >= HK) continue;
    #pragma unroll
    for (int j = 0; j < KS; ++j) {
      const int cc = 4 * lx + j;
      if (cc >= HK) continue;
      const float v = base[r * HK + cc];
      ss = fmaf(v, v, ss);
    }
  }
  for (int off = 32; off; off >>= 1) ss += __shfl_down(ss, off);
  if (c == 0) norms[n * LL + l] = ss;
}

__global__ void kscale_kernel(const float* __restrict__ norms, float* __restrict__ kscale) {
  const int n = blockIdx.x, t = threadIdx.x;
  float v = norms[n * LL + t];
  for (int off = 32; off; off >>= 1) v = fmaxf(v, __shfl_down(v, off));
  __shared__ float red[4];
  if ((t & 63) == 0) red[t >> 6] = v;
  __syncthreads();
  if (t == 0) {
    const float m = fmaxf(fmaxf(red[0], red[1]), fmaxf(red[2], red[3]));
    kscale[n] = 10.0f / sqrtf(m);
  }
}

// ---------------- K im2col gather (kscale folded, XOR-swizzled slots) ----------------
__global__ void kp_gather(const float* __restrict__ kfea, const float* __restrict__ kscale,
                          float* __restrict__ kp) {
  const int l = threadIdx.x;
  const int ij = blockIdx.x, ci = blockIdx.y, n = blockIdx.z;
  const int i = ij / 5, j = ij % 5;
  const int lt = l >> 4, li = l & 15;
  const int r = 4 * lt + i, c = 4 * (li) + j;
  float v = 0.f;
  if (r < HK && c < HK) v = kfea[((size_t)(n * CI + ci) * HK + r) * HK + c];
  v *= kscale[n];
  const int r2 = li >> 2, e = li & 3;
  const int slot = (lt * 4 + r2) ^ (lt >> 1);
  kp[((size_t)(n * CI + ci) * 25 + ij) * 256 + slot * 4 + e] = v;
}

// ---------------- QK partial scores ----------------
__global__ __launch_bounds__(128, 2) void qk_scores(
    const float* __restrict__ qpad, const float* __restrict__ kp,
    float* __restrict__ scores, size_t half_stride) {
  const int h = blockIdx.x, cih = blockIdx.y, n = blockIdx.z;
  const int tid = threadIdx.x;
  const int lt = tid & 15;
  const int wt = tid >> 4;
  __shared__ float k_s[25 * 256];
  __shared__ float q_s[25 * 64];

  int koff[4];
  #pragma unroll
  for (int r2 = 0; r2 < 4; ++r2) koff[r2] = (((lt * 4 + r2) ^ (lt >> 1)) << 2);

  float acc[16][8];
  #pragma unroll
  for (int a = 0; a < 16; ++a)
    #pragma unroll
    for (int b = 0; b < 8; ++b) acc[a][b] = 0.f;

  const float* qn = qpad + (size_t)(n * CI + cih * 32) * QPS + (size_t)(4 * h) * 264;
  const float* kpb = kp + ((size_t)(n * CI + cih * 32)) * 6400;

  for (int cc = 0; cc < 32; ++cc) {
    __syncthreads();
    const float4* ksrc = (const float4*)(kpb + (size_t)cc * 6400);
    #pragma unroll
    for (int it = 0; it < 13; ++it) {
      const int idx = tid + it * 128;
      if (idx < 1600) *(float4*)&k_s[idx * 4] = ksrc[idx];
    }
    const float* qp = qn + (size_t)cc * QPS;
    #pragma unroll
    for (int it = 0; it < 13; ++it) {
      const int s = tid + it * 128;
      if (s < 1600) {
        const int ij = s >> 6, w = s & 63;
        const int i = (ij * 205) >> 10;
        const int j = ij - 5 * i;
        q_s[s] = qp[i * 264 + 4 * w + j];
      }
    }
    __syncthreads();

    #pragma unroll 5
    for (int ij = 0; ij < 25; ++ij) {
      const float* kb = &k_s[ij * 256];
      float kk[16];
      #pragma unroll
      for (int r2 = 0; r2 < 4; ++r2) {
        const float4 kv = *(const float4*)(kb + koff[r2]);
        kk[r2 * 4 + 0] = kv.x; kk[r2 * 4 + 1] = kv.y;
        kk[r2 * 4 + 2] = kv.z; kk[r2 * 4 + 3] = kv.w;
      }
      const float4 q0 = *(const float4*)&q_s[ij * 64 + wt * 8];
      const float4 q1 = *(const float4*)&q_s[ij * 64 + wt * 8 + 4];
      const float qq[8] = {q0.x, q0.y, q0.z, q0.w, q1.x, q1.y, q1.z, q1.w};
      #pragma unroll
      for (int li = 0; li < 16; ++li)
        #pragma unroll
        for (int wi = 0; wi < 8; ++wi)
          acc[li][wi] = fmaf(kk[li], qq[wi], acc[li][wi]);
    }
  }

  float* dst = scores + (size_t)cih * half_stride + ((size_t)(n * 64 + h) * 64) * 256;
  #pragma unroll
  for (int wi = 0; wi < 8; ++wi) {
    float* d2 = dst + (size_t)(wt * 8 + wi) * 256 + lt * 16;
    #pragma unroll
    for (int r2 = 0; r2 < 4; ++r2) {
      *(float4*)(d2 + r2 * 4) = make_float4(acc[r2 * 4 + 0][wi], acc[r2 * 4 + 1][wi],
                                            acc[r2 * 4 + 2][wi], acc[r2 * 4 + 3][wi]);
    }
  }
}

// ---------------- softmax over l ----------------
__global__ void softmax_rows(const float* __restrict__ sa, const float* __restrict__ sb,
                             float* __restrict__ wn) {
  const int row = blockIdx.x * 4 + (threadIdx.x >> 6);
  const int lane = threadIdx.x & 63;
  const size_t idx = (size_t)row * 64 + lane;
  const float4 a = ((const float4*)sa)[idx];
  const float4 b = ((const float4*)sb)[idx];
  float4 v = make_float4(a.x + b.x, a.y + b.y, a.z + b.z, a.w + b.w);
  float m = fmaxf(fmaxf(v.x, v.y), fmaxf(v.z, v.w));
  for (int off = 32; off; off >>= 1) m = fmaxf(m, __shfl_xor(m, off));
  float4 e;
  e.x = __expf(v.x - m); e.y = __expf(v.y - m);
  e.z = __expf(v.z - m); e.w = __expf(v.w - m);
  float s = e.x + e.y + e.z + e.w;
  for (int off = 32; off; off >>= 1) s += __shfl_xor(s, off);
  const float inv = 1.0f / s;
  ((float4*)wn)[idx] = make_float4(e.x * inv, e.y * inv, e.z * inv, e.w * inv);
}

// ---------------- v-patch matrix gather ----------------
__global__ void vp_gather(const float* __restrict__ vfea, float* __restrict__ vp) {
  const int bij = blockIdx.x * 256 + threadIdx.x;
  const int l = blockIdx.y, n = blockIdx.z;
  if (bij >= NPAD) return;
  const int ij = bij >> 6, b = bij & 63;
  float val = 0.f;
  if (ij < 25) {
    const int i = ij / 5, j = ij % 5;
    const int ly = l >> 4, lx = l & 15;
    const int r = 4 * ly + i, c = 4 * lx + j;
    if (r < HK && c < HK) val = vfea[((size_t)(n * COC + b) * HK + r) * HK + c];
  }
  vp[((size_t)(n * LL + l)) * NPAD + bij] = val;
}

// ---------------- PV GEMM (z = batch) ----------------
__global__ __launch_bounds__(256) void pv_gemm(
    const float* __restrict__ A0, const float* __restrict__ B0, float* __restrict__ C0) {
  const int nz = blockIdx.z;
  const float* A = A0 + (size_t)nz * 4096 * 256;
  const float* Bm = B0 + (size_t)nz * LL * NPAD;
  float* C = C0 + (size_t)nz * 4096 * NPAD;
  const int m0 = blockIdx.x * 128;
  const int n0 = blockIdx.y * 128;
  const int tid = threadIdx.x;
  const int tm = tid & 15, tn = tid >> 4;
  __shared__ float As[16][132];
  __shared__ float Bs[16][128];
  float acc[8][8];
  #pragma unroll
  for (int a = 0; a < 8; ++a)
    #pragma unroll
    for (int b = 0; b < 8; ++b) acc[a][b] = 0.f;

  for (int k0 = 0; k0 < 256; k0 += 16) {
    __syncthreads();
    #pragma unroll
    for (int r = 0; r < 2; ++r) {
      const int idx = tid + r * 256;
      const int row = idx >> 2, c4 = idx & 3;
      const float4 v = *(const float4*)&A[(size_t)(m0 + row) * 256 + k0 + c4 * 4];
      As[c4 * 4 + 0][row] = v.x;
      As[c4 * 4 + 1][row] = v.y;
      As[c4 * 4 + 2][row] = v.z;
      As[c4 * 4 + 3][row] = v.w;
    }
    #pragma unroll
    for (int r = 0; r < 2; ++r) {
      const int idx = tid + r * 256;
      const int row = idx >> 5, c4 = idx & 31;
      *(float4*)&Bs[row][c4 * 4] = *(const float4*)&Bm[(size_t)(k0 + row) * NPAD + n0 + c4 * 4];
    }
    __syncthreads();
    #pragma unroll
    for (int k = 0; k < 16; ++k) {
      const float4 a0 = *(const float4*)&As[k][tm * 8];
      const float4 a1 = *(const float4*)&As[k][tm * 8 + 4];
      const float4 b0 = *(const float4*)&Bs[k][tn * 8];
      const float4 b1 = *(const float4*)&Bs[k][tn * 8 + 4];
      const float av[8] = {a0.x, a0.y, a0.z, a0.w, a1.x, a1.y, a1.z, a1.w};
      const float bv[8] = {b0.x, b0.y, b0.z, b0.w, b1.x, b1.y, b1.z, b1.w};
      #pragma unroll
      for (int mi = 0; mi < 8; ++mi)
        #pragma unroll
        for (int ni = 0; ni < 8; ++ni)
          acc[mi][ni] = fmaf(av[mi], bv[ni], acc[mi][ni]);
    }
  }
  #pragma unroll
  for (int mi = 0; mi < 8; ++mi) {
    float* dst = &C[(size_t)(m0 + tm * 8 + mi) * NPAD + n0 + tn * 8];
    *(float4*)dst = make_float4(acc[mi][0], acc[mi][1], acc[mi][2], acc[mi][3]);
    *(float4*)(dst + 4) = make_float4(acc[mi][4], acc[mi][5], acc[mi][6], acc[mi][7]);
  }
}

// ---------------- conv-transpose gather (+ /6) -> resbf bf16 [258][264][64co] ----------------
__global__ __launch_bounds__(256) void u_scatter(
    const float* __restrict__ U0, unsigned short* __restrict__ resbf, int n0) {
  const int n = n0 + blockIdx.z;
  const float* U = U0 + (size_t)blockIdx.z * 4096 * NPAD;
  const int y = blockIdx.y;
  const int xt = blockIdx.x;
  const int tid = threadIdx.x;
  __shared__ float t_lds[64][65];
  const int ym = (y + 1) >> 2, yr = (y + 1) & 3;
  const bool v0 = (ym < 64);
  const bool v1 = (yr == 0 && ym >= 1);
  const int b = tid & 63, xg = tid >> 6;
  for (int xi = 0; xi < 16; ++xi) {
    const int x = xt * 64 + xg * 16 + xi;
    const int xm = (x + 1) >> 2, xr = (x + 1) & 3;
    const bool u0 = (xm < 64);
    const bool u1 = (xr == 0 && xm >= 1);
    float s = 0.f;
    if (v0) {
      const size_t rb = (size_t)(ym * 64) * NPAD;
      if (u0) s += U[rb + (size_t)xm * NPAD + (yr * 5 + xr) * 64 + b];
      if (u1) s += U[rb + (size_t)(xm - 1) * NPAD + (yr * 5 + 4) * 64 + b];
    }
    if (v1) {
      const size_t rb = (size_t)((ym - 1) * 64) * NPAD;
      if (u0) s += U[rb + (size_t)xm * NPAD + (4 * 5 + xr) * 64 + b];
      if (u1) s += U[rb + (size_t)(xm - 1) * NPAD + (4 * 5 + 4) * 64 + b];
    }
    t_lds[xg * 16 + xi][b] = s * (1.0f / 6.0f);
  }
  __syncthreads();
  unsigned short* db = resbf + (((size_t)n * 258 + (y + 1)) * 264) * 64;
  for (int xi = 0; xi < 16; ++xi) {
    const int x = xg * 16 + xi;
    db[(size_t)(xt * 64 + x + 1) * 64 + b] = f2bf(t_lds[x][b]);
  }
}

extern "C" void kernel_launch(void* const* d_in, const int* in_sizes, int n_in,
                              void* d_out, int out_size, void* d_ws, size_t ws_size,
                              hipStream_t stream) {
  const float* ms   = (const float*)d_in[0];
  const float* pan  = (const float*)d_in[1];
  const float* pan2 = (const float*)d_in[2];
  const float* Wq   = (const float*)d_in[3];
  const float* bq   = (const float*)d_in[4];
  const float* Wk   = (const float*)d_in[5];
  const float* bk   = (const float*)d_in[6];
  const float* Wv   = (const float*)d_in[7];
  const float* bv   = (const float*)d_in[8];
  const float* Wr   = (const float*)d_in[9];
  const float* br   = (const float*)d_in[10];
  float* out = (float*)d_out;

  float* ws = (float*)d_ws;
  const size_t SZ_QP  = (size_t)NB * CI * QPS;               // 34.74M fp32 (q_pad; resbf aliases)
  const size_t SZ_K   = (size_t)NB * CI * HK * HK;           // 2.10M
  const size_t SZ_WN  = (size_t)NB * 64 * 64 * LL;           // 8.39M
  const size_t SZ_VP  = (size_t)NB * LL * NPAD;              // 3.41M
  const size_t SZ_KP  = (size_t)NB * CI * 25 * 256;          // 3.28M
  const size_t SZ_PS  = (size_t)NB * CI * 66 * 72;           // 2.43M
  const size_t SZ_WI  = 23040;                               // 46080 bf16 as floats
  const size_t SZ_PBF = ((size_t)NB * 258 * 264 * 64 + 1) / 2; // 17.44M floats (bf16 buf)
  const size_t SZ_U1  = (size_t)4096 * NPAD;                 // 6.82M per batch
  const size_t SZ_UA  = (size_t)NB * SZ_U1;                  // 54.53M

  float* q_pad   = ws;
  float* k_fea   = q_pad + SZ_QP;
  float* v_fea   = k_fea + SZ_K;
  float* wn      = v_fea + SZ_K;
  float* vp      = wn + SZ_WN;
  float* kp      = vp + SZ_VP;
  float* norms   = kp + SZ_KP;
  float* kscale  = norms + NB * LL;
  float* wtk     = kscale + 64;
  float* wtv     = wtk + 36864;
  float* wimgqf  = wtv + 36864;
  float* wimgrf  = wimgqf + SZ_WI;
  float* ms_pad  = wimgrf + SZ_WI;
  float* pan2pad = ms_pad + SZ_PS;
  float* tail    = pan2pad + SZ_PS;       // panbf -> scores -> U

  unsigned short* wimgq = (unsigned short*)wimgqf;
  unsigned short* wimgr = (unsigned short*)wimgrf;
  unsigned short* panbf = (unsigned short*)tail;
  float* scores  = tail;
  float* U       = tail;
  unsigned short* resbf = (unsigned short*)q_pad;   // q_pad dead after qk_scores

  const size_t base_elems = (size_t)(tail - ws);
  const bool batched = ws_size >= (base_elems + SZ_UA) * sizeof(float);

  // weight prep
  wtrans8_kernel<<<dim3(9, 64), 64, 0, stream>>>(Wk, wtk);
  wtrans8_kernel<<<dim3(9, 64), 64, 0, stream>>>(Wv, wtv);
  wtrans_mfma<<<dim3(18), 256, 0, stream>>>(Wq, wimgq);
  wtrans_mfma<<<dim3(18), 256, 0, stream>>>(Wr, wimgr);

  // pad inputs
  {
    const int totS = NB * CI * HK * HK;
    pad_copy<<<dim3((totS + 255) / 256), 256, 0, stream>>>(ms, ms_pad, HK, HK, 72, totS);
    pad_copy<<<dim3((totS + 255) / 256), 256, 0, stream>>>(pan2, pan2pad, HK, HK, 72, totS);
    border_zero<<<dim3(NB * CI), 256, 0, stream>>>(ms_pad, HK, HK, 72);
    border_zero<<<dim3(NB * CI), 256, 0, stream>>>(pan2pad, HK, HK, 72);
    pad_rci<<<dim3(4, 258, NB), 256, 0, stream>>>(pan, panbf);
    qpad_zero<<<dim3(NB * CI), 256, 0, stream>>>(q_pad);
  }

  // feature convs: k,v small (fp32); q big (MFMA bf16)
  conv3s<<<dim3(HK / 64, HK / 8, NB * 8), 256, 0, stream>>>(pan2pad, wtk, bk, k_fea, HK, HK, 72, HK * HK, HK);
  conv3s<<<dim3(HK / 64, HK / 8, NB * 8), 256, 0, stream>>>(ms_pad,  wtv, bv, v_fea, HK, HK, 72, HK * HK, HK);
  conv3m<<<dim3(4, 256, NB), 256, 0, stream>>>(panbf, wimgq, bq, q_pad, QPS, 264);

  // k-patch max norm -> scale
  knorm_kernel<<<dim3(LL, NB), 64, 0, stream>>>(k_fea, norms);
  kscale_kernel<<<NB, 256, 0, stream>>>(norms, kscale);

  // K im2col (kscale folded, swizzled)
  kp_gather<<<dim3(25, CI, NB), 256, 0, stream>>>(k_fea, kscale, kp);

  // QK partial scores (2 ci-halves) + softmax   [panbf dead; scores reuses tail]
  qk_scores<<<dim3(64, 2, NB), 128, 0, stream>>>(q_pad, kp, scores, SZ_WN);
  softmax_rows<<<dim3(8192), 256, 0, stream>>>(scores, scores + SZ_WN, wn);

  // resbf borders (aliases q_pad; q_pad dead after qk_scores)
  rbz<<<dim3(NB), 256, 0, stream>>>(resbf);

  // v patch matrix
  vp_gather<<<dim3((NPAD + 255) / 256, LL, NB), 256, 0, stream>>>(v_fea, vp);

  // PV GEMM + conv-transpose gather (U reuses tail; scores dead after softmax)
  if (batched) {
    pv_gemm<<<dim3(32, 13, NB), 256, 0, stream>>>(wn, vp, U);
    u_scatter<<<dim3(4, HQ, NB), 256, 0, stream>>>(U, resbf, 0);
  } else {
    for (int n = 0; n < NB; ++n) {
      pv_gemm<<<dim3(32, 13, 1), 256, 0, stream>>>(wn + (size_t)n * 4096 * 256,
                                                   vp + (size_t)n * LL * NPAD, U);
      u_scatter<<<dim3(4, HQ, 1), 256, 0, stream>>>(U, resbf, n);
    }
  }

  // final conv (MFMA bf16) -> d_out fp32
  conv3m<<<dim3(4, 256, NB), 256, 0, stream>>>(resbf, wimgr, br, out, HQ * HQ, HQ);
}

// Round 10
// 1039.332 us; speedup vs baseline: 6.7199x; 1.1531x over previous
//
#include <hip/hip_runtime.h>
#include <math.h>

#define NB   8
#define CI   64
#define COC  64
#define HQ   256
#define HK   64
#define KS   5
#define LL   256
#define NPAD 1664
#define QPS  (257 * 264)   // q padded plane stride (floats)

typedef __attribute__((ext_vector_type(8))) short bf16x8s;
typedef __attribute__((ext_vector_type(4))) float f32x4;

static __device__ __forceinline__ unsigned short f2bf(float f) {
  union { float f; unsigned u; } v; v.f = f;
  unsigned r = v.u + 0x7FFF + ((v.u >> 16) & 1);
  return (unsigned short)(r >> 16);
}

// ---------------- weight transpose for conv3s: [CO][CI][3][3] -> [cogrp8][CI][tap][8] ----------------
__global__ void wtrans8_kernel(const float* __restrict__ Wt, float* __restrict__ Wo) {
  const int co = threadIdx.x;
  const int tap = blockIdx.x;
  const int ci = blockIdx.y;
  Wo[(((co >> 3) * 64 + ci) * 9 + tap) * 8 + (co & 7)] = Wt[(co * 64 + ci) * 9 + tap];
}

// ---------------- weight image for conv3m: [18 chunk][64 co][40] bf16 ----------------
__global__ void wtrans_mfma(const float* __restrict__ Wt, unsigned short* __restrict__ wimg) {
  const int ch = blockIdx.x;
  const int tap = ch >> 1, cih = ch & 1;
  for (int idx = threadIdx.x; idx < 64 * 40; idx += 256) {
    const int co = idx / 40, s = idx - co * 40;
    unsigned short v = 0;
    if (s < 32) v = f2bf(Wt[((size_t)co * 64 + cih * 32 + s) * 9 + tap]);
    wimg[(size_t)ch * 64 * 40 + idx] = v;
  }
}

// ---------------- pad copy (fp32 ci-major, for small convs) ----------------
__global__ void pad_copy(const float* __restrict__ src, float* __restrict__ dst,
                         int H, int W, int S, int total) {
  const int idx = blockIdx.x * 256 + threadIdx.x;
  if (idx >= total) return;
  const int p = idx / (H * W);
  const int rem = idx - p * H * W;
  const int y = rem / W, x = rem - y * W;
  dst[((size_t)p * (H + 2) + y + 1) * S + x + 1] = src[idx];
}

__global__ void border_zero(float* __restrict__ dst, int H, int W, int S) {
  const int p = blockIdx.x;
  float* b = dst + (size_t)p * (H + 2) * S;
  for (int c = threadIdx.x; c < S; c += 256) {
    b[c] = 0.f;
    b[(size_t)(H + 1) * S + c] = 0.f;
  }
  for (int r = 1 + threadIdx.x; r <= H; r += 256) {
    b[(size_t)r * S] = 0.f;
    b[(size_t)r * S + W + 1] = 0.f;
  }
}

// zero same-pad strips of q_pad (fp32)
__global__ void qpad_zero(float* __restrict__ q) {
  float* p = q + (size_t)blockIdx.x * QPS;
  for (int c = threadIdx.x; c < 264; c += 256) p[256 * 264 + c] = 0.f;
  for (int r = threadIdx.x; r < 256; r += 256) p[r * 264 + 256] = 0.f;
}

// ---------------- pan fp32 [ci][256][256] -> bf16 [row 258][col 264][ci 64] ----------------
__global__ void pad_rci(const float* __restrict__ src, unsigned short* __restrict__ dst) {
  const int ct = blockIdx.x, g = blockIdx.y, n = blockIdx.z;
  const int c0 = ct * 66;
  __shared__ float t[64 * 68];
  const int jl = threadIdx.x & 63, cg = threadIdx.x >> 6;
  const int row = g - 1;
  const bool rok = (row >= 0 && row < 256);
  for (int ci = cg; ci < 64; ci += 4) {
    #pragma unroll
    for (int jb = 0; jb < 2; ++jb) {
      const int j = jl + jb * 64;
      if (j < 66) {
        const int x = c0 - 1 + j;
        float v = 0.f;
        if (rok && x >= 0 && x < 256)
          v = src[(((size_t)n * 64 + ci) * 256 + row) * 256 + x];
        t[ci * 68 + j] = v;
      }
    }
  }
  __syncthreads();
  const int cil = threadIdx.x & 63, cc = threadIdx.x >> 6;
  unsigned short* db = dst + (((size_t)n * 258 + g) * 264) * 64;
  for (int c = cc; c < 66; c += 4)
    db[(size_t)(c0 + c) * 64 + cil] = f2bf(t[cil * 68 + c]);
}

// zero borders of resbf
__global__ void rbz(unsigned short* __restrict__ resbf) {
  const int n = blockIdx.x;
  unsigned short* b = resbf + (size_t)n * 258 * 264 * 64;
  for (int idx = threadIdx.x; idx < 264 * 64; idx += 256) {
    b[idx] = 0;
    b[(size_t)257 * 264 * 64 + idx] = 0;
  }
  for (int idx = threadIdx.x; idx < 256 * 64; idx += 256) {
    const int r = idx >> 6, ci = idx & 63;
    b[((size_t)(r + 1) * 264) * 64 + ci] = 0;
    b[((size_t)(r + 1) * 264 + 257) * 64 + ci] = 0;
  }
}

// ---------------- MFMA conv 3x3 + bias + leaky relu (bf16 in, fp32 out) ----------------
__global__ __launch_bounds__(256) void conv3m(
    const unsigned short* __restrict__ inbf,
    const unsigned short* __restrict__ wimg,
    const float* __restrict__ bias,
    float* __restrict__ out, int PS, int RS) {
  const int x0 = blockIdx.x * 64;
  const int y  = blockIdx.y;
  const int n  = blockIdx.z;
  const int tid = threadIdx.x;
  const int lane = tid & 63;
  const int wv = tid >> 6;
  const int col = lane & 15;
  const int kg  = lane >> 4;

  __shared__ unsigned short in_s[3 * 66 * 72];

  {
    const unsigned short* src = inbf + ((size_t)n * 258 + y) * 264 * 64;
    if (tid < 198) {
      const int r = tid / 66, c = tid - r * 66;
      const unsigned short* s = src + ((size_t)r * 264 + x0 + c) * 64;
      unsigned short* d = &in_s[(r * 66 + c) * 72];
      #pragma unroll
      for (int q = 0; q < 8; ++q)
        *(float4*)(d + q * 8) = *(const float4*)(s + q * 8);
    }
  }
  __syncthreads();

  f32x4 acc[4];
  #pragma unroll
  for (int p = 0; p < 4; ++p) acc[p] = (f32x4){0.f, 0.f, 0.f, 0.f};

  const unsigned short* wbase = wimg + ((size_t)(wv * 16 + col)) * 40 + kg * 8;

  #pragma unroll 2
  for (int ch = 0; ch < 18; ++ch) {
    const int tap = ch >> 1, cih = ch & 1;
    const int dy = tap / 3, dx = tap - dy * 3;
    const bf16x8s a = *(const bf16x8s*)(wbase + (size_t)ch * 64 * 40);
    const int cix = cih * 32 + kg * 8;
    #pragma unroll
    for (int p = 0; p < 4; ++p) {
      const int c = p * 16 + col + dx;
      const bf16x8s b = *(const bf16x8s*)&in_s[(dy * 66 + c) * 72 + cix];
      acc[p] = __builtin_amdgcn_mfma_f32_16x16x32_bf16(a, b, acc[p], 0, 0, 0);
    }
  }

  const int cobase = wv * 16 + kg * 4;
  const float4 bb = *(const float4*)&bias[cobase];
  const float bv[4] = {bb.x, bb.y, bb.z, bb.w};
  #pragma unroll
  for (int p = 0; p < 4; ++p) {
    const int x = x0 + p * 16 + col;
    #pragma unroll
    for (int r = 0; r < 4; ++r) {
      float t = acc[p][r] + bv[r];
      t = t > 0.f ? t : 0.01f * t;
      out[(size_t)(n * 64 + cobase + r) * PS + (size_t)y * RS + x] = t;
    }
  }
}

// ---------------- small conv 3x3 (fp32, for k/v 64x64) ----------------
__global__ __launch_bounds__(256) void conv3s(
    const float* __restrict__ inp, const float* __restrict__ Wts,
    const float* __restrict__ bias, float* __restrict__ out,
    int H, int Wd, int S, int outPS, int outRS) {
  const int x0 = blockIdx.x * 64;
  const int y0 = blockIdx.y * 8;
  const int z  = blockIdx.z;
  const int n  = z >> 3;
  const int cog = z & 7;
  const int tid = threadIdx.x;
  const int xq = tid & 15;
  const int yt = (tid >> 4) & 7;
  const int cg = tid >> 7;
  const int Hp = H + 2;

  __shared__ float in_s[10 * 72];
  __shared__ float w_s[CI * 9 * 8];

  {
    const float* wbase = Wts + (size_t)cog * (CI * 9 * 8);
    for (int idx = tid; idx < CI * 9 * 2; idx += 256)
      *(float4*)&w_s[idx * 4] = *(const float4*)(wbase + idx * 4);
  }

  float acc[4][4];
  #pragma unroll
  for (int a = 0; a < 4; ++a)
    #pragma unroll
    for (int b = 0; b < 4; ++b) acc[a][b] = 0.f;

  const bool hasA = tid < 180;
  const int arow = tid / 18, ac4 = tid - arow * 18;
  const float* gplane0 = inp + (size_t)(n * CI) * Hp * S;
  const size_t aoff = ((size_t)(y0 + arow)) * S + x0 + ac4 * 4;

  float4 sA = make_float4(0.f, 0.f, 0.f, 0.f);
  if (hasA) sA = *(const float4*)(gplane0 + aoff);

  for (int ci = 0; ci < CI; ++ci) {
    __syncthreads();
    if (hasA) *(float4*)&in_s[arow * 72 + ac4 * 4] = sA;
    if (ci + 1 < CI && hasA)
      sA = *(const float4*)(gplane0 + (size_t)(ci + 1) * Hp * S + aoff);
    __syncthreads();

    float xin[3][8];
    const int cb = xq * 4;
    #pragma unroll
    for (int r = 0; r < 3; ++r) {
      const float4 xa = *(const float4*)&in_s[(yt + r) * 72 + cb];
      const float4 xb = *(const float4*)&in_s[(yt + r) * 72 + cb + 4];
      xin[r][0] = xa.x; xin[r][1] = xa.y; xin[r][2] = xa.z; xin[r][3] = xa.w;
      xin[r][4] = xb.x; xin[r][5] = xb.y; xin[r][6] = xb.z; xin[r][7] = xb.w;
    }

    const float* wci = &w_s[(ci * 9) * 8 + cg * 4];
    #pragma unroll
    for (int ky = 0; ky < 3; ++ky) {
      #pragma unroll
      for (int kx = 0; kx < 3; ++kx) {
        const float4 w4 = *(const float4*)&wci[(ky * 3 + kx) * 8];
        const float wv[4] = {w4.x, w4.y, w4.z, w4.w};
        #pragma unroll
        for (int c = 0; c < 4; ++c)
          #pragma unroll
          for (int dx = 0; dx < 4; ++dx)
            acc[c][dx] = fmaf(wv[c], xin[ky][dx + kx], acc[c][dx]);
      }
    }
  }

  #pragma unroll
  for (int c = 0; c < 4; ++c) {
    const int co = cog * 8 + cg * 4 + c;
    const float bv = bias[co];
    float4 o;
    float t;
    t = acc[c][0] + bv; o.x = t > 0.f ? t : 0.01f * t;
    t = acc[c][1] + bv; o.y = t > 0.f ? t : 0.01f * t;
    t = acc[c][2] + bv; o.z = t > 0.f ? t : 0.01f * t;
    t = acc[c][3] + bv; o.w = t > 0.f ? t : 0.01f * t;
    *(float4*)(out + (size_t)(n * COC + co) * outPS + (size_t)(y0 + yt) * outRS + x0 + xq * 4) = o;
  }
}

// ---------------- k-patch squared norms ----------------
__global__ void knorm_kernel(const float* __restrict__ kfea, float* __restrict__ norms) {
  const int l = blockIdx.x, n = blockIdx.y, c = threadIdx.x;
  const int ly = l >> 4, lx = l & 15;
  const float* base = kfea + ((size_t)(n * CI + c) * HK) * HK;
  float ss = 0.f;
  #pragma unroll
  for (int i = 0; i < KS; ++i) {
    const int r = 4 * ly + i;
    if (r >= HK) continue;
    #pragma unroll
    for (int j = 0; j < KS; ++j) {
      const int cc = 4 * lx + j;
      if (cc >= HK) continue;
      const float v = base[r * HK + cc];
      ss = fmaf(v, v, ss);
    }
  }
  for (int off = 32; off; off >>= 1) ss += __shfl_down(ss, off);
  if (c == 0) norms[n * LL + l] = ss;
}

__global__ void kscale_kernel(const float* __restrict__ norms, float* __restrict__ kscale) {
  const int n = blockIdx.x, t = threadIdx.x;
  float v = norms[n * LL + t];
  for (int off = 32; off; off >>= 1) v = fmaxf(v, __shfl_down(v, off));
  __shared__ float red[4];
  if ((t & 63) == 0) red[t >> 6] = v;
  __syncthreads();
  if (t == 0) {
    const float m = fmaxf(fmaxf(red[0], red[1]), fmaxf(red[2], red[3]));
    kscale[n] = 10.0f / sqrtf(m);
  }
}

// ---------------- K im2col gather (kscale folded, XOR-swizzled slots) ----------------
__global__ void kp_gather(const float* __restrict__ kfea, const float* __restrict__ kscale,
                          float* __restrict__ kp) {
  const int l = threadIdx.x;
  const int ij = blockIdx.x, ci = blockIdx.y, n = blockIdx.z;
  const int i = ij / 5, j = ij % 5;
  const int lt = l >> 4, li = l & 15;
  const int r = 4 * lt + i, c = 4 * (li) + j;
  float v = 0.f;
  if (r < HK && c < HK) v = kfea[((size_t)(n * CI + ci) * HK + r) * HK + c];
  v *= kscale[n];
  const int r2 = li >> 2, e = li & 3;
  const int slot = (lt * 4 + r2) ^ (lt >> 1);
  kp[((size_t)(n * CI + ci) * 25 + ij) * 256 + slot * 4 + e] = v;
}

// ---------------- QK partial scores: l-split for occupancy ----------------
// grid (64 h, 4 zz = cih*2+lh, 8 n); block 128. acc[8 l][8 w] per thread.
__global__ __launch_bounds__(128) void qk_scores(
    const float* __restrict__ qpad, const float* __restrict__ kp,
    float* __restrict__ scores, size_t half_stride) {
  const int h = blockIdx.x, zz = blockIdx.y, n = blockIdx.z;
  const int cih = zz >> 1, lh = zz & 1;
  const int tid = threadIdx.x;
  const int lt = tid & 15;   // 8 l's: l = lh*128 + lt*8 + r*4 + e
  const int wt = tid >> 4;   // w = wt*8 + wi
  __shared__ float k_s[25 * 128];
  __shared__ float q_s[25 * 64];

  // swizzled local k offsets (floats within a 128-float ij row)
  int koff[2];
  #pragma unroll
  for (int r = 0; r < 2; ++r) {
    const int s_un = lh * 32 + lt * 2 + r;
    const int slot = s_un ^ ((s_un >> 2) >> 1);
    koff[r] = (slot - lh * 32) * 4;
  }

  float acc[8][8];
  #pragma unroll
  for (int a = 0; a < 8; ++a)
    #pragma unroll
    for (int b = 0; b < 8; ++b) acc[a][b] = 0.f;

  const float* qn = qpad + (size_t)(n * CI + cih * 32) * QPS + (size_t)(4 * h) * 264;
  const float* kpb = kp + ((size_t)(n * CI + cih * 32)) * 6400;

  for (int cc = 0; cc < 32; ++cc) {
    __syncthreads();
    // stage K half: 25 ij x 32 float4 (=128 floats) each
    const float4* ksrc = (const float4*)(kpb + (size_t)cc * 6400);
    #pragma unroll
    for (int it = 0; it < 7; ++it) {
      const int idx = tid + it * 128;
      if (idx < 800) {
        const int ij = idx >> 5, f4 = idx & 31;
        *(float4*)&k_s[idx * 4] = ksrc[ij * 64 + lh * 32 + f4];
      }
    }
    // stage Q: im2col from padded plane
    const float* qp = qn + (size_t)cc * QPS;
    #pragma unroll
    for (int it = 0; it < 13; ++it) {
      const int s = tid + it * 128;
      if (s < 1600) {
        const int ij = s >> 6, w = s & 63;
        const int i = (ij * 205) >> 10;
        const int j = ij - 5 * i;
        q_s[s] = qp[i * 264 + 4 * w + j];
      }
    }
    __syncthreads();

    #pragma unroll 5
    for (int ij = 0; ij < 25; ++ij) {
      const float* kb = &k_s[ij * 128];
      float kk[8];
      #pragma unroll
      for (int r = 0; r < 2; ++r) {
        const float4 kv = *(const float4*)(kb + koff[r]);
        kk[r * 4 + 0] = kv.x; kk[r * 4 + 1] = kv.y;
        kk[r * 4 + 2] = kv.z; kk[r * 4 + 3] = kv.w;
      }
      const float4 q0 = *(const float4*)&q_s[ij * 64 + wt * 8];
      const float4 q1 = *(const float4*)&q_s[ij * 64 + wt * 8 + 4];
      const float qq[8] = {q0.x, q0.y, q0.z, q0.w, q1.x, q1.y, q1.z, q1.w};
      #pragma unroll
      for (int li = 0; li < 8; ++li)
        #pragma unroll
        for (int wi = 0; wi < 8; ++wi)
          acc[li][wi] = fmaf(kk[li], qq[wi], acc[li][wi]);
    }
  }

  float* dst = scores + (size_t)cih * half_stride + ((size_t)(n * 64 + h) * 64) * 256;
  #pragma unroll
  for (int wi = 0; wi < 8; ++wi) {
    float* d2 = dst + (size_t)(wt * 8 + wi) * 256 + lh * 128 + lt * 8;
    #pragma unroll
    for (int r = 0; r < 2; ++r) {
      *(float4*)(d2 + r * 4) = make_float4(acc[r * 4 + 0][wi], acc[r * 4 + 1][wi],
                                           acc[r * 4 + 2][wi], acc[r * 4 + 3][wi]);
    }
  }
}

// ---------------- softmax over l (sums 2 cih partials), writes bf16 wn ----------------
__global__ void softmax_rows(const float* __restrict__ sa, const float* __restrict__ sb,
                             unsigned short* __restrict__ wnbf) {
  const int row = blockIdx.x * 4 + (threadIdx.x >> 6);
  const int lane = threadIdx.x & 63;
  const size_t idx = (size_t)row * 64 + lane;
  const float4 a = ((const float4*)sa)[idx];
  const float4 b = ((const float4*)sb)[idx];
  float4 v = make_float4(a.x + b.x, a.y + b.y, a.z + b.z, a.w + b.w);
  float m = fmaxf(fmaxf(v.x, v.y), fmaxf(v.z, v.w));
  for (int off = 32; off; off >>= 1) m = fmaxf(m, __shfl_xor(m, off));
  float4 e;
  e.x = __expf(v.x - m); e.y = __expf(v.y - m);
  e.z = __expf(v.z - m); e.w = __expf(v.w - m);
  float s = e.x + e.y + e.z + e.w;
  for (int off = 32; off; off >>= 1) s += __shfl_xor(s, off);
  const float inv = 1.0f / s;
  unsigned long long pack = (unsigned long long)f2bf(e.x * inv)
                          | ((unsigned long long)f2bf(e.y * inv) << 16)
                          | ((unsigned long long)f2bf(e.z * inv) << 32)
                          | ((unsigned long long)f2bf(e.w * inv) << 48);
  *(unsigned long long*)(wnbf + idx * 4) = pack;
}

// ---------------- v-patch transposed bf16 gather: vpt[n][bij][l] ----------------
// grid (NPAD/4, NB), block 256: 4 bij rows x 64 l4-threads (4 l each)
__global__ void vpt_gather(const float* __restrict__ vfea, unsigned short* __restrict__ vpt) {
  const int l4 = threadIdx.x & 63, bj = threadIdx.x >> 6;
  const int bij = blockIdx.x * 4 + bj;
  const int n = blockIdx.y;
  const int ij = bij >> 6, b = bij & 63;
  unsigned short o[4] = {0, 0, 0, 0};
  if (ij < 25) {
    const int i = ij / 5, j = ij % 5;
    const int ly = l4 >> 2;
    const int r = 4 * ly + i;
    if (r < HK) {
      const float* base = vfea + ((size_t)(n * COC + b) * HK + r) * HK;
      #pragma unroll
      for (int e = 0; e < 4; ++e) {
        const int lx = (l4 & 3) * 4 + e;
        const int c = 4 * lx + j;
        if (c < HK) o[e] = f2bf(base[c]);
      }
    }
  }
  unsigned long long pack = (unsigned long long)o[0] | ((unsigned long long)o[1] << 16)
                          | ((unsigned long long)o[2] << 32) | ((unsigned long long)o[3] << 48);
  *(unsigned long long*)(vpt + ((size_t)n * NPAD + bij) * 256 + l4 * 4) = pack;
}

// ---------------- PV MFMA GEMM: U[4096][NPAD] = wn[4096][256] x vpt^T ----------------
// grid (64 mt, 13 nt, nz), block 256 = 4 waves (2m x 2n); wave tile 32m x 64n
__global__ __launch_bounds__(256) void pv_mfma(
    const unsigned short* __restrict__ wnb, const unsigned short* __restrict__ vpt,
    float* __restrict__ C0) {
  const int nz = blockIdx.z;
  const unsigned short* A = wnb + (size_t)nz * 4096 * 256;
  const unsigned short* B = vpt + (size_t)nz * NPAD * 256;
  float* C = C0 + (size_t)nz * 4096 * NPAD;
  const int m0 = blockIdx.x * 64;
  const int n0 = blockIdx.y * 128;
  const int tid = threadIdx.x;
  const int lane = tid & 63;
  const int wv = tid >> 6;
  const int wm = wv >> 1, wn_ = wv & 1;
  const int col = lane & 15, kg = lane >> 4;

  __shared__ unsigned short A_s[64 * 40];
  __shared__ unsigned short B_s[128 * 40];

  f32x4 acc[2][4];
  #pragma unroll
  for (int fm = 0; fm < 2; ++fm)
    #pragma unroll
    for (int fn = 0; fn < 4; ++fn) acc[fm][fn] = (f32x4){0.f, 0.f, 0.f, 0.f};

  for (int k0 = 0; k0 < 256; k0 += 32) {
    __syncthreads();
    {
      const int row = tid >> 2, q = tid & 3;
      *(float4*)&A_s[row * 40 + q * 8] =
          *(const float4*)&A[(size_t)(m0 + row) * 256 + k0 + q * 8];
    }
    {
      const int row = tid >> 1, hh = tid & 1;
      *(float4*)&B_s[row * 40 + hh * 16] =
          *(const float4*)&B[(size_t)(n0 + row) * 256 + k0 + hh * 16];
      *(float4*)&B_s[row * 40 + hh * 16 + 8] =
          *(const float4*)&B[(size_t)(n0 + row) * 256 + k0 + hh * 16 + 8];
    }
    __syncthreads();

    bf16x8s a[2], b[4];
    #pragma unroll
    for (int fm = 0; fm < 2; ++fm)
      a[fm] = *(const bf16x8s*)&A_s[(wm * 32 + fm * 16 + col) * 40 + kg * 8];
    #pragma unroll
    for (int fn = 0; fn < 4; ++fn)
      b[fn] = *(const bf16x8s*)&B_s[(wn_ * 64 + fn * 16 + col) * 40 + kg * 8];
    #pragma unroll
    for (int fm = 0; fm < 2; ++fm)
      #pragma unroll
      for (int fn = 0; fn < 4; ++fn)
        acc[fm][fn] = __builtin_amdgcn_mfma_f32_16x16x32_bf16(a[fm], b[fn], acc[fm][fn], 0, 0, 0);
  }

  #pragma unroll
  for (int fm = 0; fm < 2; ++fm) {
    #pragma unroll
    for (int fn = 0; fn < 4; ++fn) {
      const int cg = n0 + wn_ * 64 + fn * 16 + col;
      #pragma unroll
      for (int r = 0; r < 4; ++r) {
        const int rg = m0 + wm * 32 + fm * 16 + kg * 4 + r;
        C[(size_t)rg * NPAD + cg] = acc[fm][fn][r];
      }
    }
  }
}

// ---------------- conv-transpose gather (+ /6) -> resbf bf16 [258][264][64co] ----------------
__global__ __launch_bounds__(256) void u_scatter(
    const float* __restrict__ U0, unsigned short* __restrict__ resbf, int n0) {
  const int n = n0 + blockIdx.z;
  const float* U = U0 + (size_t)blockIdx.z * 4096 * NPAD;
  const int y = blockIdx.y;
  const int xt = blockIdx.x;
  const int tid = threadIdx.x;
  __shared__ float t_lds[64][65];
  const int ym = (y + 1) >> 2, yr = (y + 1) & 3;
  const bool v0 = (ym < 64);
  const bool v1 = (yr == 0 && ym >= 1);
  const int b = tid & 63, xg = tid >> 6;
  for (int xi = 0; xi < 16; ++xi) {
    const int x = xt * 64 + xg * 16 + xi;
    const int xm = (x + 1) >> 2, xr = (x + 1) & 3;
    const bool u0 = (xm < 64);
    const bool u1 = (xr == 0 && xm >= 1);
    float s = 0.f;
    if (v0) {
      const size_t rb = (size_t)(ym * 64) * NPAD;
      if (u0) s += U[rb + (size_t)xm * NPAD + (yr * 5 + xr) * 64 + b];
      if (u1) s += U[rb + (size_t)(xm - 1) * NPAD + (yr * 5 + 4) * 64 + b];
    }
    if (v1) {
      const size_t rb = (size_t)((ym - 1) * 64) * NPAD;
      if (u0) s += U[rb + (size_t)xm * NPAD + (4 * 5 + xr) * 64 + b];
      if (u1) s += U[rb + (size_t)(xm - 1) * NPAD + (4 * 5 + 4) * 64 + b];
    }
    t_lds[xg * 16 + xi][b] = s * (1.0f / 6.0f);
  }
  __syncthreads();
  unsigned short* db = resbf + (((size_t)n * 258 + (y + 1)) * 264) * 64;
  for (int xi = 0; xi < 16; ++xi) {
    const int x = xg * 16 + xi;
    db[(size_t)(xt * 64 + x + 1) * 64 + b] = f2bf(t_lds[x][b]);
  }
}

extern "C" void kernel_launch(void* const* d_in, const int* in_sizes, int n_in,
                              void* d_out, int out_size, void* d_ws, size_t ws_size,
                              hipStream_t stream) {
  const float* ms   = (const float*)d_in[0];
  const float* pan  = (const float*)d_in[1];
  const float* pan2 = (const float*)d_in[2];
  const float* Wq   = (const float*)d_in[3];
  const float* bq   = (const float*)d_in[4];
  const float* Wk   = (const float*)d_in[5];
  const float* bk   = (const float*)d_in[6];
  const float* Wv   = (const float*)d_in[7];
  const float* bv   = (const float*)d_in[8];
  const float* Wr   = (const float*)d_in[9];
  const float* br   = (const float*)d_in[10];
  float* out = (float*)d_out;

  float* ws = (float*)d_ws;
  const size_t SZ_QP  = (size_t)NB * CI * QPS;               // 34.74M fp32 (q_pad; resbf aliases)
  const size_t SZ_K   = (size_t)NB * CI * HK * HK;           // 2.10M
  const size_t SZ_WN  = (size_t)NB * 64 * 64 * LL;           // 8.39M (scores half size)
  const size_t SZ_VPT = (size_t)NB * NPAD * 256 / 2;         // 1.70M floats (bf16)
  const size_t SZ_KP  = (size_t)NB * CI * 25 * 256;          // 3.28M
  const size_t SZ_PS  = (size_t)NB * CI * 66 * 72;           // 2.43M
  const size_t SZ_WI  = 23040;
  const size_t SZ_U1  = (size_t)4096 * NPAD;                 // 6.82M per batch
  const size_t SZ_UA  = (size_t)NB * SZ_U1;                  // 54.53M

  float* q_pad   = ws;
  float* k_fea   = q_pad + SZ_QP;
  float* v_fea   = k_fea + SZ_K;
  float* wnbf_f  = v_fea + SZ_K;          // bf16 wn: SZ_WN/2 floats
  float* vptbf_f = wnbf_f + SZ_WN / 2;
  float* kp      = vptbf_f + SZ_VPT;
  float* norms   = kp + SZ_KP;
  float* kscale  = norms + NB * LL;
  float* wtk     = kscale + 64;
  float* wtv     = wtk + 36864;
  float* wimgqf  = wtv + 36864;
  float* wimgrf  = wimgqf + SZ_WI;
  float* ms_pad  = wimgrf + SZ_WI;
  float* pan2pad = ms_pad + SZ_PS;
  float* tail    = pan2pad + SZ_PS;       // panbf -> scores(2x) -> U

  unsigned short* wimgq = (unsigned short*)wimgqf;
  unsigned short* wimgr = (unsigned short*)wimgrf;
  unsigned short* wnbf  = (unsigned short*)wnbf_f;
  unsigned short* vptbf = (unsigned short*)vptbf_f;
  unsigned short* panbf = (unsigned short*)tail;
  float* scores  = tail;
  float* U       = tail;
  unsigned short* resbf = (unsigned short*)q_pad;   // q_pad dead after qk_scores

  const size_t base_elems = (size_t)(tail - ws);
  const bool batched = ws_size >= (base_elems + SZ_UA) * sizeof(float);

  // weight prep
  wtrans8_kernel<<<dim3(9, 64), 64, 0, stream>>>(Wk, wtk);
  wtrans8_kernel<<<dim3(9, 64), 64, 0, stream>>>(Wv, wtv);
  wtrans_mfma<<<dim3(18), 256, 0, stream>>>(Wq, wimgq);
  wtrans_mfma<<<dim3(18), 256, 0, stream>>>(Wr, wimgr);

  // pad inputs
  {
    const int totS = NB * CI * HK * HK;
    pad_copy<<<dim3((totS + 255) / 256), 256, 0, stream>>>(ms, ms_pad, HK, HK, 72, totS);
    pad_copy<<<dim3((totS + 255) / 256), 256, 0, stream>>>(pan2, pan2pad, HK, HK, 72, totS);
    border_zero<<<dim3(NB * CI), 256, 0, stream>>>(ms_pad, HK, HK, 72);
    border_zero<<<dim3(NB * CI), 256, 0, stream>>>(pan2pad, HK, HK, 72);
    pad_rci<<<dim3(4, 258, NB), 256, 0, stream>>>(pan, panbf);
    qpad_zero<<<dim3(NB * CI), 256, 0, stream>>>(q_pad);
  }

  // feature convs: k,v small (fp32); q big (MFMA bf16)
  conv3s<<<dim3(HK / 64, HK / 8, NB * 8), 256, 0, stream>>>(pan2pad, wtk, bk, k_fea, HK, HK, 72, HK * HK, HK);
  conv3s<<<dim3(HK / 64, HK / 8, NB * 8), 256, 0, stream>>>(ms_pad,  wtv, bv, v_fea, HK, HK, 72, HK * HK, HK);
  conv3m<<<dim3(4, 256, NB), 256, 0, stream>>>(panbf, wimgq, bq, q_pad, QPS, 264);

  // k-patch max norm -> scale
  knorm_kernel<<<dim3(LL, NB), 64, 0, stream>>>(k_fea, norms);
  kscale_kernel<<<NB, 256, 0, stream>>>(norms, kscale);

  // K im2col (kscale folded, swizzled)
  kp_gather<<<dim3(25, CI, NB), 256, 0, stream>>>(k_fea, kscale, kp);

  // QK partial scores (2 cih x 2 lh) + softmax -> bf16 wn
  qk_scores<<<dim3(64, 4, NB), 128, 0, stream>>>(q_pad, kp, scores, SZ_WN);
  softmax_rows<<<dim3(8192), 256, 0, stream>>>(scores, scores + SZ_WN, wnbf);

  // resbf borders (aliases q_pad; q_pad dead after qk_scores)
  rbz<<<dim3(NB), 256, 0, stream>>>(resbf);

  // v patch bf16 transposed matrix
  vpt_gather<<<dim3(NPAD / 4, NB), 256, 0, stream>>>(v_fea, vptbf);

  // PV MFMA + conv-transpose gather (U reuses tail; scores dead after softmax)
  if (batched) {
    pv_mfma<<<dim3(64, 13, NB), 256, 0, stream>>>(wnbf, vptbf, U);
    u_scatter<<<dim3(4, HQ, NB), 256, 0, stream>>>(U, resbf, 0);
  } else {
    for (int n = 0; n < NB; ++n) {
      pv_mfma<<<dim3(64, 13, 1), 256, 0, stream>>>(wnbf + (size_t)n * 4096 * 256,
                                                   vptbf + (size_t)n * NPAD * 256, U);
      u_scatter<<<dim3(4, HQ, 1), 256, 0, stream>>>(U, resbf, n);
    }
  }

  // final conv (MFMA bf16) -> d_out fp32
  conv3m<<<dim3(4, 256, NB), 256, 0, stream>>>(resbf, wimgr, br, out, HQ * HQ, HQ);
}

// Round 11
// 980.007 us; speedup vs baseline: 7.1267x; 1.0605x over previous
//
#include <hip/hip_runtime.h>
#include <math.h>

#define NB   8
#define CI   64
#define COC  64
#define HQ   256
#define HK   64
#define KS   5
#define LL   256
#define NPAD 1664
#define QP2  (257 * 264)   // q bf16 plane (rows 0..256, row 256 = same-pad zeros)

typedef __attribute__((ext_vector_type(8))) short bf16x8s;
typedef __attribute__((ext_vector_type(4))) float f32x4;

static __device__ __forceinline__ unsigned short f2bf(float f) {
  union { float f; unsigned u; } v; v.f = f;
  unsigned r = v.u + 0x7FFF + ((v.u >> 16) & 1);
  return (unsigned short)(r >> 16);
}
static __device__ __forceinline__ float bf2f(unsigned short h) {
  union { unsigned u; float f; } v; v.u = ((unsigned)h) << 16; return v.f;
}

// ---------------- weight transpose for conv3s: [CO][CI][3][3] -> [cogrp8][CI][tap][8] ----------------
__global__ void wtrans8_kernel(const float* __restrict__ Wt, float* __restrict__ Wo) {
  const int co = threadIdx.x;
  const int tap = blockIdx.x;
  const int ci = blockIdx.y;
  Wo[(((co >> 3) * 64 + ci) * 9 + tap) * 8 + (co & 7)] = Wt[(co * 64 + ci) * 9 + tap];
}

// ---------------- weight image for conv3m: [18 chunk][64 co][40] bf16 ----------------
__global__ void wtrans_mfma(const float* __restrict__ Wt, unsigned short* __restrict__ wimg) {
  const int ch = blockIdx.x;
  const int tap = ch >> 1, cih = ch & 1;
  for (int idx = threadIdx.x; idx < 64 * 40; idx += 256) {
    const int co = idx / 40, s = idx - co * 40;
    unsigned short v = 0;
    if (s < 32) v = f2bf(Wt[((size_t)co * 64 + cih * 32 + s) * 9 + tap]);
    wimg[(size_t)ch * 64 * 40 + idx] = v;
  }
}

// ---------------- pad copy (fp32 ci-major, for small convs) ----------------
__global__ void pad_copy(const float* __restrict__ src, float* __restrict__ dst,
                         int H, int W, int S, int total) {
  const int idx = blockIdx.x * 256 + threadIdx.x;
  if (idx >= total) return;
  const int p = idx / (H * W);
  const int rem = idx - p * H * W;
  const int y = rem / W, x = rem - y * W;
  dst[((size_t)p * (H + 2) + y + 1) * S + x + 1] = src[idx];
}

__global__ void border_zero(float* __restrict__ dst, int H, int W, int S) {
  const int p = blockIdx.x;
  float* b = dst + (size_t)p * (H + 2) * S;
  for (int c = threadIdx.x; c < S; c += 256) {
    b[c] = 0.f;
    b[(size_t)(H + 1) * S + c] = 0.f;
  }
  for (int r = 1 + threadIdx.x; r <= H; r += 256) {
    b[(size_t)r * S] = 0.f;
    b[(size_t)r * S + W + 1] = 0.f;
  }
}

// ---------------- pan fp32 [ci][256][256] -> bf16 [row 258][col 264][ci 64] ----------------
__global__ void pad_rci(const float* __restrict__ src, unsigned short* __restrict__ dst) {
  const int ct = blockIdx.x, g = blockIdx.y, n = blockIdx.z;
  const int c0 = ct * 66;
  __shared__ float t[64 * 68];
  const int jl = threadIdx.x & 63, cg = threadIdx.x >> 6;
  const int row = g - 1;
  const bool rok = (row >= 0 && row < 256);
  for (int ci = cg; ci < 64; ci += 4) {
    #pragma unroll
    for (int jb = 0; jb < 2; ++jb) {
      const int j = jl + jb * 64;
      if (j < 66) {
        const int x = c0 - 1 + j;
        float v = 0.f;
        if (rok && x >= 0 && x < 256)
          v = src[(((size_t)n * 64 + ci) * 256 + row) * 256 + x];
        t[ci * 68 + j] = v;
      }
    }
  }
  __syncthreads();
  const int cil = threadIdx.x & 63, cc = threadIdx.x >> 6;
  unsigned short* db = dst + (((size_t)n * 258 + g) * 264) * 64;
  for (int c = cc; c < 66; c += 4)
    db[(size_t)(c0 + c) * 64 + cil] = f2bf(t[cil * 68 + c]);
}

// zero borders of resbf ([258][264][64])
__global__ void rbz(unsigned short* __restrict__ resbf) {
  const int n = blockIdx.x;
  unsigned short* b = resbf + (size_t)n * 258 * 264 * 64;
  for (int idx = threadIdx.x; idx < 264 * 64; idx += 256) {
    b[idx] = 0;
    b[(size_t)257 * 264 * 64 + idx] = 0;
  }
  for (int idx = threadIdx.x; idx < 256 * 64; idx += 256) {
    const int r = idx >> 6, ci = idx & 63;
    b[((size_t)(r + 1) * 264) * 64 + ci] = 0;
    b[((size_t)(r + 1) * 264 + 257) * 64 + ci] = 0;
  }
}

// zero same-pad strips of q hi/lo ([257][264][64]): row 256 full, col 256 rows 0..255
__global__ void qz(unsigned short* __restrict__ qhi, unsigned short* __restrict__ qlo) {
  const int n = blockIdx.x;
  unsigned short* bh = qhi + (size_t)n * QP2 * 64;
  unsigned short* bl = qlo + (size_t)n * QP2 * 64;
  for (int g = threadIdx.x; g < 4224; g += 256) {
    ((unsigned long long*)(bh + (size_t)256 * 264 * 64))[g] = 0ull;
    ((unsigned long long*)(bl + (size_t)256 * 264 * 64))[g] = 0ull;
  }
  for (int g = threadIdx.x; g < 4096; g += 256) {
    const int r = g >> 4, q = g & 15;
    const size_t off = ((size_t)r * 264 + 256) * 64 + q * 4;
    *(unsigned long long*)(bh + off) = 0ull;
    *(unsigned long long*)(bl + off) = 0ull;
  }
}

// ---------------- MFMA conv 3x3 + bias + leaky relu (bf16 in, fp32 planar out) ----------------
__global__ __launch_bounds__(256) void conv3m(
    const unsigned short* __restrict__ inbf,
    const unsigned short* __restrict__ wimg,
    const float* __restrict__ bias,
    float* __restrict__ out, int PS, int RS) {
  const int x0 = blockIdx.x * 64;
  const int y  = blockIdx.y;
  const int n  = blockIdx.z;
  const int tid = threadIdx.x;
  const int lane = tid & 63;
  const int wv = tid >> 6;
  const int col = lane & 15;
  const int kg  = lane >> 4;

  __shared__ unsigned short in_s[3 * 66 * 72];

  {
    const unsigned short* src = inbf + ((size_t)n * 258 + y) * 264 * 64;
    if (tid < 198) {
      const int r = tid / 66, c = tid - r * 66;
      const unsigned short* s = src + ((size_t)r * 264 + x0 + c) * 64;
      unsigned short* d = &in_s[(r * 66 + c) * 72];
      #pragma unroll
      for (int q = 0; q < 8; ++q)
        *(float4*)(d + q * 8) = *(const float4*)(s + q * 8);
    }
  }
  __syncthreads();

  f32x4 acc[4];
  #pragma unroll
  for (int p = 0; p < 4; ++p) acc[p] = (f32x4){0.f, 0.f, 0.f, 0.f};

  const unsigned short* wbase = wimg + ((size_t)(wv * 16 + col)) * 40 + kg * 8;

  #pragma unroll 2
  for (int ch = 0; ch < 18; ++ch) {
    const int tap = ch >> 1, cih = ch & 1;
    const int dy = tap / 3, dx = tap - dy * 3;
    const bf16x8s a = *(const bf16x8s*)(wbase + (size_t)ch * 64 * 40);
    const int cix = cih * 32 + kg * 8;
    #pragma unroll
    for (int p = 0; p < 4; ++p) {
      const int c = p * 16 + col + dx;
      const bf16x8s b = *(const bf16x8s*)&in_s[(dy * 66 + c) * 72 + cix];
      acc[p] = __builtin_amdgcn_mfma_f32_16x16x32_bf16(a, b, acc[p], 0, 0, 0);
    }
  }

  const int cobase = wv * 16 + kg * 4;
  const float4 bb = *(const float4*)&bias[cobase];
  const float bv[4] = {bb.x, bb.y, bb.z, bb.w};
  #pragma unroll
  for (int p = 0; p < 4; ++p) {
    const int x = x0 + p * 16 + col;
    #pragma unroll
    for (int r = 0; r < 4; ++r) {
      float t = acc[p][r] + bv[r];
      t = t > 0.f ? t : 0.01f * t;
      out[(size_t)(n * 64 + cobase + r) * PS + (size_t)y * RS + x] = t;
    }
  }
}

// ---------------- MFMA conv for Q: writes bf16 hi/lo in [257][264][64co] rci layout ----------------
__global__ __launch_bounds__(256) void conv3mq(
    const unsigned short* __restrict__ inbf,
    const unsigned short* __restrict__ wimg,
    const float* __restrict__ bias,
    unsigned short* __restrict__ qhi, unsigned short* __restrict__ qlo) {
  const int x0 = blockIdx.x * 64;
  const int y  = blockIdx.y;
  const int n  = blockIdx.z;
  const int tid = threadIdx.x;
  const int lane = tid & 63;
  const int wv = tid >> 6;
  const int col = lane & 15;
  const int kg  = lane >> 4;

  __shared__ unsigned short in_s[3 * 66 * 72];

  {
    const unsigned short* src = inbf + ((size_t)n * 258 + y) * 264 * 64;
    if (tid < 198) {
      const int r = tid / 66, c = tid - r * 66;
      const unsigned short* s = src + ((size_t)r * 264 + x0 + c) * 64;
      unsigned short* d = &in_s[(r * 66 + c) * 72];
      #pragma unroll
      for (int q = 0; q < 8; ++q)
        *(float4*)(d + q * 8) = *(const float4*)(s + q * 8);
    }
  }
  __syncthreads();

  f32x4 acc[4];
  #pragma unroll
  for (int p = 0; p < 4; ++p) acc[p] = (f32x4){0.f, 0.f, 0.f, 0.f};

  const unsigned short* wbase = wimg + ((size_t)(wv * 16 + col)) * 40 + kg * 8;

  #pragma unroll 2
  for (int ch = 0; ch < 18; ++ch) {
    const int tap = ch >> 1, cih = ch & 1;
    const int dy = tap / 3, dx = tap - dy * 3;
    const bf16x8s a = *(const bf16x8s*)(wbase + (size_t)ch * 64 * 40);
    const int cix = cih * 32 + kg * 8;
    #pragma unroll
    for (int p = 0; p < 4; ++p) {
      const int c = p * 16 + col + dx;
      const bf16x8s b = *(const bf16x8s*)&in_s[(dy * 66 + c) * 72 + cix];
      acc[p] = __builtin_amdgcn_mfma_f32_16x16x32_bf16(a, b, acc[p], 0, 0, 0);
    }
  }

  const int cobase = wv * 16 + kg * 4;
  const float4 bb = *(const float4*)&bias[cobase];
  const float bv[4] = {bb.x, bb.y, bb.z, bb.w};
  unsigned short* hb = qhi + ((size_t)n * 257 + y) * 264 * 64;
  unsigned short* lb = qlo + ((size_t)n * 257 + y) * 264 * 64;
  #pragma unroll
  for (int p = 0; p < 4; ++p) {
    const int x = x0 + p * 16 + col;
    unsigned long long hp = 0, lp = 0;
    #pragma unroll
    for (int r = 0; r < 4; ++r) {
      float t = acc[p][r] + bv[r];
      t = t > 0.f ? t : 0.01f * t;
      const unsigned short h = f2bf(t);
      const unsigned short lo = f2bf(t - bf2f(h));
      hp |= ((unsigned long long)h) << (16 * r);
      lp |= ((unsigned long long)lo) << (16 * r);
    }
    *(unsigned long long*)(hb + (size_t)x * 64 + cobase) = hp;
    *(unsigned long long*)(lb + (size_t)x * 64 + cobase) = lp;
  }
}

// ---------------- small conv 3x3 (fp32, for k/v 64x64) ----------------
__global__ __launch_bounds__(256) void conv3s(
    const float* __restrict__ inp, const float* __restrict__ Wts,
    const float* __restrict__ bias, float* __restrict__ out,
    int H, int Wd, int S, int outPS, int outRS) {
  const int x0 = blockIdx.x * 64;
  const int y0 = blockIdx.y * 8;
  const int z  = blockIdx.z;
  const int n  = z >> 3;
  const int cog = z & 7;
  const int tid = threadIdx.x;
  const int xq = tid & 15;
  const int yt = (tid >> 4) & 7;
  const int cg = tid >> 7;
  const int Hp = H + 2;

  __shared__ float in_s[10 * 72];
  __shared__ float w_s[CI * 9 * 8];

  {
    const float* wbase = Wts + (size_t)cog * (CI * 9 * 8);
    for (int idx = tid; idx < CI * 9 * 2; idx += 256)
      *(float4*)&w_s[idx * 4] = *(const float4*)(wbase + idx * 4);
  }

  float acc[4][4];
  #pragma unroll
  for (int a = 0; a < 4; ++a)
    #pragma unroll
    for (int b = 0; b < 4; ++b) acc[a][b] = 0.f;

  const bool hasA = tid < 180;
  const int arow = tid / 18, ac4 = tid - arow * 18;
  const float* gplane0 = inp + (size_t)(n * CI) * Hp * S;
  const size_t aoff = ((size_t)(y0 + arow)) * S + x0 + ac4 * 4;

  float4 sA = make_float4(0.f, 0.f, 0.f, 0.f);
  if (hasA) sA = *(const float4*)(gplane0 + aoff);

  for (int ci = 0; ci < CI; ++ci) {
    __syncthreads();
    if (hasA) *(float4*)&in_s[arow * 72 + ac4 * 4] = sA;
    if (ci + 1 < CI && hasA)
      sA = *(const float4*)(gplane0 + (size_t)(ci + 1) * Hp * S + aoff);
    __syncthreads();

    float xin[3][8];
    const int cb = xq * 4;
    #pragma unroll
    for (int r = 0; r < 3; ++r) {
      const float4 xa = *(const float4*)&in_s[(yt + r) * 72 + cb];
      const float4 xb = *(const float4*)&in_s[(yt + r) * 72 + cb + 4];
      xin[r][0] = xa.x; xin[r][1] = xa.y; xin[r][2] = xa.z; xin[r][3] = xa.w;
      xin[r][4] = xb.x; xin[r][5] = xb.y; xin[r][6] = xb.z; xin[r][7] = xb.w;
    }

    const float* wci = &w_s[(ci * 9) * 8 + cg * 4];
    #pragma unroll
    for (int ky = 0; ky < 3; ++ky) {
      #pragma unroll
      for (int kx = 0; kx < 3; ++kx) {
        const float4 w4 = *(const float4*)&wci[(ky * 3 + kx) * 8];
        const float wv[4] = {w4.x, w4.y, w4.z, w4.w};
        #pragma unroll
        for (int c = 0; c < 4; ++c)
          #pragma unroll
          for (int dx = 0; dx < 4; ++dx)
            acc[c][dx] = fmaf(wv[c], xin[ky][dx + kx], acc[c][dx]);
      }
    }
  }

  #pragma unroll
  for (int c = 0; c < 4; ++c) {
    const int co = cog * 8 + cg * 4 + c;
    const float bv = bias[co];
    float4 o;
    float t;
    t = acc[c][0] + bv; o.x = t > 0.f ? t : 0.01f * t;
    t = acc[c][1] + bv; o.y = t > 0.f ? t : 0.01f * t;
    t = acc[c][2] + bv; o.z = t > 0.f ? t : 0.01f * t;
    t = acc[c][3] + bv; o.w = t > 0.f ? t : 0.01f * t;
    *(float4*)(out + (size_t)(n * COC + co) * outPS + (size_t)(y0 + yt) * outRS + x0 + xq * 4) = o;
  }
}

// ---------------- k-patch squared norms ----------------
__global__ void knorm_kernel(const float* __restrict__ kfea, float* __restrict__ norms) {
  const int l = blockIdx.x, n = blockIdx.y, c = threadIdx.x;
  const int ly = l >> 4, lx = l & 15;
  const float* base = kfea + ((size_t)(n * CI + c) * HK) * HK;
  float ss = 0.f;
  #pragma unroll
  for (int i = 0; i < KS; ++i) {
    const int r = 4 * ly + i;
    if (r >= HK) continue;
    #pragma unroll
    for (int j = 0; j < KS; ++j) {
      const int cc = 4 * lx + j;
      if (cc >= HK) continue;
      const float v = base[r * HK + cc];
      ss = fmaf(v, v, ss);
    }
  }
  for (int off = 32; off; off >>= 1) ss += __shfl_down(ss, off);
  if (c == 0) norms[n * LL + l] = ss;
}

__global__ void kscale_kernel(const float* __restrict__ norms, float* __restrict__ kscale) {
  const int n = blockIdx.x, t = threadIdx.x;
  float v = norms[n * LL + t];
  for (int off = 32; off; off >>= 1) v = fmaxf(v, __shfl_down(v, off));
  __shared__ float red[4];
  if ((t & 63) == 0) red[t >> 6] = v;
  __syncthreads();
  if (t == 0) {
    const float m = fmaxf(fmaxf(red[0], red[1]), fmaxf(red[2], red[3]));
    kscale[n] = 10.0f / sqrtf(m);
  }
}

// ---------------- K im2col hi/lo bf16: k[n][chunk 50][l 256][s 32] ----------------
// chunk = tap*2 + cih; grid (25 tap, 2 cih, NB), block 256 = 32 s x 8 lg
__global__ void kp_gather2(const float* __restrict__ kfea, const float* __restrict__ kscale,
                           unsigned short* __restrict__ khi, unsigned short* __restrict__ klo) {
  const int tap = blockIdx.x, cih = blockIdx.y, n = blockIdx.z;
  const int s = threadIdx.x & 31, lg = threadIdx.x >> 5;
  const int i = tap / 5, j = tap % 5;
  const float sc = kscale[n];
  const float* kb = kfea + ((size_t)(n * 64 + cih * 32 + s) * 64) * 64;
  const size_t ob = (((size_t)n * 50 + tap * 2 + cih) * 256) * 32;
  for (int lb = 0; lb < 32; ++lb) {
    const int l = lb * 8 + lg;
    const int r = 4 * (l >> 4) + i, c = 4 * (l & 15) + j;
    float v = 0.f;
    if (r < 64 && c < 64) v = kb[r * 64 + c] * sc;
    const unsigned short h = f2bf(v);
    khi[ob + (size_t)l * 32 + s] = h;
    klo[ob + (size_t)l * 32 + s] = f2bf(v - bf2f(h));
  }
}

// ---------------- QK MFMA: scores[n][4096 pix][256 l], hi/lo 3-product bf16 ----------------
// grid (64 y, NB), block 256 = 4 waves; wave wv covers l-quarter wv*64..+64, all 64 x.
__global__ __launch_bounds__(256, 2) void qk_mfma(
    const unsigned short* __restrict__ qhi, const unsigned short* __restrict__ qlo,
    const unsigned short* __restrict__ khi, const unsigned short* __restrict__ klo,
    float* __restrict__ scores) {
  const int y = blockIdx.x, n = blockIdx.y;
  const int tid = threadIdx.x;
  const int lane = tid & 63, wv = tid >> 6;
  const int col = lane & 15, kg = lane >> 4;

  __shared__ unsigned short ks[2][2][256 * 36];

  f32x4 acc[4][4];
  #pragma unroll
  for (int fm = 0; fm < 4; ++fm)
    #pragma unroll
    for (int fn = 0; fn < 4; ++fn) acc[fm][fn] = (f32x4){0.f, 0.f, 0.f, 0.f};

  const unsigned short* khb = khi + (size_t)n * 50 * 8192;
  const unsigned short* klb = klo + (size_t)n * 50 * 8192;
  const unsigned short* qhb = qhi + (size_t)n * QP2 * 64;
  const unsigned short* qlb = qlo + (size_t)n * QP2 * 64;

  int segoff[4];
  #pragma unroll
  for (int it = 0; it < 4; ++it) {
    const int s = tid + it * 256;
    segoff[it] = (s >> 2) * 32 + (s & 3) * 8;   // global elem offset within chunk
  }
  int lsoff[4];
  #pragma unroll
  for (int it = 0; it < 4; ++it) {
    const int s = tid + it * 256;
    lsoff[it] = (s >> 2) * 36 + (s & 3) * 8;    // LDS elem offset (padded row 36)
  }

  float4 ph[4], pl[4];
  #pragma unroll
  for (int it = 0; it < 4; ++it) {
    ph[it] = *(const float4*)(khb + segoff[it]);
    pl[it] = *(const float4*)(klb + segoff[it]);
  }

  int cur = 0;
  for (int ch = 0; ch < 50; ++ch) {
    __syncthreads();
    #pragma unroll
    for (int it = 0; it < 4; ++it) {
      *(float4*)&ks[cur][0][lsoff[it]] = ph[it];
      *(float4*)&ks[cur][1][lsoff[it]] = pl[it];
    }
    __syncthreads();
    if (ch + 1 < 50) {
      const size_t cb = (size_t)(ch + 1) * 8192;
      #pragma unroll
      for (int it = 0; it < 4; ++it) {
        ph[it] = *(const float4*)(khb + cb + segoff[it]);
        pl[it] = *(const float4*)(klb + cb + segoff[it]);
      }
    }
    const int tap = ch >> 1, cih = ch & 1;
    const int i = tap / 5, j = tap - 5 * i;
    bf16x8s ah[4], al[4];
    #pragma unroll
    for (int fm = 0; fm < 4; ++fm) {
      const size_t qoff = (((size_t)(4 * y + i) * 264) + 4 * (fm * 16 + col) + j) * 64
                        + cih * 32 + kg * 8;
      ah[fm] = *(const bf16x8s*)(qhb + qoff);
      al[fm] = *(const bf16x8s*)(qlb + qoff);
    }
    #pragma unroll
    for (int fn = 0; fn < 4; ++fn) {
      const int ll = wv * 64 + fn * 16 + col;
      const bf16x8s bh = *(const bf16x8s*)&ks[cur][0][ll * 36 + kg * 8];
      const bf16x8s bl = *(const bf16x8s*)&ks[cur][1][ll * 36 + kg * 8];
      #pragma unroll
      for (int fm = 0; fm < 4; ++fm) {
        acc[fm][fn] = __builtin_amdgcn_mfma_f32_16x16x32_bf16(ah[fm], bh, acc[fm][fn], 0, 0, 0);
        acc[fm][fn] = __builtin_amdgcn_mfma_f32_16x16x32_bf16(ah[fm], bl, acc[fm][fn], 0, 0, 0);
        acc[fm][fn] = __builtin_amdgcn_mfma_f32_16x16x32_bf16(al[fm], bh, acc[fm][fn], 0, 0, 0);
      }
    }
    cur ^= 1;
  }

  float* sb = scores + (size_t)n * 4096 * 256;
  #pragma unroll
  for (int fm = 0; fm < 4; ++fm)
    #pragma unroll
    for (int fn = 0; fn < 4; ++fn)
      #pragma unroll
      for (int r = 0; r < 4; ++r)
        sb[(size_t)(y * 64 + fm * 16 + kg * 4 + r) * 256 + wv * 64 + fn * 16 + col]
            = acc[fm][fn][r];
}

// ---------------- softmax over l, writes bf16 wn ----------------
__global__ void softmax_rows(const float* __restrict__ sa, unsigned short* __restrict__ wnbf) {
  const int row = blockIdx.x * 4 + (threadIdx.x >> 6);
  const int lane = threadIdx.x & 63;
  const size_t idx = (size_t)row * 64 + lane;
  const float4 v = ((const float4*)sa)[idx];
  float m = fmaxf(fmaxf(v.x, v.y), fmaxf(v.z, v.w));
  for (int off = 32; off; off >>= 1) m = fmaxf(m, __shfl_xor(m, off));
  float4 e;
  e.x = __expf(v.x - m); e.y = __expf(v.y - m);
  e.z = __expf(v.z - m); e.w = __expf(v.w - m);
  float s = e.x + e.y + e.z + e.w;
  for (int off = 32; off; off >>= 1) s += __shfl_xor(s, off);
  const float inv = 1.0f / s;
  unsigned long long pack = (unsigned long long)f2bf(e.x * inv)
                          | ((unsigned long long)f2bf(e.y * inv) << 16)
                          | ((unsigned long long)f2bf(e.z * inv) << 32)
                          | ((unsigned long long)f2bf(e.w * inv) << 48);
  *(unsigned long long*)(wnbf + idx * 4) = pack;
}

// ---------------- v-patch transposed bf16 gather: vpt[n][bij][l] ----------------
__global__ void vpt_gather(const float* __restrict__ vfea, unsigned short* __restrict__ vpt) {
  const int l4 = threadIdx.x & 63, bj = threadIdx.x >> 6;
  const int bij = blockIdx.x * 4 + bj;
  const int n = blockIdx.y;
  const int ij = bij >> 6, b = bij & 63;
  unsigned short o[4] = {0, 0, 0, 0};
  if (ij < 25) {
    const int i = ij / 5, j = ij % 5;
    const int ly = l4 >> 2;
    const int r = 4 * ly + i;
    if (r < HK) {
      const float* base = vfea + ((size_t)(n * COC + b) * HK + r) * HK;
      #pragma unroll
      for (int e = 0; e < 4; ++e) {
        const int lx = (l4 & 3) * 4 + e;
        const int c = 4 * lx + j;
        if (c < HK) o[e] = f2bf(base[c]);
      }
    }
  }
  unsigned long long pack = (unsigned long long)o[0] | ((unsigned long long)o[1] << 16)
                          | ((unsigned long long)o[2] << 32) | ((unsigned long long)o[3] << 48);
  *(unsigned long long*)(vpt + ((size_t)n * NPAD + bij) * 256 + l4 * 4) = pack;
}

// ---------------- PV MFMA GEMM: U[4096][NPAD] = wn[4096][256] x vpt^T ----------------
__global__ __launch_bounds__(256) void pv_mfma(
    const unsigned short* __restrict__ wnb, const unsigned short* __restrict__ vpt,
    float* __restrict__ C0) {
  const int nz = blockIdx.z;
  const unsigned short* A = wnb + (size_t)nz * 4096 * 256;
  const unsigned short* B = vpt + (size_t)nz * NPAD * 256;
  float* C = C0 + (size_t)nz * 4096 * NPAD;
  const int m0 = blockIdx.x * 64;
  const int n0 = blockIdx.y * 128;
  const int tid = threadIdx.x;
  const int lane = tid & 63;
  const int wv = tid >> 6;
  const int wm = wv >> 1, wn_ = wv & 1;
  const int col = lane & 15, kg = lane >> 4;

  __shared__ unsigned short A_s[64 * 40];
  __shared__ unsigned short B_s[128 * 40];

  f32x4 acc[2][4];
  #pragma unroll
  for (int fm = 0; fm < 2; ++fm)
    #pragma unroll
    for (int fn = 0; fn < 4; ++fn) acc[fm][fn] = (f32x4){0.f, 0.f, 0.f, 0.f};

  for (int k0 = 0; k0 < 256; k0 += 32) {
    __syncthreads();
    {
      const int row = tid >> 2, q = tid & 3;
      *(float4*)&A_s[row * 40 + q * 8] =
          *(const float4*)&A[(size_t)(m0 + row) * 256 + k0 + q * 8];
    }
    {
      const int row = tid >> 1, hh = tid & 1;
      *(float4*)&B_s[row * 40 + hh * 16] =
          *(const float4*)&B[(size_t)(n0 + row) * 256 + k0 + hh * 16];
      *(float4*)&B_s[row * 40 + hh * 16 + 8] =
          *(const float4*)&B[(size_t)(n0 + row) * 256 + k0 + hh * 16 + 8];
    }
    __syncthreads();

    bf16x8s a[2], b[4];
    #pragma unroll
    for (int fm = 0; fm < 2; ++fm)
      a[fm] = *(const bf16x8s*)&A_s[(wm * 32 + fm * 16 + col) * 40 + kg * 8];
    #pragma unroll
    for (int fn = 0; fn < 4; ++fn)
      b[fn] = *(const bf16x8s*)&B_s[(wn_ * 64 + fn * 16 + col) * 40 + kg * 8];
    #pragma unroll
    for (int fm = 0; fm < 2; ++fm)
      #pragma unroll
      for (int fn = 0; fn < 4; ++fn)
        acc[fm][fn] = __builtin_amdgcn_mfma_f32_16x16x32_bf16(a[fm], b[fn], acc[fm][fn], 0, 0, 0);
  }

  #pragma unroll
  for (int fm = 0; fm < 2; ++fm) {
    #pragma unroll
    for (int fn = 0; fn < 4; ++fn) {
      const int cg = n0 + wn_ * 64 + fn * 16 + col;
      #pragma unroll
      for (int r = 0; r < 4; ++r) {
        const int rg = m0 + wm * 32 + fm * 16 + kg * 4 + r;
        C[(size_t)rg * NPAD + cg] = acc[fm][fn][r];
      }
    }
  }
}

// ---------------- conv-transpose gather (+ /6) -> resbf bf16 [258][264][64co] ----------------
__global__ __launch_bounds__(256) void u_scatter(
    const float* __restrict__ U0, unsigned short* __restrict__ resbf, int n0) {
  const int n = n0 + blockIdx.z;
  const float* U = U0 + (size_t)blockIdx.z * 4096 * NPAD;
  const int y = blockIdx.y;
  const int xt = blockIdx.x;
  const int tid = threadIdx.x;
  __shared__ float t_lds[64][65];
  const int ym = (y + 1) >> 2, yr = (y + 1) & 3;
  const bool v0 = (ym < 64);
  const bool v1 = (yr == 0 && ym >= 1);
  const int b = tid & 63, xg = tid >> 6;
  for (int xi = 0; xi < 16; ++xi) {
    const int x = xt * 64 + xg * 16 + xi;
    const int xm = (x + 1) >> 2, xr = (x + 1) & 3;
    const bool u0 = (xm < 64);
    const bool u1 = (xr == 0 && xm >= 1);
    float s = 0.f;
    if (v0) {
      const size_t rb = (size_t)(ym * 64) * NPAD;
      if (u0) s += U[rb + (size_t)xm * NPAD + (yr * 5 + xr) * 64 + b];
      if (u1) s += U[rb + (size_t)(xm - 1) * NPAD + (yr * 5 + 4) * 64 + b];
    }
    if (v1) {
      const size_t rb = (size_t)((ym - 1) * 64) * NPAD;
      if (u0) s += U[rb + (size_t)xm * NPAD + (4 * 5 + xr) * 64 + b];
      if (u1) s += U[rb + (size_t)(xm - 1) * NPAD + (4 * 5 + 4) * 64 + b];
    }
    t_lds[xg * 16 + xi][b] = s * (1.0f / 6.0f);
  }
  __syncthreads();
  unsigned short* db = resbf + (((size_t)n * 258 + (y + 1)) * 264) * 64;
  for (int xi = 0; xi < 16; ++xi) {
    const int x = xg * 16 + xi;
    db[(size_t)(xt * 64 + x + 1) * 64 + b] = f2bf(t_lds[x][b]);
  }
}

extern "C" void kernel_launch(void* const* d_in, const int* in_sizes, int n_in,
                              void* d_out, int out_size, void* d_ws, size_t ws_size,
                              hipStream_t stream) {
  const float* ms   = (const float*)d_in[0];
  const float* pan  = (const float*)d_in[1];
  const float* pan2 = (const float*)d_in[2];
  const float* Wq   = (const float*)d_in[3];
  const float* bq   = (const float*)d_in[4];
  const float* Wk   = (const float*)d_in[5];
  const float* bk   = (const float*)d_in[6];
  const float* Wv   = (const float*)d_in[7];
  const float* bv   = (const float*)d_in[8];
  const float* Wr   = (const float*)d_in[9];
  const float* br   = (const float*)d_in[10];
  float* out = (float*)d_out;

  float* ws = (float*)d_ws;
  const size_t SZ_QP  = (size_t)NB * CI * QP2;               // 34.74M floats = qhi|qlo bf16
  const size_t SZ_K   = (size_t)NB * CI * HK * HK;           // 2.10M
  const size_t SZ_WN  = (size_t)NB * 64 * 64 * LL;           // 8.39M
  const size_t SZ_VPT = (size_t)NB * NPAD * 256 / 2;         // 1.70M floats (bf16)
  const size_t SZ_KP  = (size_t)NB * 50 * 256 * 32;          // 3.28M floats = khi|klo bf16
  const size_t SZ_PS  = (size_t)NB * CI * 66 * 72;           // 2.43M
  const size_t SZ_WI  = 23040;
  const size_t SZ_U1  = (size_t)4096 * NPAD;                 // 6.82M per batch
  const size_t SZ_UA  = (size_t)NB * SZ_U1;                  // 54.53M

  float* q_pad   = ws;                    // qhi|qlo bf16; later resbf
  float* k_fea   = q_pad + SZ_QP;
  float* v_fea   = k_fea + SZ_K;
  float* wnbf_f  = v_fea + SZ_K;
  float* vptbf_f = wnbf_f + SZ_WN / 2;
  float* kp      = vptbf_f + SZ_VPT;      // khi|klo bf16
  float* norms   = kp + SZ_KP;
  float* kscale  = norms + NB * LL;
  float* wtk     = kscale + 64;
  float* wtv     = wtk + 36864;
  float* wimgqf  = wtv + 36864;
  float* wimgrf  = wimgqf + SZ_WI;
  float* ms_pad  = wimgrf + SZ_WI;
  float* pan2pad = ms_pad + SZ_PS;
  float* tail    = pan2pad + SZ_PS;       // panbf -> scores -> U

  unsigned short* qhi  = (unsigned short*)q_pad;
  unsigned short* qlo  = qhi + (size_t)NB * QP2 * 64;
  unsigned short* khi  = (unsigned short*)kp;
  unsigned short* klo  = khi + (size_t)NB * 50 * 256 * 32;
  unsigned short* wimgq = (unsigned short*)wimgqf;
  unsigned short* wimgr = (unsigned short*)wimgrf;
  unsigned short* wnbf  = (unsigned short*)wnbf_f;
  unsigned short* vptbf = (unsigned short*)vptbf_f;
  unsigned short* panbf = (unsigned short*)tail;
  float* scores  = tail;
  float* U       = tail;
  unsigned short* resbf = (unsigned short*)q_pad;   // q dead after qk_mfma

  const size_t base_elems = (size_t)(tail - ws);
  const bool batched = ws_size >= (base_elems + SZ_UA) * sizeof(float);

  // weight prep
  wtrans8_kernel<<<dim3(9, 64), 64, 0, stream>>>(Wk, wtk);
  wtrans8_kernel<<<dim3(9, 64), 64, 0, stream>>>(Wv, wtv);
  wtrans_mfma<<<dim3(18), 256, 0, stream>>>(Wq, wimgq);
  wtrans_mfma<<<dim3(18), 256, 0, stream>>>(Wr, wimgr);

  // pad inputs
  {
    const int totS = NB * CI * HK * HK;
    pad_copy<<<dim3((totS + 255) / 256), 256, 0, stream>>>(ms, ms_pad, HK, HK, 72, totS);
    pad_copy<<<dim3((totS + 255) / 256), 256, 0, stream>>>(pan2, pan2pad, HK, HK, 72, totS);
    border_zero<<<dim3(NB * CI), 256, 0, stream>>>(ms_pad, HK, HK, 72);
    border_zero<<<dim3(NB * CI), 256, 0, stream>>>(pan2pad, HK, HK, 72);
    pad_rci<<<dim3(4, 258, NB), 256, 0, stream>>>(pan, panbf);
  }

  // feature convs: k,v small (fp32); q big (MFMA bf16 -> hi/lo rci)
  conv3s<<<dim3(HK / 64, HK / 8, NB * 8), 256, 0, stream>>>(pan2pad, wtk, bk, k_fea, HK, HK, 72, HK * HK, HK);
  conv3s<<<dim3(HK / 64, HK / 8, NB * 8), 256, 0, stream>>>(ms_pad,  wtv, bv, v_fea, HK, HK, 72, HK * HK, HK);
  conv3mq<<<dim3(4, 256, NB), 256, 0, stream>>>(panbf, wimgq, bq, qhi, qlo);
  qz<<<dim3(NB), 256, 0, stream>>>(qhi, qlo);

  // k-patch max norm -> scale
  knorm_kernel<<<dim3(LL, NB), 64, 0, stream>>>(k_fea, norms);
  kscale_kernel<<<NB, 256, 0, stream>>>(norms, kscale);

  // K im2col hi/lo (kscale folded)
  kp_gather2<<<dim3(25, 2, NB), 256, 0, stream>>>(k_fea, kscale, khi, klo);

  // QK MFMA scores + softmax -> bf16 wn  [panbf dead; scores reuses tail]
  qk_mfma<<<dim3(64, NB), 256, 0, stream>>>(qhi, qlo, khi, klo, scores);
  softmax_rows<<<dim3(8192), 256, 0, stream>>>(scores, wnbf);

  // resbf borders (aliases q hi/lo; dead after qk_mfma)
  rbz<<<dim3(NB), 256, 0, stream>>>(resbf);

  // v patch bf16 transposed matrix
  vpt_gather<<<dim3(NPAD / 4, NB), 256, 0, stream>>>(v_fea, vptbf);

  // PV MFMA + conv-transpose gather (U reuses tail after softmax consumed scores)
  if (batched) {
    pv_mfma<<<dim3(64, 13, NB), 256, 0, stream>>>(wnbf, vptbf, U);
    u_scatter<<<dim3(4, HQ, NB), 256, 0, stream>>>(U, resbf, 0);
  } else {
    for (int n = 0; n < NB; ++n) {
      pv_mfma<<<dim3(64, 13, 1), 256, 0, stream>>>(wnbf + (size_t)n * 4096 * 256,
                                                   vptbf + (size_t)n * NPAD * 256, U);
      u_scatter<<<dim3(4, HQ, 1), 256, 0, stream>>>(U, resbf, n);
    }
  }

  // final conv (MFMA bf16) -> d_out fp32
  conv3m<<<dim3(4, 256, NB), 256, 0, stream>>>(resbf, wimgr, br, out, HQ * HQ, HQ);
}

// Round 12
// 777.077 us; speedup vs baseline: 8.9878x; 1.2611x over previous
//
#include <hip/hip_runtime.h>
#include <math.h>

#define NB   8
#define CI   64
#define COC  64
#define HQ   256
#define HK   64
#define KS   5
#define LL   256
#define NPAD 1664
#define QP2  (257 * 264)   // q bf16 plane (rows 0..256, row 256 = same-pad zeros)

typedef __attribute__((ext_vector_type(8))) short bf16x8s;
typedef __attribute__((ext_vector_type(4))) float f32x4;

static __device__ __forceinline__ unsigned short f2bf(float f) {
  union { float f; unsigned u; } v; v.f = f;
  unsigned r = v.u + 0x7FFF + ((v.u >> 16) & 1);
  return (unsigned short)(r >> 16);
}
static __device__ __forceinline__ float bf2f(unsigned short h) {
  union { unsigned u; float f; } v; v.u = ((unsigned)h) << 16; return v.f;
}

// ---------------- weight transpose for conv3s: [CO][CI][3][3] -> [cogrp8][CI][tap][8] ----------------
__global__ void wtrans8_kernel(const float* __restrict__ Wt, float* __restrict__ Wo) {
  const int co = threadIdx.x;
  const int tap = blockIdx.x;
  const int ci = blockIdx.y;
  Wo[(((co >> 3) * 64 + ci) * 9 + tap) * 8 + (co & 7)] = Wt[(co * 64 + ci) * 9 + tap];
}

// ---------------- weight image for conv3m: [18 chunk][64 co][40] bf16 ----------------
__global__ void wtrans_mfma(const float* __restrict__ Wt, unsigned short* __restrict__ wimg) {
  const int ch = blockIdx.x;
  const int tap = ch >> 1, cih = ch & 1;
  for (int idx = threadIdx.x; idx < 64 * 40; idx += 256) {
    const int co = idx / 40, s = idx - co * 40;
    unsigned short v = 0;
    if (s < 32) v = f2bf(Wt[((size_t)co * 64 + cih * 32 + s) * 9 + tap]);
    wimg[(size_t)ch * 64 * 40 + idx] = v;
  }
}

// ---------------- pad copy (fp32 ci-major, for small convs) ----------------
__global__ void pad_copy(const float* __restrict__ src, float* __restrict__ dst,
                         int H, int W, int S, int total) {
  const int idx = blockIdx.x * 256 + threadIdx.x;
  if (idx >= total) return;
  const int p = idx / (H * W);
  const int rem = idx - p * H * W;
  const int y = rem / W, x = rem - y * W;
  dst[((size_t)p * (H + 2) + y + 1) * S + x + 1] = src[idx];
}

__global__ void border_zero(float* __restrict__ dst, int H, int W, int S) {
  const int p = blockIdx.x;
  float* b = dst + (size_t)p * (H + 2) * S;
  for (int c = threadIdx.x; c < S; c += 256) {
    b[c] = 0.f;
    b[(size_t)(H + 1) * S + c] = 0.f;
  }
  for (int r = 1 + threadIdx.x; r <= H; r += 256) {
    b[(size_t)r * S] = 0.f;
    b[(size_t)r * S + W + 1] = 0.f;
  }
}

// ---------------- pan fp32 [ci][256][256] -> bf16 [row 258][col 264][ci 64] ----------------
__global__ void pad_rci(const float* __restrict__ src, unsigned short* __restrict__ dst) {
  const int ct = blockIdx.x, g = blockIdx.y, n = blockIdx.z;
  const int c0 = ct * 66;
  __shared__ float t[64 * 68];
  const int jl = threadIdx.x & 63, cg = threadIdx.x >> 6;
  const int row = g - 1;
  const bool rok = (row >= 0 && row < 256);
  for (int ci = cg; ci < 64; ci += 4) {
    #pragma unroll
    for (int jb = 0; jb < 2; ++jb) {
      const int j = jl + jb * 64;
      if (j < 66) {
        const int x = c0 - 1 + j;
        float v = 0.f;
        if (rok && x >= 0 && x < 256)
          v = src[(((size_t)n * 64 + ci) * 256 + row) * 256 + x];
        t[ci * 68 + j] = v;
      }
    }
  }
  __syncthreads();
  const int cil = threadIdx.x & 63, cc = threadIdx.x >> 6;
  unsigned short* db = dst + (((size_t)n * 258 + g) * 264) * 64;
  for (int c = cc; c < 66; c += 4)
    db[(size_t)(c0 + c) * 64 + cil] = f2bf(t[cil * 68 + c]);
}

// zero borders of resbf ([258][264][64])
__global__ void rbz(unsigned short* __restrict__ resbf) {
  const int n = blockIdx.x;
  unsigned short* b = resbf + (size_t)n * 258 * 264 * 64;
  for (int idx = threadIdx.x; idx < 264 * 64; idx += 256) {
    b[idx] = 0;
    b[(size_t)257 * 264 * 64 + idx] = 0;
  }
  for (int idx = threadIdx.x; idx < 256 * 64; idx += 256) {
    const int r = idx >> 6, ci = idx & 63;
    b[((size_t)(r + 1) * 264) * 64 + ci] = 0;
    b[((size_t)(r + 1) * 264 + 257) * 64 + ci] = 0;
  }
}

// zero same-pad strips of q hi/lo ([257][264][64]): row 256 full, col 256 rows 0..255
__global__ void qz(unsigned short* __restrict__ qhi, unsigned short* __restrict__ qlo) {
  const int n = blockIdx.x;
  unsigned short* bh = qhi + (size_t)n * QP2 * 64;
  unsigned short* bl = qlo + (size_t)n * QP2 * 64;
  for (int g = threadIdx.x; g < 4224; g += 256) {
    ((unsigned long long*)(bh + (size_t)256 * 264 * 64))[g] = 0ull;
    ((unsigned long long*)(bl + (size_t)256 * 264 * 64))[g] = 0ull;
  }
  for (int g = threadIdx.x; g < 4096; g += 256) {
    const int r = g >> 4, q = g & 15;
    const size_t off = ((size_t)r * 264 + 256) * 64 + q * 4;
    *(unsigned long long*)(bh + off) = 0ull;
    *(unsigned long long*)(bl + off) = 0ull;
  }
}

// ---------------- MFMA conv 3x3 + bias + leaky relu (bf16 in, fp32 planar out) ----------------
__global__ __launch_bounds__(256) void conv3m(
    const unsigned short* __restrict__ inbf,
    const unsigned short* __restrict__ wimg,
    const float* __restrict__ bias,
    float* __restrict__ out, int PS, int RS) {
  const int x0 = blockIdx.x * 64;
  const int y  = blockIdx.y;
  const int n  = blockIdx.z;
  const int tid = threadIdx.x;
  const int lane = tid & 63;
  const int wv = tid >> 6;
  const int col = lane & 15;
  const int kg  = lane >> 4;

  __shared__ unsigned short in_s[3 * 66 * 72];

  {
    const unsigned short* src = inbf + ((size_t)n * 258 + y) * 264 * 64;
    if (tid < 198) {
      const int r = tid / 66, c = tid - r * 66;
      const unsigned short* s = src + ((size_t)r * 264 + x0 + c) * 64;
      unsigned short* d = &in_s[(r * 66 + c) * 72];
      #pragma unroll
      for (int q = 0; q < 8; ++q)
        *(float4*)(d + q * 8) = *(const float4*)(s + q * 8);
    }
  }
  __syncthreads();

  f32x4 acc[4];
  #pragma unroll
  for (int p = 0; p < 4; ++p) acc[p] = (f32x4){0.f, 0.f, 0.f, 0.f};

  const unsigned short* wbase = wimg + ((size_t)(wv * 16 + col)) * 40 + kg * 8;

  #pragma unroll 2
  for (int ch = 0; ch < 18; ++ch) {
    const int tap = ch >> 1, cih = ch & 1;
    const int dy = tap / 3, dx = tap - dy * 3;
    const bf16x8s a = *(const bf16x8s*)(wbase + (size_t)ch * 64 * 40);
    const int cix = cih * 32 + kg * 8;
    #pragma unroll
    for (int p = 0; p < 4; ++p) {
      const int c = p * 16 + col + dx;
      const bf16x8s b = *(const bf16x8s*)&in_s[(dy * 66 + c) * 72 + cix];
      acc[p] = __builtin_amdgcn_mfma_f32_16x16x32_bf16(a, b, acc[p], 0, 0, 0);
    }
  }

  const int cobase = wv * 16 + kg * 4;
  const float4 bb = *(const float4*)&bias[cobase];
  const float bv[4] = {bb.x, bb.y, bb.z, bb.w};
  #pragma unroll
  for (int p = 0; p < 4; ++p) {
    const int x = x0 + p * 16 + col;
    #pragma unroll
    for (int r = 0; r < 4; ++r) {
      float t = acc[p][r] + bv[r];
      t = t > 0.f ? t : 0.01f * t;
      out[(size_t)(n * 64 + cobase + r) * PS + (size_t)y * RS + x] = t;
    }
  }
}

// ---------------- MFMA conv for Q: writes bf16 hi/lo in [257][264][64co] rci layout ----------------
__global__ __launch_bounds__(256) void conv3mq(
    const unsigned short* __restrict__ inbf,
    const unsigned short* __restrict__ wimg,
    const float* __restrict__ bias,
    unsigned short* __restrict__ qhi, unsigned short* __restrict__ qlo) {
  const int x0 = blockIdx.x * 64;
  const int y  = blockIdx.y;
  const int n  = blockIdx.z;
  const int tid = threadIdx.x;
  const int lane = tid & 63;
  const int wv = tid >> 6;
  const int col = lane & 15;
  const int kg  = lane >> 4;

  __shared__ unsigned short in_s[3 * 66 * 72];

  {
    const unsigned short* src = inbf + ((size_t)n * 258 + y) * 264 * 64;
    if (tid < 198) {
      const int r = tid / 66, c = tid - r * 66;
      const unsigned short* s = src + ((size_t)r * 264 + x0 + c) * 64;
      unsigned short* d = &in_s[(r * 66 + c) * 72];
      #pragma unroll
      for (int q = 0; q < 8; ++q)
        *(float4*)(d + q * 8) = *(const float4*)(s + q * 8);
    }
  }
  __syncthreads();

  f32x4 acc[4];
  #pragma unroll
  for (int p = 0; p < 4; ++p) acc[p] = (f32x4){0.f, 0.f, 0.f, 0.f};

  const unsigned short* wbase = wimg + ((size_t)(wv * 16 + col)) * 40 + kg * 8;

  #pragma unroll 2
  for (int ch = 0; ch < 18; ++ch) {
    const int tap = ch >> 1, cih = ch & 1;
    const int dy = tap / 3, dx = tap - dy * 3;
    const bf16x8s a = *(const bf16x8s*)(wbase + (size_t)ch * 64 * 40);
    const int cix = cih * 32 + kg * 8;
    #pragma unroll
    for (int p = 0; p < 4; ++p) {
      const int c = p * 16 + col + dx;
      const bf16x8s b = *(const bf16x8s*)&in_s[(dy * 66 + c) * 72 + cix];
      acc[p] = __builtin_amdgcn_mfma_f32_16x16x32_bf16(a, b, acc[p], 0, 0, 0);
    }
  }

  const int cobase = wv * 16 + kg * 4;
  const float4 bb = *(const float4*)&bias[cobase];
  const float bv[4] = {bb.x, bb.y, bb.z, bb.w};
  unsigned short* hb = qhi + ((size_t)n * 257 + y) * 264 * 64;
  unsigned short* lb = qlo + ((size_t)n * 257 + y) * 264 * 64;
  #pragma unroll
  for (int p = 0; p < 4; ++p) {
    const int x = x0 + p * 16 + col;
    unsigned long long hp = 0, lp = 0;
    #pragma unroll
    for (int r = 0; r < 4; ++r) {
      float t = acc[p][r] + bv[r];
      t = t > 0.f ? t : 0.01f * t;
      const unsigned short h = f2bf(t);
      const unsigned short lo = f2bf(t - bf2f(h));
      hp |= ((unsigned long long)h) << (16 * r);
      lp |= ((unsigned long long)lo) << (16 * r);
    }
    *(unsigned long long*)(hb + (size_t)x * 64 + cobase) = hp;
    *(unsigned long long*)(lb + (size_t)x * 64 + cobase) = lp;
  }
}

// ---------------- small conv 3x3 (fp32, for k/v 64x64) ----------------
__global__ __launch_bounds__(256) void conv3s(
    const float* __restrict__ inp, const float* __restrict__ Wts,
    const float* __restrict__ bias, float* __restrict__ out,
    int H, int Wd, int S, int outPS, int outRS) {
  const int x0 = blockIdx.x * 64;
  const int y0 = blockIdx.y * 8;
  const int z  = blockIdx.z;
  const int n  = z >> 3;
  const int cog = z & 7;
  const int tid = threadIdx.x;
  const int xq = tid & 15;
  const int yt = (tid >> 4) & 7;
  const int cg = tid >> 7;
  const int Hp = H + 2;

  __shared__ float in_s[10 * 72];
  __shared__ float w_s[CI * 9 * 8];

  {
    const float* wbase = Wts + (size_t)cog * (CI * 9 * 8);
    for (int idx = tid; idx < CI * 9 * 2; idx += 256)
      *(float4*)&w_s[idx * 4] = *(const float4*)(wbase + idx * 4);
  }

  float acc[4][4];
  #pragma unroll
  for (int a = 0; a < 4; ++a)
    #pragma unroll
    for (int b = 0; b < 4; ++b) acc[a][b] = 0.f;

  const bool hasA = tid < 180;
  const int arow = tid / 18, ac4 = tid - arow * 18;
  const float* gplane0 = inp + (size_t)(n * CI) * Hp * S;
  const size_t aoff = ((size_t)(y0 + arow)) * S + x0 + ac4 * 4;

  float4 sA = make_float4(0.f, 0.f, 0.f, 0.f);
  if (hasA) sA = *(const float4*)(gplane0 + aoff);

  for (int ci = 0; ci < CI; ++ci) {
    __syncthreads();
    if (hasA) *(float4*)&in_s[arow * 72 + ac4 * 4] = sA;
    if (ci + 1 < CI && hasA)
      sA = *(const float4*)(gplane0 + (size_t)(ci + 1) * Hp * S + aoff);
    __syncthreads();

    float xin[3][8];
    const int cb = xq * 4;
    #pragma unroll
    for (int r = 0; r < 3; ++r) {
      const float4 xa = *(const float4*)&in_s[(yt + r) * 72 + cb];
      const float4 xb = *(const float4*)&in_s[(yt + r) * 72 + cb + 4];
      xin[r][0] = xa.x; xin[r][1] = xa.y; xin[r][2] = xa.z; xin[r][3] = xa.w;
      xin[r][4] = xb.x; xin[r][5] = xb.y; xin[r][6] = xb.z; xin[r][7] = xb.w;
    }

    const float* wci = &w_s[(ci * 9) * 8 + cg * 4];
    #pragma unroll
    for (int ky = 0; ky < 3; ++ky) {
      #pragma unroll
      for (int kx = 0; kx < 3; ++kx) {
        const float4 w4 = *(const float4*)&wci[(ky * 3 + kx) * 8];
        const float wv[4] = {w4.x, w4.y, w4.z, w4.w};
        #pragma unroll
        for (int c = 0; c < 4; ++c)
          #pragma unroll
          for (int dx = 0; dx < 4; ++dx)
            acc[c][dx] = fmaf(wv[c], xin[ky][dx + kx], acc[c][dx]);
      }
    }
  }

  #pragma unroll
  for (int c = 0; c < 4; ++c) {
    const int co = cog * 8 + cg * 4 + c;
    const float bv = bias[co];
    float4 o;
    float t;
    t = acc[c][0] + bv; o.x = t > 0.f ? t : 0.01f * t;
    t = acc[c][1] + bv; o.y = t > 0.f ? t : 0.01f * t;
    t = acc[c][2] + bv; o.z = t > 0.f ? t : 0.01f * t;
    t = acc[c][3] + bv; o.w = t > 0.f ? t : 0.01f * t;
    *(float4*)(out + (size_t)(n * COC + co) * outPS + (size_t)(y0 + yt) * outRS + x0 + xq * 4) = o;
  }
}

// ---------------- k-patch squared norms ----------------
__global__ void knorm_kernel(const float* __restrict__ kfea, float* __restrict__ norms) {
  const int l = blockIdx.x, n = blockIdx.y, c = threadIdx.x;
  const int ly = l >> 4, lx = l & 15;
  const float* base = kfea + ((size_t)(n * CI + c) * HK) * HK;
  float ss = 0.f;
  #pragma unroll
  for (int i = 0; i < KS; ++i) {
    const int r = 4 * ly + i;
    if (r >= HK) continue;
    #pragma unroll
    for (int j = 0; j < KS; ++j) {
      const int cc = 4 * lx + j;
      if (cc >= HK) continue;
      const float v = base[r * HK + cc];
      ss = fmaf(v, v, ss);
    }
  }
  for (int off = 32; off; off >>= 1) ss += __shfl_down(ss, off);
  if (c == 0) norms[n * LL + l] = ss;
}

__global__ void kscale_kernel(const float* __restrict__ norms, float* __restrict__ kscale) {
  const int n = blockIdx.x, t = threadIdx.x;
  float v = norms[n * LL + t];
  for (int off = 32; off; off >>= 1) v = fmaxf(v, __shfl_down(v, off));
  __shared__ float red[4];
  if ((t & 63) == 0) red[t >> 6] = v;
  __syncthreads();
  if (t == 0) {
    const float m = fmaxf(fmaxf(red[0], red[1]), fmaxf(red[2], red[3]));
    kscale[n] = 10.0f / sqrtf(m);
  }
}

// ---------------- K im2col hi/lo bf16: k[n][chunk 50][l 256][s 32] ----------------
__global__ void kp_gather2(const float* __restrict__ kfea, const float* __restrict__ kscale,
                           unsigned short* __restrict__ khi, unsigned short* __restrict__ klo) {
  const int tap = blockIdx.x, cih = blockIdx.y, n = blockIdx.z;
  const int s = threadIdx.x & 31, lg = threadIdx.x >> 5;
  const int i = tap / 5, j = tap % 5;
  const float sc = kscale[n];
  const float* kb = kfea + ((size_t)(n * 64 + cih * 32 + s) * 64) * 64;
  const size_t ob = (((size_t)n * 50 + tap * 2 + cih) * 256) * 32;
  for (int lb = 0; lb < 32; ++lb) {
    const int l = lb * 8 + lg;
    const int r = 4 * (l >> 4) + i, c = 4 * (l & 15) + j;
    float v = 0.f;
    if (r < 64 && c < 64) v = kb[r * 64 + c] * sc;
    const unsigned short h = f2bf(v);
    khi[ob + (size_t)l * 32 + s] = h;
    klo[ob + (size_t)l * 32 + s] = f2bf(v - bf2f(h));
  }
}

// ---------------- QK MFMA: LDS-free streaming, hi/lo 3-product bf16 ----------------
// grid (64 y, NB), block 256 = 4 waves; wave wv covers l-quarter wv*64..+64, all 64 x.
// B fragments are 16B-contiguous reads from kp's [chunk][l][32] layout (L2-resident, 3.2 MB/batch).
__global__ __launch_bounds__(256) void qk_mfma(
    const unsigned short* __restrict__ qhi, const unsigned short* __restrict__ qlo,
    const unsigned short* __restrict__ khi, const unsigned short* __restrict__ klo,
    float* __restrict__ scores) {
  const int y = blockIdx.x, n = blockIdx.y;
  const int tid = threadIdx.x;
  const int lane = tid & 63, wv = tid >> 6;
  const int col = lane & 15, kg = lane >> 4;

  f32x4 acc[4][4];
  #pragma unroll
  for (int fm = 0; fm < 4; ++fm)
    #pragma unroll
    for (int fn = 0; fn < 4; ++fn) acc[fm][fn] = (f32x4){0.f, 0.f, 0.f, 0.f};

  const unsigned short* khb = khi + (size_t)n * 50 * 8192;
  const unsigned short* klb = klo + (size_t)n * 50 * 8192;
  const unsigned short* qhb = qhi + (size_t)n * QP2 * 64;
  const unsigned short* qlb = qlo + (size_t)n * QP2 * 64;

  for (int ch = 0; ch < 50; ++ch) {
    const int tap = ch >> 1, cih = ch & 1;
    const int i = tap / 5, j = tap - 5 * i;
    // A fragments (Q): 16B contiguous per lane from rci layout
    bf16x8s ah[4], al[4];
    #pragma unroll
    for (int fm = 0; fm < 4; ++fm) {
      const size_t qoff = (((size_t)(4 * y + i) * 264) + 4 * (fm * 16 + col) + j) * 64
                        + cih * 32 + kg * 8;
      ah[fm] = *(const bf16x8s*)(qhb + qoff);
      al[fm] = *(const bf16x8s*)(qlb + qoff);
    }
    // B fragments (K): wave reads a contiguous 1KB region per fn
    #pragma unroll
    for (int fn = 0; fn < 4; ++fn) {
      const size_t boff = ((size_t)ch * 256 + wv * 64 + fn * 16 + col) * 32 + kg * 8;
      const bf16x8s bh = *(const bf16x8s*)(khb + boff);
      const bf16x8s bl = *(const bf16x8s*)(klb + boff);
      #pragma unroll
      for (int fm = 0; fm < 4; ++fm) {
        acc[fm][fn] = __builtin_amdgcn_mfma_f32_16x16x32_bf16(ah[fm], bh, acc[fm][fn], 0, 0, 0);
        acc[fm][fn] = __builtin_amdgcn_mfma_f32_16x16x32_bf16(ah[fm], bl, acc[fm][fn], 0, 0, 0);
        acc[fm][fn] = __builtin_amdgcn_mfma_f32_16x16x32_bf16(al[fm], bh, acc[fm][fn], 0, 0, 0);
      }
    }
  }

  float* sb = scores + (size_t)n * 4096 * 256;
  #pragma unroll
  for (int fm = 0; fm < 4; ++fm)
    #pragma unroll
    for (int fn = 0; fn < 4; ++fn)
      #pragma unroll
      for (int r = 0; r < 4; ++r)
        sb[(size_t)(y * 64 + fm * 16 + kg * 4 + r) * 256 + wv * 64 + fn * 16 + col]
            = acc[fm][fn][r];
}

// ---------------- softmax over l, writes bf16 wn ----------------
__global__ void softmax_rows(const float* __restrict__ sa, unsigned short* __restrict__ wnbf) {
  const int row = blockIdx.x * 4 + (threadIdx.x >> 6);
  const int lane = threadIdx.x & 63;
  const size_t idx = (size_t)row * 64 + lane;
  const float4 v = ((const float4*)sa)[idx];
  float m = fmaxf(fmaxf(v.x, v.y), fmaxf(v.z, v.w));
  for (int off = 32; off; off >>= 1) m = fmaxf(m, __shfl_xor(m, off));
  float4 e;
  e.x = __expf(v.x - m); e.y = __expf(v.y - m);
  e.z = __expf(v.z - m); e.w = __expf(v.w - m);
  float s = e.x + e.y + e.z + e.w;
  for (int off = 32; off; off >>= 1) s += __shfl_xor(s, off);
  const float inv = 1.0f / s;
  unsigned long long pack = (unsigned long long)f2bf(e.x * inv)
                          | ((unsigned long long)f2bf(e.y * inv) << 16)
                          | ((unsigned long long)f2bf(e.z * inv) << 32)
                          | ((unsigned long long)f2bf(e.w * inv) << 48);
  *(unsigned long long*)(wnbf + idx * 4) = pack;
}

// ---------------- v-patch transposed bf16 gather: vpt[n][bij][l] ----------------
__global__ void vpt_gather(const float* __restrict__ vfea, unsigned short* __restrict__ vpt) {
  const int l4 = threadIdx.x & 63, bj = threadIdx.x >> 6;
  const int bij = blockIdx.x * 4 + bj;
  const int n = blockIdx.y;
  const int ij = bij >> 6, b = bij & 63;
  unsigned short o[4] = {0, 0, 0, 0};
  if (ij < 25) {
    const int i = ij / 5, j = ij % 5;
    const int ly = l4 >> 2;
    const int r = 4 * ly + i;
    if (r < HK) {
      const float* base = vfea + ((size_t)(n * COC + b) * HK + r) * HK;
      #pragma unroll
      for (int e = 0; e < 4; ++e) {
        const int lx = (l4 & 3) * 4 + e;
        const int c = 4 * lx + j;
        if (c < HK) o[e] = f2bf(base[c]);
      }
    }
  }
  unsigned long long pack = (unsigned long long)o[0] | ((unsigned long long)o[1] << 16)
                          | ((unsigned long long)o[2] << 32) | ((unsigned long long)o[3] << 48);
  *(unsigned long long*)(vpt + ((size_t)n * NPAD + bij) * 256 + l4 * 4) = pack;
}

// ---------------- PV MFMA GEMM: U[4096][NPAD] = wn[4096][256] x vpt^T ----------------
__global__ __launch_bounds__(256) void pv_mfma(
    const unsigned short* __restrict__ wnb, const unsigned short* __restrict__ vpt,
    float* __restrict__ C0) {
  const int nz = blockIdx.z;
  const unsigned short* A = wnb + (size_t)nz * 4096 * 256;
  const unsigned short* B = vpt + (size_t)nz * NPAD * 256;
  float* C = C0 + (size_t)nz * 4096 * NPAD;
  const int m0 = blockIdx.x * 64;
  const int n0 = blockIdx.y * 128;
  const int tid = threadIdx.x;
  const int lane = tid & 63;
  const int wv = tid >> 6;
  const int wm = wv >> 1, wn_ = wv & 1;
  const int col = lane & 15, kg = lane >> 4;

  __shared__ unsigned short A_s[64 * 40];
  __shared__ unsigned short B_s[128 * 40];

  f32x4 acc[2][4];
  #pragma unroll
  for (int fm = 0; fm < 2; ++fm)
    #pragma unroll
    for (int fn = 0; fn < 4; ++fn) acc[fm][fn] = (f32x4){0.f, 0.f, 0.f, 0.f};

  for (int k0 = 0; k0 < 256; k0 += 32) {
    __syncthreads();
    {
      const int row = tid >> 2, q = tid & 3;
      *(float4*)&A_s[row * 40 + q * 8] =
          *(const float4*)&A[(size_t)(m0 + row) * 256 + k0 + q * 8];
    }
    {
      const int row = tid >> 1, hh = tid & 1;
      *(float4*)&B_s[row * 40 + hh * 16] =
          *(const float4*)&B[(size_t)(n0 + row) * 256 + k0 + hh * 16];
      *(float4*)&B_s[row * 40 + hh * 16 + 8] =
          *(const float4*)&B[(size_t)(n0 + row) * 256 + k0 + hh * 16 + 8];
    }
    __syncthreads();

    bf16x8s a[2], b[4];
    #pragma unroll
    for (int fm = 0; fm < 2; ++fm)
      a[fm] = *(const bf16x8s*)&A_s[(wm * 32 + fm * 16 + col) * 40 + kg * 8];
    #pragma unroll
    for (int fn = 0; fn < 4; ++fn)
      b[fn] = *(const bf16x8s*)&B_s[(wn_ * 64 + fn * 16 + col) * 40 + kg * 8];
    #pragma unroll
    for (int fm = 0; fm < 2; ++fm)
      #pragma unroll
      for (int fn = 0; fn < 4; ++fn)
        acc[fm][fn] = __builtin_amdgcn_mfma_f32_16x16x32_bf16(a[fm], b[fn], acc[fm][fn], 0, 0, 0);
  }

  #pragma unroll
  for (int fm = 0; fm < 2; ++fm) {
    #pragma unroll
    for (int fn = 0; fn < 4; ++fn) {
      const int cg = n0 + wn_ * 64 + fn * 16 + col;
      #pragma unroll
      for (int r = 0; r < 4; ++r) {
        const int rg = m0 + wm * 32 + fm * 16 + kg * 4 + r;
        C[(size_t)rg * NPAD + cg] = acc[fm][fn][r];
      }
    }
  }
}

// ---------------- conv-transpose gather (+ /6) -> resbf bf16 [258][264][64co] ----------------
__global__ __launch_bounds__(256) void u_scatter(
    const float* __restrict__ U0, unsigned short* __restrict__ resbf, int n0) {
  const int n = n0 + blockIdx.z;
  const float* U = U0 + (size_t)blockIdx.z * 4096 * NPAD;
  const int y = blockIdx.y;
  const int xt = blockIdx.x;
  const int tid = threadIdx.x;
  __shared__ float t_lds[64][65];
  const int ym = (y + 1) >> 2, yr = (y + 1) & 3;
  const bool v0 = (ym < 64);
  const bool v1 = (yr == 0 && ym >= 1);
  const int b = tid & 63, xg = tid >> 6;
  for (int xi = 0; xi < 16; ++xi) {
    const int x = xt * 64 + xg * 16 + xi;
    const int xm = (x + 1) >> 2, xr = (x + 1) & 3;
    const bool u0 = (xm < 64);
    const bool u1 = (xr == 0 && xm >= 1);
    float s = 0.f;
    if (v0) {
      const size_t rb = (size_t)(ym * 64) * NPAD;
      if (u0) s += U[rb + (size_t)xm * NPAD + (yr * 5 + xr) * 64 + b];
      if (u1) s += U[rb + (size_t)(xm - 1) * NPAD + (yr * 5 + 4) * 64 + b];
    }
    if (v1) {
      const size_t rb = (size_t)((ym - 1) * 64) * NPAD;
      if (u0) s += U[rb + (size_t)xm * NPAD + (4 * 5 + xr) * 64 + b];
      if (u1) s += U[rb + (size_t)(xm - 1) * NPAD + (4 * 5 + 4) * 64 + b];
    }
    t_lds[xg * 16 + xi][b] = s * (1.0f / 6.0f);
  }
  __syncthreads();
  unsigned short* db = resbf + (((size_t)n * 258 + (y + 1)) * 264) * 64;
  for (int xi = 0; xi < 16; ++xi) {
    const int x = xg * 16 + xi;
    db[(size_t)(xt * 64 + x + 1) * 64 + b] = f2bf(t_lds[x][b]);
  }
}

extern "C" void kernel_launch(void* const* d_in, const int* in_sizes, int n_in,
                              void* d_out, int out_size, void* d_ws, size_t ws_size,
                              hipStream_t stream) {
  const float* ms   = (const float*)d_in[0];
  const float* pan  = (const float*)d_in[1];
  const float* pan2 = (const float*)d_in[2];
  const float* Wq   = (const float*)d_in[3];
  const float* bq   = (const float*)d_in[4];
  const float* Wk   = (const float*)d_in[5];
  const float* bk   = (const float*)d_in[6];
  const float* Wv   = (const float*)d_in[7];
  const float* bv   = (const float*)d_in[8];
  const float* Wr   = (const float*)d_in[9];
  const float* br   = (const float*)d_in[10];
  float* out = (float*)d_out;

  float* ws = (float*)d_ws;
  const size_t SZ_QP  = (size_t)NB * CI * QP2;               // qhi|qlo bf16 (34.74M floats)
  const size_t SZ_K   = (size_t)NB * CI * HK * HK;           // 2.10M
  const size_t SZ_WN  = (size_t)NB * 64 * 64 * LL;           // 8.39M
  const size_t SZ_VPT = (size_t)NB * NPAD * 256 / 2;         // 1.70M floats (bf16)
  const size_t SZ_KP  = (size_t)NB * 50 * 256 * 32;          // khi|klo bf16 (3.28M floats)
  const size_t SZ_PS  = (size_t)NB * CI * 66 * 72;           // 2.43M
  const size_t SZ_WI  = 23040;
  const size_t SZ_U1  = (size_t)4096 * NPAD;                 // 6.82M per batch
  const size_t SZ_UA  = (size_t)NB * SZ_U1;                  // 54.53M

  float* q_pad   = ws;                    // qhi|qlo bf16; later resbf
  float* k_fea   = q_pad + SZ_QP;
  float* v_fea   = k_fea + SZ_K;
  float* wnbf_f  = v_fea + SZ_K;
  float* vptbf_f = wnbf_f + SZ_WN / 2;
  float* kp      = vptbf_f + SZ_VPT;      // khi|klo bf16
  float* norms   = kp + SZ_KP;
  float* kscale  = norms + NB * LL;
  float* wtk     = kscale + 64;
  float* wtv     = wtk + 36864;
  float* wimgqf  = wtv + 36864;
  float* wimgrf  = wimgqf + SZ_WI;
  float* ms_pad  = wimgrf + SZ_WI;
  float* pan2pad = ms_pad + SZ_PS;
  float* tail    = pan2pad + SZ_PS;       // panbf -> scores -> U

  unsigned short* qhi  = (unsigned short*)q_pad;
  unsigned short* qlo  = qhi + (size_t)NB * QP2 * 64;
  unsigned short* khi  = (unsigned short*)kp;
  unsigned short* klo  = khi + (size_t)NB * 50 * 256 * 32;
  unsigned short* wimgq = (unsigned short*)wimgqf;
  unsigned short* wimgr = (unsigned short*)wimgrf;
  unsigned short* wnbf  = (unsigned short*)wnbf_f;
  unsigned short* vptbf = (unsigned short*)vptbf_f;
  unsigned short* panbf = (unsigned short*)tail;
  float* scores  = tail;
  float* U       = tail;
  unsigned short* resbf = (unsigned short*)q_pad;   // q dead after qk_mfma

  const size_t base_elems = (size_t)(tail - ws);
  const bool batched = ws_size >= (base_elems + SZ_UA) * sizeof(float);

  // weight prep
  wtrans8_kernel<<<dim3(9, 64), 64, 0, stream>>>(Wk, wtk);
  wtrans8_kernel<<<dim3(9, 64), 64, 0, stream>>>(Wv, wtv);
  wtrans_mfma<<<dim3(18), 256, 0, stream>>>(Wq, wimgq);
  wtrans_mfma<<<dim3(18), 256, 0, stream>>>(Wr, wimgr);

  // pad inputs
  {
    const int totS = NB * CI * HK * HK;
    pad_copy<<<dim3((totS + 255) / 256), 256, 0, stream>>>(ms, ms_pad, HK, HK, 72, totS);
    pad_copy<<<dim3((totS + 255) / 256), 256, 0, stream>>>(pan2, pan2pad, HK, HK, 72, totS);
    border_zero<<<dim3(NB * CI), 256, 0, stream>>>(ms_pad, HK, HK, 72);
    border_zero<<<dim3(NB * CI), 256, 0, stream>>>(pan2pad, HK, HK, 72);
    pad_rci<<<dim3(4, 258, NB), 256, 0, stream>>>(pan, panbf);
  }

  // feature convs: k,v small (fp32); q big (MFMA bf16 -> hi/lo rci)
  conv3s<<<dim3(HK / 64, HK / 8, NB * 8), 256, 0, stream>>>(pan2pad, wtk, bk, k_fea, HK, HK, 72, HK * HK, HK);
  conv3s<<<dim3(HK / 64, HK / 8, NB * 8), 256, 0, stream>>>(ms_pad,  wtv, bv, v_fea, HK, HK, 72, HK * HK, HK);
  conv3mq<<<dim3(4, 256, NB), 256, 0, stream>>>(panbf, wimgq, bq, qhi, qlo);
  qz<<<dim3(NB), 256, 0, stream>>>(qhi, qlo);

  // k-patch max norm -> scale
  knorm_kernel<<<dim3(LL, NB), 64, 0, stream>>>(k_fea, norms);
  kscale_kernel<<<NB, 256, 0, stream>>>(norms, kscale);

  // K im2col hi/lo (kscale folded)
  kp_gather2<<<dim3(25, 2, NB), 256, 0, stream>>>(k_fea, kscale, khi, klo);

  // QK MFMA scores + softmax -> bf16 wn  [panbf dead; scores reuses tail]
  qk_mfma<<<dim3(64, NB), 256, 0, stream>>>(qhi, qlo, khi, klo, scores);
  softmax_rows<<<dim3(8192), 256, 0, stream>>>(scores, wnbf);

  // resbf borders (aliases q hi/lo; dead after qk_mfma)
  rbz<<<dim3(NB), 256, 0, stream>>>(resbf);

  // v patch bf16 transposed matrix
  vpt_gather<<<dim3(NPAD / 4, NB), 256, 0, stream>>>(v_fea, vptbf);

  // PV MFMA + conv-transpose gather (U reuses tail after softmax consumed scores)
  if (batched) {
    pv_mfma<<<dim3(64, 13, NB), 256, 0, stream>>>(wnbf, vptbf, U);
    u_scatter<<<dim3(4, HQ, NB), 256, 0, stream>>>(U, resbf, 0);
  } else {
    for (int n = 0; n < NB; ++n) {
      pv_mfma<<<dim3(64, 13, 1), 256, 0, stream>>>(wnbf + (size_t)n * 4096 * 256,
                                                   vptbf + (size_t)n * NPAD * 256, U);
      u_scatter<<<dim3(4, HQ, 1), 256, 0, stream>>>(U, resbf, n);
    }
  }

  // final conv (MFMA bf16) -> d_out fp32
  conv3m<<<dim3(4, 256, NB), 256, 0, stream>>>(resbf, wimgr, br, out, HQ * HQ, HQ);
}